// Round 16
// baseline (236.851 us; speedup 1.0000x reference)
//
#include <hip/hip_runtime.h>

#define DEV __device__ __forceinline__

typedef unsigned short u16;
typedef unsigned int   u32;
typedef short  s16x8  __attribute__((ext_vector_type(8)));
typedef float  f32x4  __attribute__((ext_vector_type(4)));
typedef float  f32x16 __attribute__((ext_vector_type(16)));

constexpr int Bc = 2, Hc = 16, Tc = 2048, Dc = 1024, HDc = 64, Mc = 4096;
constexpr int TP = Tc + 32;           // key rows incl. prompts
constexpr float SCALEc = 0.125f;      // 1/sqrt(64)
constexpr float LOG2E = 1.44269504088896340736f;
constexpr float SCALE2c = SCALEc * LOG2E;   // log2-domain scale
constexpr float NEGc = -1e30f;

typedef __attribute__((address_space(3))) void lds_void;
typedef const __attribute__((address_space(1))) void g_void;

DEV void gload16(const void* g, void* l) {
  __builtin_amdgcn_global_load_lds((g_void*)g, (lds_void*)l, 16, 0, 0);
}

DEV int swz(int r) { return (r & 7) ^ ((r >> 3) & 7); }   // LDS col-slot swizzle

DEV u32 bfr(float f) {                 // f32 -> bf16 bits, RNE
  u32 u = __float_as_uint(f);
  return (u + 0x7fffu + ((u >> 16) & 1u)) >> 16;
}
DEV u32 cvtpk(float a, float b) {      // packed f32x2 -> bf16x2 (RNE), 1 inst
  u32 r;
  asm("v_cvt_pk_bf16_f32 %0, %1, %2" : "=v"(r) : "v"(a), "v"(b));
  return r;
}
DEV s16x8 mk8(u32 w0, u32 w1, u32 w2, u32 w3) {
  union { u32 u[4]; s16x8 v; } x;
  x.u[0] = w0; x.u[1] = w1; x.u[2] = w2; x.u[3] = w3;
  return x.v;
}
DEV float geluf(float x) { return 0.5f * x * (1.0f + erff(x * 0.70710678118654752440f)); }

DEV float wredS(float v) {
  #pragma unroll
  for (int o = 32; o; o >>= 1) v += __shfl_xor(v, o);
  return v;
}
DEV float wredM(float v) {
  #pragma unroll
  for (int o = 32; o; o >>= 1) v = fmaxf(v, __shfl_xor(v, o));
  return v;
}
DEV float bredS(float v, float* sm) {   // 4-wave block
  v = wredS(v);
  __syncthreads();
  if ((threadIdx.x & 63) == 0) sm[threadIdx.x >> 6] = v;
  __syncthreads();
  return sm[0] + sm[1] + sm[2] + sm[3];
}
DEV float bredM(float v, float* sm) {
  v = wredM(v);
  __syncthreads();
  if ((threadIdx.x & 63) == 0) sm[threadIdx.x >> 6] = v;
  __syncthreads();
  return fmaxf(fmaxf(sm[0], sm[1]), fmaxf(sm[2], sm[3]));
}

// ---------------- weight transpose+convert: dst[n][k] = bf16(src[k][n]) -----
__global__ __launch_bounds__(256) void transpose_w_k(const float* __restrict__ src,
                                                     u16* __restrict__ dst) {
  __shared__ float tile[32][33];
  int bx = blockIdx.x, by = blockIdx.y;     // n0 = bx*32 , k0 = by*32
  int tx = threadIdx.x & 31, ty = threadIdx.x >> 5;   // ty 0..7
  #pragma unroll
  for (int i = 0; i < 32; i += 8)
    tile[ty + i][tx] = src[(size_t)(by * 32 + ty + i) * Dc + bx * 32 + tx];
  __syncthreads();
  #pragma unroll
  for (int i = 0; i < 32; i += 8)
    dst[(size_t)(bx * 32 + ty + i) * Dc + by * 32 + tx] = (u16)bfr(tile[tx][ty + i]);
}

// ---------------- f32 -> bf16 bulk convert ----------------------------------
__global__ __launch_bounds__(256) void cvt_bf16_k(const float* __restrict__ in,
                                                  u16* __restrict__ out, int n4) {
  int i = blockIdx.x * 256 + threadIdx.x;
  if (i < n4) {
    float4 v = ((const float4*)in)[i];
    ushort4 u;
    u.x = (u16)bfr(v.x); u.y = (u16)bfr(v.y); u.z = (u16)bfr(v.z); u.w = (u16)bfr(v.w);
    ((ushort4*)out)[i] = u;
  }
}

// ---------------- append prompt rows to K (head-split, bf16) ----------------
__global__ __launch_bounds__(256) void kprompt_k(const float* __restrict__ p1,
                                                 const float* __restrict__ p2,
                                                 u16* __restrict__ kb) {
  int i = blockIdx.x * 256 + threadIdx.x;   // 65536 = B*H*32*64
  int d = i & 63, j = (i >> 6) & 31, h = (i >> 11) & 15, b = i >> 15;
  float v = (j < 16) ? p1[(size_t)(b * 16 + j) * Dc + h * 64 + d]
                     : p2[(size_t)(b * 16 + j - 16) * Dc + h * 64 + d];
  kb[(((size_t)(b * Hc + h) * TP + Tc + j) << 6) + d] = (u16)bfr(v);
}

// ---------------- V transpose per head: vb[bh][t][d] -> vt[bh][d][t] --------
__global__ __launch_bounds__(256) void vtrans_k(const u16* __restrict__ vb,
                                                u16* __restrict__ vt) {
  __shared__ u16 tl[64][65];
  int bh = blockIdx.x >> 5, tc = blockIdx.x & 31;
  int d = threadIdx.x & 63, r = threadIdx.x >> 6;
  #pragma unroll
  for (int i = 0; i < 64; i += 4)
    tl[r + i][d] = vb[(((size_t)bh * Tc + tc * 64 + r + i) << 6) + d];
  __syncthreads();
  int t = threadIdx.x & 63, dd = threadIdx.x >> 6;
  #pragma unroll
  for (int i = 0; i < 64; i += 4)
    vt[((size_t)bh * 64 + dd + i) * Tc + tc * 64 + t] = tl[t][dd + i];
}

// ---------------- 128x128 bf16 MFMA GEMM ------------------------------------
// BM=BN=128 BK=32; 4 waves 2x2. LDS-staged C epilogue -> coalesced vector
// stores. 1D grid + XCD swizzle.
// MODE 0: QKV epilogue; MODE 1: bias+gelu->bf16; MODE 2: bias+residual->f32
template <int MODE, int NBX>
__global__ __launch_bounds__(256, 3) void gemm128_k(
    const u16* __restrict__ A, const u16* __restrict__ Bt,
    const float* __restrict__ bias0, const float* __restrict__ bias1,
    const float* __restrict__ bias2,
    u16* __restrict__ outQ, u16* __restrict__ outK, u16* __restrict__ outV,
    u16* __restrict__ outB, float* __restrict__ outF,
    const float* __restrict__ resid) {
  __shared__ __align__(16) u16 smem[17408];
  u16* as0 = smem;                 // [2][128*32]
  u16* bs0 = smem + 2 * 128 * 32;  // [2][128*32]
  const int tid = threadIdx.x, lane = tid & 63, wave = tid >> 6;
  const int wr = wave >> 1, wc = wave & 1;
  const int nwg = gridDim.x, bid = (int)blockIdx.x;
  const int wg = (bid & 7) * (nwg >> 3) + (bid >> 3);
  const int row0 = (wg % NBX) * 128, col0 = (wg / NBX) * 128;

  f32x4 zero4;
  #pragma unroll
  for (int r = 0; r < 4; ++r) zero4[r] = 0.f;
  f32x4 acc[4][4];
  #pragma unroll
  for (int i = 0; i < 4; ++i)
    #pragma unroll
    for (int j = 0; j < 4; ++j) acc[i][j] = zero4;

  auto stage = [&](int buf, int kt) {
    const int k0 = kt * 32;
    #pragma unroll
    for (int is = 0; is < 2; ++is) {
      int q = is * 256 + tid; int r = q >> 2, c = q & 3, g = c ^ ((r >> 1) & 3);
      gload16(A + (size_t)(row0 + r) * Dc + k0 + g * 8,
              as0 + (size_t)buf * 4096 + (is * 256 + wave * 64) * 8);
    }
    #pragma unroll
    for (int is = 0; is < 2; ++is) {
      int q = is * 256 + tid; int r = q >> 2, c = q & 3, g = c ^ ((r >> 1) & 3);
      gload16(Bt + (size_t)(col0 + r) * Dc + k0 + g * 8,
              bs0 + (size_t)buf * 4096 + (is * 256 + wave * 64) * 8);
    }
  };

  stage(0, 0);
  asm volatile("s_waitcnt vmcnt(0)" ::: "memory");
  __syncthreads();

  int cur = 0;
  for (int kt = 0; kt < 32; ++kt) {
    if (kt + 1 < 32) stage(cur ^ 1, kt + 1);
    s16x8 af[4], bfv[4];
    #pragma unroll
    for (int f = 0; f < 4; ++f) {
      int r = wr * 64 + f * 16 + (lane & 15);
      int c = (lane >> 4) ^ ((r >> 1) & 3);
      af[f] = *(const s16x8*)&as0[cur * 4096 + r * 32 + c * 8];
    }
    #pragma unroll
    for (int f = 0; f < 4; ++f) {
      int r = wc * 64 + f * 16 + (lane & 15);
      int c = (lane >> 4) ^ ((r >> 1) & 3);
      bfv[f] = *(const s16x8*)&bs0[cur * 4096 + r * 32 + c * 8];
    }
    __builtin_amdgcn_s_setprio(1);
    #pragma unroll
    for (int i = 0; i < 4; ++i)
      #pragma unroll
      for (int j = 0; j < 4; ++j)
        acc[i][j] = __builtin_amdgcn_mfma_f32_16x16x32_bf16(af[i], bfv[j], acc[i][j], 0, 0, 0);
    __builtin_amdgcn_s_setprio(0);
    __syncthreads();
    cur ^= 1;
  }

  if (MODE == 0 || MODE == 1) {
    const int CS = 136;
    u16* ct = smem;
    #pragma unroll
    for (int i = 0; i < 4; ++i)
      #pragma unroll
      for (int j = 0; j < 4; ++j)
        #pragma unroll
        for (int r = 0; r < 4; ++r) {
          int rl = wr * 64 + i * 16 + (lane >> 4) * 4 + r;
          int cl = wc * 64 + j * 16 + (lane & 15);
          float v = acc[i][j][r];
          if (MODE == 0) {
            int n = (col0 + cl) & 1023;
            int which = (col0 + cl) >> 10;
            v += (which == 0 ? bias0 : (which == 1 ? bias1 : bias2))[n];
          } else {
            v = geluf(v + bias0[col0 + cl]);
          }
          ct[rl * CS + cl] = (u16)bfr(v);
        }
    __syncthreads();
    #pragma unroll
    for (int it = 0; it < 16; ++it) {
      int linear = it * 256 + tid;
      int row = linear >> 5, c4 = (linear & 31) * 4;
      ushort4 val = *(const ushort4*)&ct[row * CS + c4];
      int grow = row0 + row;
      if (MODE == 1) {
        *(ushort4*)&outB[(size_t)grow * Dc + col0 + c4] = val;
      } else {
        int col = col0 + c4;
        int which = col >> 10, n = col & 1023;
        int hh = n >> 6, d = n & 63, bb = grow >> 11, t = grow & 2047;
        if (which == 0)
          *(ushort4*)&outQ[(((size_t)(bb * Hc + hh) * Tc + t) << 6) + d] = val;
        else if (which == 1)
          *(ushort4*)&outK[(((size_t)(bb * Hc + hh) * TP + t) << 6) + d] = val;
        else
          *(ushort4*)&outV[(((size_t)(bb * Hc + hh) * Tc + t) << 6) + d] = val;
      }
    }
  } else {
    const int CSF = 132;
    float* cf = (float*)smem;
    #pragma unroll
    for (int p = 0; p < 2; ++p) {
      if (wr == p) {
        #pragma unroll
        for (int i = 0; i < 4; ++i)
          #pragma unroll
          for (int j = 0; j < 4; ++j)
            #pragma unroll
            for (int r = 0; r < 4; ++r) {
              int rl = i * 16 + (lane >> 4) * 4 + r;
              int cl = wc * 64 + j * 16 + (lane & 15);
              cf[rl * CSF + cl] = acc[i][j][r];
            }
      }
      __syncthreads();
      #pragma unroll
      for (int it = 0; it < 8; ++it) {
        int linear = it * 256 + tid;
        int row = linear >> 5, c4 = (linear & 31) * 4;
        float4 v = *(const float4*)&cf[row * CSF + c4];
        int grow = row0 + p * 64 + row;
        int col = col0 + c4;
        float4 rr = *(const float4*)&resid[(size_t)grow * Dc + col];
        float4 o;
        o.x = v.x + bias0[col + 0] + rr.x;
        o.y = v.y + bias0[col + 1] + rr.y;
        o.z = v.z + bias0[col + 2] + rr.z;
        o.w = v.w + bias0[col + 3] + rr.w;
        *(float4*)&outF[(size_t)grow * Dc + col] = o;
      }
      __syncthreads();
    }
  }
}

// ---------------- flash attention, fixed-m, split-K x2 ----------------------
// R13 base (69.5us: f32 full-line partials, FETCH=12.4MB demand-clean).
// Residency A/B: lb2 clean (12.4MB) / lb4 thrash (209MB) / THIS ROUND lb3.
// Falsifier: FETCH>80MB or dur>=80us -> revert to lb2.
// P half-exchange via v_permlane32_swap_b32.
__global__ __launch_bounds__(256, 3) void attn_k(
    const u16* __restrict__ qb,   // [bh][T][64]
    const u16* __restrict__ kb,   // [bh][T+32][64]
    const u16* __restrict__ vt,   // [bh][64][T]
    const float* __restrict__ maskp,   // [B][T]
    float* __restrict__ OP0, float* __restrict__ OP1,
    float* __restrict__ ML) {
  __shared__ __align__(16) u16 kls[2][64 * 64];
  __shared__ __align__(16) u16 vls[2][64 * 64];
  __shared__ float mls[1024];

  const int tid = threadIdx.x, lane = tid & 63, wave = tid >> 6;
  const int wg = ((int)blockIdx.x & 7) * 128 + ((int)blockIdx.x >> 3);
  const int ks = wg & 1, qt = (wg >> 1) & 15, bh = wg >> 5;
  const int b = bh >> 4;
  const int lo = lane & 31, h5 = lane >> 5;
  const size_t kbase = (size_t)bh * TP * 64;
  const size_t vbase = (size_t)bh * 64 * Tc;

  for (int i = tid; i < 1024; i += 256)
    mls[i] = (1.0f - maskp[(size_t)b * Tc + ks * 1024 + i]) * NEGc;

  const int q0 = qt * 128 + wave * 32;
  s16x8 qf[4];
  #pragma unroll
  for (int kc = 0; kc < 4; ++kc)
    qf[kc] = *(const s16x8*)(qb + ((size_t)bh * Tc + q0 + lo) * 64 + kc * 16 + h5 * 8);

  auto stageKV = [&](int buf, int kt2) {
    #pragma unroll
    for (int is = 0; is < 2; ++is) {
      int q = is * 256 + tid; int r = q >> 3, c = q & 7, g = c ^ swz(r);
      gload16(kb + kbase + (size_t)(kt2 * 64 + r) * 64 + g * 8,
              &kls[buf][(is * 256 + wave * 64) * 8]);
      gload16(vt + vbase + (size_t)r * Tc + kt2 * 64 + g * 8,
              &vls[buf][(is * 256 + wave * 64) * 8]);
    }
  };

  stageKV(0, ks * 16);
  asm volatile("s_waitcnt vmcnt(0)" ::: "memory");
  __syncthreads();

  f32x16 zero16;
  #pragma unroll
  for (int r = 0; r < 16; ++r) zero16[r] = 0.f;
  f32x16 O0 = zero16, O1 = zero16, racc = zero16;

  int cur = 0;
  for (int kt = 0; kt < 16; ++kt) {
    if (kt + 1 < 16) stageKV(cur ^ 1, ks * 16 + kt + 1);

    #pragma unroll
    for (int c = 0; c < 2; ++c) {
      f32x16 s = zero16;
      __builtin_amdgcn_s_setprio(1);
      #pragma unroll
      for (int kc = 0; kc < 4; ++kc) {
        int r = c * 32 + lo;
        int ci = (kc * 2 + h5) ^ swz(r);
        s16x8 kf = *(const s16x8*)&kls[cur][r * 64 + ci * 8];
        s = __builtin_amdgcn_mfma_f32_32x32x16_bf16(kf, qf[kc], s, 0, 0, 0);
      }
      __builtin_amdgcn_s_setprio(0);

      float4 mq[4];
      #pragma unroll
      for (int g = 0; g < 4; ++g)
        mq[g] = *(const float4*)&mls[kt * 64 + c * 32 + 4 * h5 + 8 * g];

      float p[16];
      #pragma unroll
      for (int r = 0; r < 16; ++r) {
        float mv = (&mq[r >> 2].x)[r & 3];
        p[r] = exp2f(s[r] * SCALE2c + mv);
        racc[r] += p[r];
      }

      // P -> bf16 A-frags: permlane32_swap half-exchange
      #pragma unroll
      for (int k1 = 0; k1 < 2; ++k1) {
        u32 w0 = cvtpk(p[8 * k1 + 0], p[8 * k1 + 1]);
        u32 w1 = cvtpk(p[8 * k1 + 2], p[8 * k1 + 3]);
        u32 w2 = cvtpk(p[8 * k1 + 4], p[8 * k1 + 5]);
        u32 w3 = cvtpk(p[8 * k1 + 6], p[8 * k1 + 7]);
        asm volatile("v_permlane32_swap_b32 %0, %1" : "+v"(w2), "+v"(w0));
        asm volatile("v_permlane32_swap_b32 %0, %1" : "+v"(w3), "+v"(w1));
        s16x8 pf = mk8(w0, w1, w2, w3);
        __builtin_amdgcn_s_setprio(1);
        #pragma unroll
        for (int db = 0; db < 2; ++db) {
          int d = db * 32 + lo;
          int ci = (c * 4 + k1 * 2 + h5) ^ swz(d);
          s16x8 vf = *(const s16x8*)&vls[cur][d * 64 + ci * 8];
          if (db == 0) O0 = __builtin_amdgcn_mfma_f32_32x32x16_bf16(pf, vf, O0, 0, 0, 0);
          else         O1 = __builtin_amdgcn_mfma_f32_32x32x16_bf16(pf, vf, O1, 0, 0, 0);
        }
        __builtin_amdgcn_s_setprio(0);
      }
    }
    __syncthreads();
    cur ^= 1;
  }

  // epilogue: f32 unnormalized partials (full 128B lines per row) + row sums
  float* dst = ks ? OP1 : OP0;
  #pragma unroll
  for (int r = 0; r < 16; ++r) {
    int row = q0 + (r & 3) + 8 * (r >> 2) + 4 * h5;
    dst[((size_t)bh * Tc + row) * 64 + lo]      = O0[r];
    dst[((size_t)bh * Tc + row) * 64 + 32 + lo] = O1[r];
  }
  float lt = 0.f;
  #pragma unroll
  for (int r = 0; r < 16; ++r) lt += racc[r];
  lt += __shfl_xor(lt, 32);
  if (lane < 32)
    ML[((size_t)ks * 32 + bh) * Tc + q0 + lo] = lt;
}

// ---------------- combine the 2 flash partials -> ctx -----------------------
__global__ __launch_bounds__(256) void combine_k(const float* __restrict__ OP0,
                                                 const float* __restrict__ OP1,
                                                 const float* __restrict__ ML,
                                                 float* __restrict__ ctx) {
  int idx = blockIdx.x * 256 + threadIdx.x;  // 32*2048*16
  int row = idx >> 4;                        // bh*T + t
  int c4 = (idx & 15) * 4;
  float linv = 1.0f / (ML[(size_t)row] + ML[(size_t)32 * Tc + row]);
  float4 v0 = *(const float4*)(OP0 + (size_t)row * 64 + c4);
  float4 v1 = *(const float4*)(OP1 + (size_t)row * 64 + c4);
  float4 o;
  o.x = (v0.x + v1.x) * linv;
  o.y = (v0.y + v1.y) * linv;
  o.z = (v0.z + v1.z) * linv;
  o.w = (v0.w + v1.w) * linv;
  *(float4*)(ctx + (size_t)row * 64 + c4) = o;
}

// ---------------- prompt scores: SP[bh][32][T] = (Kp . Q^T) * scale ---------
__global__ __launch_bounds__(256) void promptsc_k(const u16* __restrict__ qb,
                                                  const u16* __restrict__ kb,
                                                  float* __restrict__ SP) {
  __shared__ __align__(16) u16 kpls[32 * 64];
  const int tid = threadIdx.x, lane = tid & 63, wave = tid >> 6;
  const int qt = blockIdx.x, bh = blockIdx.y;
  const int lo = lane & 31, h5 = lane >> 5;
  const size_t kbase = (size_t)bh * TP * 64;

  {
    int r = tid >> 3, c = tid & 7, g = c ^ swz(r);
    gload16(kb + kbase + (size_t)(Tc + r) * 64 + g * 8, &kpls[wave * 64 * 8]);
  }
  const int q0 = qt * 128 + wave * 32;
  s16x8 qf[4];
  #pragma unroll
  for (int kc = 0; kc < 4; ++kc)
    qf[kc] = *(const s16x8*)(qb + ((size_t)bh * Tc + q0 + lo) * 64 + kc * 16 + h5 * 8);
  asm volatile("s_waitcnt vmcnt(0)" ::: "memory");
  __syncthreads();

  f32x16 sp;
  #pragma unroll
  for (int r = 0; r < 16; ++r) sp[r] = 0.f;
  #pragma unroll
  for (int kc = 0; kc < 4; ++kc) {
    int ci = (kc * 2 + h5) ^ swz(lo);
    s16x8 kf = *(const s16x8*)&kpls[lo * 64 + ci * 8];
    sp = __builtin_amdgcn_mfma_f32_32x32x16_bf16(kf, qf[kc], sp, 0, 0, 0);
  }
  #pragma unroll
  for (int r = 0; r < 16; ++r) {
    int pr = (r & 3) + 8 * (r >> 2) + 4 * h5;
    SP[((size_t)bh * 32 + pr) * Tc + q0 + lo] = sp[r] * SCALEc;
  }
}

// ---------------- prompt double softmax over t ------------------------------
__global__ __launch_bounds__(256) void prompt_softmax_k(float* __restrict__ SP,
                                                        const float* __restrict__ pr1,
                                                        const float* __restrict__ pr2) {
  __shared__ float sm[4];
  int row = blockIdx.x;          // bh*32 + p
  int bh = row >> 5, p = row & 31, b = bh >> 4;
  const float* prior = (p < 16 ? pr1 : pr2) + (size_t)b * Tc;
  float* s = SP + (size_t)row * Tc;
  int tid = threadIdx.x;
  float v[8], pw[8];
  #pragma unroll
  for (int i = 0; i < 8; ++i) { int t = tid + i * 256; v[i] = s[t]; pw[i] = prior[t]; }
  float mx = -INFINITY;
  #pragma unroll
  for (int i = 0; i < 8; ++i) mx = fmaxf(mx, v[i]);
  mx = bredM(mx, sm);
  float sum = 0.f;
  #pragma unroll
  for (int i = 0; i < 8; ++i) { v[i] = __expf(v[i] - mx); sum += v[i]; }
  sum = bredS(sum, sm);
  float inv = 1.0f / sum;
  float mx2 = -INFINITY;
  #pragma unroll
  for (int i = 0; i < 8; ++i) { v[i] = v[i] * inv * pw[i]; mx2 = fmaxf(mx2, v[i]); }
  mx2 = bredM(mx2, sm);
  float sum2 = 0.f;
  #pragma unroll
  for (int i = 0; i < 8; ++i) { v[i] = __expf(v[i] - mx2); sum2 += v[i]; }
  sum2 = bredS(sum2, sm);
  float inv2 = 1.0f / sum2;
  #pragma unroll
  for (int i = 0; i < 8; ++i) s[tid + i * 256] = v[i] * inv2;
}

// ---------------- p_v partials: PVP[ts][bh][32][64] = PA-chunk @ ctx-chunk --
__global__ __launch_bounds__(256) void pv_partial_k(const float* __restrict__ PA,
                                                    const float* __restrict__ ctx,
                                                    float* __restrict__ PVP) {
  __shared__ float pal[32][128];
  const int bh = blockIdx.x, ts = blockIdx.y;
  const int tid = threadIdx.x;
  const int t0 = ts * 128;
  const float* pabase = PA + (size_t)bh * 32 * Tc;

  #pragma unroll
  for (int i = 0; i < 4; ++i) {
    int e = tid + i * 256;
    int p = e >> 5, c4 = e & 31;
    *(float4*)&pal[p][c4 * 4] = *(const float4*)&pabase[(size_t)p * Tc + t0 + c4 * 4];
  }
  __syncthreads();

  const int d4 = tid & 15, p0 = tid >> 4;
  const float* cb = ctx + ((size_t)bh * Tc + t0) * 64 + d4 * 4;
  float4 a0 = make_float4(0.f, 0.f, 0.f, 0.f);
  float4 a1 = make_float4(0.f, 0.f, 0.f, 0.f);
  for (int tt = 0; tt < 128; ++tt) {
    float4 v = *(const float4*)(cb + (size_t)tt * 64);
    float w0 = pal[p0][tt], w1 = pal[p0 + 16][tt];
    a0.x += w0 * v.x; a0.y += w0 * v.y; a0.z += w0 * v.z; a0.w += w0 * v.w;
    a1.x += w1 * v.x; a1.y += w1 * v.y; a1.z += w1 * v.z; a1.w += w1 * v.w;
  }
  float* o = PVP + (((size_t)ts * 32 + bh) * 32) * 64 + d4 * 4;
  *(float4*)(o + (size_t)p0 * 64) = a0;
  *(float4*)(o + (size_t)(p0 + 16) * 64) = a1;
}

__global__ __launch_bounds__(256) void pv_reduce_k(const float* __restrict__ PVP,
                                                   float* __restrict__ PVo) {
  int e = blockIdx.x * 256 + threadIdx.x;   // 0..65535
  float s = 0.f;
  #pragma unroll
  for (int ts = 0; ts < 16; ++ts) s += PVP[(size_t)ts * 65536 + e];
  PVo[e] = s;
}

// ---------------- residual + LN (main path) ---------------------------------
__global__ __launch_bounds__(256) void resln_k(const float* __restrict__ x,
                                               const float* __restrict__ ctx,
                                               const float* __restrict__ g,
                                               const float* __restrict__ be,
                                               float* __restrict__ res,
                                               u16* __restrict__ lnout) {
  __shared__ float sm[4];
  int row = blockIdx.x;            // 0..4095
  int b = row >> 11, t = row & 2047;
  int tid = threadIdx.x, c4 = tid * 4;
  int h = c4 >> 6, d = c4 & 63;
  float4 xv = *(const float4*)(x + (size_t)row * Dc + c4);
  float4 cv = *(const float4*)(ctx + (((size_t)(b * Hc + h) * Tc + t) << 6) + d);
  float r0 = xv.x + cv.x, r1 = xv.y + cv.y, r2 = xv.z + cv.z, r3 = xv.w + cv.w;
  float4 rr; rr.x = r0; rr.y = r1; rr.z = r2; rr.w = r3;
  *(float4*)(res + (size_t)row * Dc + c4) = rr;
  float s = bredS(r0 + r1 + r2 + r3, sm);
  float sq = bredS(r0 * r0 + r1 * r1 + r2 * r2 + r3 * r3, sm);
  float mu = s * (1.0f / Dc);
  float var = sq * (1.0f / Dc) - mu * mu;
  float rs = rsqrtf(var + 1e-6f);
  ushort4 o;
  o.x = (u16)bfr((r0 - mu) * rs * g[c4 + 0] + be[c4 + 0]);
  o.y = (u16)bfr((r1 - mu) * rs * g[c4 + 1] + be[c4 + 1]);
  o.z = (u16)bfr((r2 - mu) * rs * g[c4 + 2] + be[c4 + 2]);
  o.w = (u16)bfr((r3 - mu) * rs * g[c4 + 3] + be[c4 + 3]);
  *(ushort4*)(lnout + (size_t)row * Dc + c4) = o;
}

// ---------------- prompt merge + residual + LN ------------------------------
__global__ __launch_bounds__(256) void promptln_k(const float* __restrict__ PVo,
                                                  const float* __restrict__ p1,
                                                  const float* __restrict__ p2,
                                                  const float* __restrict__ g,
                                                  const float* __restrict__ be,
                                                  float* __restrict__ PMLN) {
  __shared__ float sm[4];
  int row = blockIdx.x;            // 0..63 : b = row>>5, j = row&31
  int b = row >> 5, j = row & 31;
  int tid = threadIdx.x, c4 = tid * 4;
  int h = c4 >> 6, d = c4 & 63;
  const float* pr = (j < 16) ? (p1 + (size_t)(b * 16 + j) * Dc + c4)
                             : (p2 + (size_t)(b * 16 + j - 16) * Dc + c4);
  float4 pv4 = *(const float4*)(PVo + (((size_t)(b * Hc + h) * 32 + j) << 6) + d);
  float4 pp4 = *(const float4*)pr;
  float r0 = pv4.x + pp4.x, r1 = pv4.y + pp4.y, r2 = pv4.z + pp4.z, r3 = pv4.w + pp4.w;
  float s = bredS(r0 + r1 + r2 + r3, sm);
  float sq = bredS(r0 * r0 + r1 * r1 + r2 * r2 + r3 * r3, sm);
  float mu = s * (1.0f / Dc);
  float var = sq * (1.0f / Dc) - mu * mu;
  float rs = rsqrtf(var + 1e-6f);
  float4 o;
  o.x = (r0 - mu) * rs * g[c4 + 0] + be[c4 + 0];
  o.y = (r1 - mu) * rs * g[c4 + 1] + be[c4 + 1];
  o.z = (r2 - mu) * rs * g[c4 + 2] + be[c4 + 2];
  o.w = (r3 - mu) * rs * g[c4 + 3] + be[c4 + 3];
  *(float4*)(PMLN + (size_t)row * Dc + c4) = o;
}

// ---------------- prompt FFN, split-K partials ------------------------------
__global__ __launch_bounds__(256) void pffn_partial_k(const float* __restrict__ PMLN,
                                                      const float* __restrict__ Wp1,
                                                      const float* __restrict__ Wp2,
                                                      float* __restrict__ PB) {
  __shared__ float pm[32][32];
  const int tid = threadIdx.x;
  const int ks = blockIdx.x, ct = blockIdx.y, s = blockIdx.z;
  const int c = ct * 256 + tid;
  const int k0 = ks * 32;
  const float* W = s ? Wp2 : Wp1;

  #pragma unroll
  for (int i = 0; i < 4; ++i) {
    int e = tid + i * 256;
    int r = e >> 5, kk = e & 31;
    int grow = (r >> 4) * 32 + s * 16 + (r & 15);
    pm[r][kk] = PMLN[(size_t)grow * Dc + k0 + kk];
  }
  __syncthreads();

  float acc[32];
  #pragma unroll
  for (int r = 0; r < 32; ++r) acc[r] = 0.f;
  for (int kk = 0; kk < 32; ++kk) {
    float w = W[(size_t)(k0 + kk) * Dc + c];
    #pragma unroll
    for (int r = 0; r < 32; ++r) acc[r] += pm[r][kk] * w;
  }

  float* pb = PB + (((size_t)ks * 2 + s) * 32) * Dc + c;
  #pragma unroll
  for (int r = 0; r < 32; ++r) pb[(size_t)r * Dc] = acc[r];
}

__global__ __launch_bounds__(256) void pffn_reduce_k(const float* __restrict__ PB,
                                                     const float* __restrict__ bp1,
                                                     const float* __restrict__ bp2,
                                                     float* __restrict__ out) {
  int e = blockIdx.x * 256 + threadIdx.x;   // 0..65535
  int s = e >> 15, rem = e & 32767;
  int r = rem >> 10, c = rem & 1023;
  float sum = 0.f;
  const float* pb = PB + ((size_t)s * 32 + r) * Dc + c;
  #pragma unroll
  for (int ks = 0; ks < 32; ++ks) sum += pb[(size_t)ks * 2 * 32 * Dc];
  const float* bp = s ? bp2 : bp1;
  out[(size_t)Mc * Dc + (size_t)s * (32 * Dc) + (size_t)r * Dc + c] = geluf(sum + bp[c]);
}

// ============================================================================
extern "C" void kernel_launch(void* const* d_in, const int* in_sizes, int n_in,
                              void* d_out, int out_size, void* d_ws, size_t ws_size,
                              hipStream_t stream) {
  (void)in_sizes; (void)n_in; (void)out_size; (void)ws_size;
  const float* x   = (const float*)d_in[0];
  const float* p1  = (const float*)d_in[1];
  const float* p2  = (const float*)d_in[2];
  const float* pr1 = (const float*)d_in[3];
  const float* pr2 = (const float*)d_in[4];
  const float* msk = (const float*)d_in[5];
  const float* Wq  = (const float*)d_in[6];
  const float* bq  = (const float*)d_in[7];
  const float* Wk  = (const float*)d_in[8];
  const float* bk  = (const float*)d_in[9];
  const float* Wv  = (const float*)d_in[10];
  const float* bv  = (const float*)d_in[11];
  const float* g2  = (const float*)d_in[12];
  const float* be2 = (const float*)d_in[13];
  const float* W1  = (const float*)d_in[14];
  const float* b1  = (const float*)d_in[15];
  const float* W2  = (const float*)d_in[16];
  const float* b2  = (const float*)d_in[17];
  const float* Wp1 = (const float*)d_in[18];
  const float* bp1 = (const float*)d_in[19];
  const float* Wp2 = (const float*)d_in[20];
  const float* bp2 = (const float*)d_in[21];

  char* ws = (char*)d_ws;
  size_t off = 0;
  auto alloc = [&](size_t bytes) {
    void* p = ws + off;
    off += (bytes + 255) & ~(size_t)255;
    return p;
  };
  u16* WQKVT = (u16*)alloc((size_t)3072 * 1024 * 2);
  u16* W1T   = (u16*)alloc((size_t)1024 * 1024 * 2);
  u16* W2T   = (u16*)alloc((size_t)1024 * 1024 * 2);
  u16* XB    = (u16*)alloc((size_t)Mc * Dc * 2);
  u16* QB    = (u16*)alloc((size_t)32 * Tc * 64 * 2);
  u16* KB    = (u16*)alloc((size_t)32 * TP * 64 * 2);
  u16* VB    = (u16*)alloc((size_t)32 * Tc * 64 * 2);
  u16* VT    = (u16*)alloc((size_t)32 * 64 * Tc * 2);
  float* CTX = (float*)alloc((size_t)32 * Tc * 64 * 4);
  float* SP  = (float*)alloc((size_t)32 * 32 * Tc * 4);
  float* PVo = (float*)alloc((size_t)32 * 32 * 64 * 4);
  float* RES = (float*)alloc((size_t)Mc * Dc * 4);
  float* PMLN = (float*)alloc((size_t)64 * Dc * 4);
  float* ML  = (float*)alloc((size_t)2 * 32 * Tc * 4);
  float* PVP = (float*)alloc((size_t)16 * 32 * 32 * 64 * 4);
  u16* LNOUT = XB;    // reuse: XB dead after QKV GEMM
  u16* H1    = VB;    // reuse: VB dead after V transpose
  float* PB  = SP;    // reuse: SP dead after pv
  float* OP0 = CTX;   // attn partial ks=0 (combined in place -> ctx)
  float* OP1 = RES;   // attn partial ks=1 (RES free until resln_k)

  float* outMain = (float*)d_out;

  // 1. weight transposes (bf16)
  transpose_w_k<<<dim3(32, 32), 256, 0, stream>>>(Wq, WQKVT);
  transpose_w_k<<<dim3(32, 32), 256, 0, stream>>>(Wk, WQKVT + (size_t)1024 * 1024);
  transpose_w_k<<<dim3(32, 32), 256, 0, stream>>>(Wv, WQKVT + (size_t)2 * 1024 * 1024);
  transpose_w_k<<<dim3(32, 32), 256, 0, stream>>>(W1, W1T);
  transpose_w_k<<<dim3(32, 32), 256, 0, stream>>>(W2, W2T);
  // 2. x -> bf16
  cvt_bf16_k<<<4096, 256, 0, stream>>>(x, XB, (Mc * Dc) / 4);
  // 3. QKV fused GEMM (N=3072), 128x128 tile, XCD swizzle (768 blocks)
  gemm128_k<0, 32><<<768, 256, 0, stream>>>(XB, WQKVT, bq, bk, bv, QB, KB, VB,
                                            nullptr, nullptr, nullptr);
  // 4. append prompt key rows
  kprompt_k<<<256, 256, 0, stream>>>(p1, p2, KB);
  // 5. V transpose per head
  vtrans_k<<<1024, 256, 0, stream>>>(VB, VT);
  // 6. flash attention (fixed-m, split-K x2, f32 partials, lb3 A/B)
  attn_k<<<1024, 256, 0, stream>>>(QB, KB, VT, msk, OP0, OP1, ML);
  // 6a. prompt scores
  promptsc_k<<<dim3(16, 32), 256, 0, stream>>>(QB, KB, SP);
  // 6b. combine partials -> ctx (in place over OP0)
  combine_k<<<4096, 256, 0, stream>>>(OP0, OP1, ML, CTX);
  // 7. prompt double-softmax (in place)
  prompt_softmax_k<<<1024, 256, 0, stream>>>(SP, pr1, pr2);
  // 8. p_v = p_a @ ctx : split-T partials + reduce
  pv_partial_k<<<dim3(32, 16), 256, 0, stream>>>(SP, CTX, PVP);
  pv_reduce_k<<<256, 256, 0, stream>>>(PVP, PVo);
  // 9. residual + LN (main)
  resln_k<<<4096, 256, 0, stream>>>(x, CTX, g2, be2, RES, LNOUT);
  // 10. prompt merge + LN
  promptln_k<<<64, 256, 0, stream>>>(PVo, p1, p2, g2, be2, PMLN);
  // 11. prompt FFN (split-K): partials then reduce -> d_out (p1_out, p2_out)
  pffn_partial_k<<<dim3(32, 4, 2), 256, 0, stream>>>(PMLN, Wp1, Wp2, PB);
  pffn_reduce_k<<<256, 256, 0, stream>>>(PB, bp1, bp2, outMain);
  // 12. FFN1: gelu(ln @ W1 + b1) -> bf16, 128x128 tile (256 blocks)
  gemm128_k<1, 32><<<256, 256, 0, stream>>>(LNOUT, W1T, b1, nullptr, nullptr,
                                            nullptr, nullptr, nullptr, H1,
                                            nullptr, nullptr);
  // 13. FFN2: h1 @ W2 + b2 + residual -> d_out (main), 128x128 tile
  gemm128_k<2, 32><<<256, 256, 0, stream>>>(H1, W2T, b2, nullptr, nullptr,
                                            nullptr, nullptr, nullptr, nullptr,
                                            outMain, RES);
}

// Round 17
// 223.953 us; speedup vs baseline: 1.0576x; 1.0576x over previous
//
#include <hip/hip_runtime.h>

#define DEV __device__ __forceinline__

typedef unsigned short u16;
typedef unsigned int   u32;
typedef short  s16x8  __attribute__((ext_vector_type(8)));
typedef float  f32x4  __attribute__((ext_vector_type(4)));
typedef float  f32x16 __attribute__((ext_vector_type(16)));

constexpr int Bc = 2, Hc = 16, Tc = 2048, Dc = 1024, HDc = 64, Mc = 4096;
constexpr int TP = Tc + 32;           // key rows incl. prompts
constexpr float SCALEc = 0.125f;      // 1/sqrt(64)
constexpr float LOG2E = 1.44269504088896340736f;
constexpr float SCALE2c = SCALEc * LOG2E;   // log2-domain scale
constexpr float NEGc = -1e30f;

typedef __attribute__((address_space(3))) void lds_void;
typedef const __attribute__((address_space(1))) void g_void;

DEV void gload16(const void* g, void* l) {
  __builtin_amdgcn_global_load_lds((g_void*)g, (lds_void*)l, 16, 0, 0);
}

DEV int swz(int r) { return (r & 7) ^ ((r >> 3) & 7); }   // LDS col-slot swizzle

DEV u32 bfr(float f) {                 // f32 -> bf16 bits, RNE
  u32 u = __float_as_uint(f);
  return (u + 0x7fffu + ((u >> 16) & 1u)) >> 16;
}
DEV u32 cvtpk(float a, float b) {      // packed f32x2 -> bf16x2 (RNE), 1 inst
  u32 r;
  asm("v_cvt_pk_bf16_f32 %0, %1, %2" : "=v"(r) : "v"(a), "v"(b));
  return r;
}
DEV s16x8 mk8(u32 w0, u32 w1, u32 w2, u32 w3) {
  union { u32 u[4]; s16x8 v; } x;
  x.u[0] = w0; x.u[1] = w1; x.u[2] = w2; x.u[3] = w3;
  return x.v;
}
DEV float geluf(float x) { return 0.5f * x * (1.0f + erff(x * 0.70710678118654752440f)); }

DEV float wredS(float v) {
  #pragma unroll
  for (int o = 32; o; o >>= 1) v += __shfl_xor(v, o);
  return v;
}
DEV float wredM(float v) {
  #pragma unroll
  for (int o = 32; o; o >>= 1) v = fmaxf(v, __shfl_xor(v, o));
  return v;
}
DEV float bredS(float v, float* sm) {   // 4-wave block
  v = wredS(v);
  __syncthreads();
  if ((threadIdx.x & 63) == 0) sm[threadIdx.x >> 6] = v;
  __syncthreads();
  return sm[0] + sm[1] + sm[2] + sm[3];
}
DEV float bredM(float v, float* sm) {
  v = wredM(v);
  __syncthreads();
  if ((threadIdx.x & 63) == 0) sm[threadIdx.x >> 6] = v;
  __syncthreads();
  return fmaxf(fmaxf(sm[0], sm[1]), fmaxf(sm[2], sm[3]));
}

// ---------------- batched weight transpose+convert (5 matrices, 1 launch) ---
// dst[n][k] = bf16(src[k][n]); z selects the (src,dst) pair.
__global__ __launch_bounds__(256) void transpose_w5_k(
    const float* __restrict__ Wq, const float* __restrict__ Wk,
    const float* __restrict__ Wv, const float* __restrict__ W1,
    const float* __restrict__ W2, u16* __restrict__ WQKVT,
    u16* __restrict__ W1T, u16* __restrict__ W2T) {
  __shared__ float tile[32][33];
  int bx = blockIdx.x, by = blockIdx.y, z = blockIdx.z;
  const float* src = (z == 0) ? Wq : (z == 1) ? Wk : (z == 2) ? Wv
                    : (z == 3) ? W1 : W2;
  u16* dst = (z == 0) ? WQKVT
           : (z == 1) ? WQKVT + (size_t)1024 * 1024
           : (z == 2) ? WQKVT + (size_t)2 * 1024 * 1024
           : (z == 3) ? W1T : W2T;
  int tx = threadIdx.x & 31, ty = threadIdx.x >> 5;   // ty 0..7
  #pragma unroll
  for (int i = 0; i < 32; i += 8)
    tile[ty + i][tx] = src[(size_t)(by * 32 + ty + i) * Dc + bx * 32 + tx];
  __syncthreads();
  #pragma unroll
  for (int i = 0; i < 32; i += 8)
    dst[(size_t)(bx * 32 + ty + i) * Dc + by * 32 + tx] = (u16)bfr(tile[tx][ty + i]);
}

// ---------------- f32 -> bf16 bulk convert ----------------------------------
__global__ __launch_bounds__(256) void cvt_bf16_k(const float* __restrict__ in,
                                                  u16* __restrict__ out, int n4) {
  int i = blockIdx.x * 256 + threadIdx.x;
  if (i < n4) {
    float4 v = ((const float4*)in)[i];
    ushort4 u;
    u.x = (u16)bfr(v.x); u.y = (u16)bfr(v.y); u.z = (u16)bfr(v.z); u.w = (u16)bfr(v.w);
    ((ushort4*)out)[i] = u;
  }
}

// ---------------- append prompt rows to K (head-split, bf16) ----------------
__global__ __launch_bounds__(256) void kprompt_k(const float* __restrict__ p1,
                                                 const float* __restrict__ p2,
                                                 u16* __restrict__ kb) {
  int i = blockIdx.x * 256 + threadIdx.x;   // 65536 = B*H*32*64
  int d = i & 63, j = (i >> 6) & 31, h = (i >> 11) & 15, b = i >> 15;
  float v = (j < 16) ? p1[(size_t)(b * 16 + j) * Dc + h * 64 + d]
                     : p2[(size_t)(b * 16 + j - 16) * Dc + h * 64 + d];
  kb[(((size_t)(b * Hc + h) * TP + Tc + j) << 6) + d] = (u16)bfr(v);
}

// ---------------- V transpose per head: vb[bh][t][d] -> vt[bh][d][t] --------
__global__ __launch_bounds__(256) void vtrans_k(const u16* __restrict__ vb,
                                                u16* __restrict__ vt) {
  __shared__ u16 tl[64][65];
  int bh = blockIdx.x >> 5, tc = blockIdx.x & 31;
  int d = threadIdx.x & 63, r = threadIdx.x >> 6;
  #pragma unroll
  for (int i = 0; i < 64; i += 4)
    tl[r + i][d] = vb[(((size_t)bh * Tc + tc * 64 + r + i) << 6) + d];
  __syncthreads();
  int t = threadIdx.x & 63, dd = threadIdx.x >> 6;
  #pragma unroll
  for (int i = 0; i < 64; i += 4)
    vt[((size_t)bh * 64 + dd + i) * Tc + tc * 64 + t] = tl[t][dd + i];
}

// ---------------- 128x128 bf16 MFMA GEMM ------------------------------------
// BM=BN=128 BK=32; 4 waves 2x2. LDS-staged C epilogue -> coalesced vector
// stores. 1D grid + XCD swizzle.
// MODE 0: QKV epilogue; MODE 1: bias+gelu->bf16; MODE 2: bias+residual->f32
template <int MODE, int NBX>
__global__ __launch_bounds__(256, 3) void gemm128_k(
    const u16* __restrict__ A, const u16* __restrict__ Bt,
    const float* __restrict__ bias0, const float* __restrict__ bias1,
    const float* __restrict__ bias2,
    u16* __restrict__ outQ, u16* __restrict__ outK, u16* __restrict__ outV,
    u16* __restrict__ outB, float* __restrict__ outF,
    const float* __restrict__ resid) {
  __shared__ __align__(16) u16 smem[17408];
  u16* as0 = smem;                 // [2][128*32]
  u16* bs0 = smem + 2 * 128 * 32;  // [2][128*32]
  const int tid = threadIdx.x, lane = tid & 63, wave = tid >> 6;
  const int wr = wave >> 1, wc = wave & 1;
  const int nwg = gridDim.x, bid = (int)blockIdx.x;
  const int wg = (bid & 7) * (nwg >> 3) + (bid >> 3);
  const int row0 = (wg % NBX) * 128, col0 = (wg / NBX) * 128;

  f32x4 zero4;
  #pragma unroll
  for (int r = 0; r < 4; ++r) zero4[r] = 0.f;
  f32x4 acc[4][4];
  #pragma unroll
  for (int i = 0; i < 4; ++i)
    #pragma unroll
    for (int j = 0; j < 4; ++j) acc[i][j] = zero4;

  auto stage = [&](int buf, int kt) {
    const int k0 = kt * 32;
    #pragma unroll
    for (int is = 0; is < 2; ++is) {
      int q = is * 256 + tid; int r = q >> 2, c = q & 3, g = c ^ ((r >> 1) & 3);
      gload16(A + (size_t)(row0 + r) * Dc + k0 + g * 8,
              as0 + (size_t)buf * 4096 + (is * 256 + wave * 64) * 8);
    }
    #pragma unroll
    for (int is = 0; is < 2; ++is) {
      int q = is * 256 + tid; int r = q >> 2, c = q & 3, g = c ^ ((r >> 1) & 3);
      gload16(Bt + (size_t)(col0 + r) * Dc + k0 + g * 8,
              bs0 + (size_t)buf * 4096 + (is * 256 + wave * 64) * 8);
    }
  };

  stage(0, 0);
  asm volatile("s_waitcnt vmcnt(0)" ::: "memory");
  __syncthreads();

  int cur = 0;
  for (int kt = 0; kt < 32; ++kt) {
    if (kt + 1 < 32) stage(cur ^ 1, kt + 1);
    s16x8 af[4], bfv[4];
    #pragma unroll
    for (int f = 0; f < 4; ++f) {
      int r = wr * 64 + f * 16 + (lane & 15);
      int c = (lane >> 4) ^ ((r >> 1) & 3);
      af[f] = *(const s16x8*)&as0[cur * 4096 + r * 32 + c * 8];
    }
    #pragma unroll
    for (int f = 0; f < 4; ++f) {
      int r = wc * 64 + f * 16 + (lane & 15);
      int c = (lane >> 4) ^ ((r >> 1) & 3);
      bfv[f] = *(const s16x8*)&bs0[cur * 4096 + r * 32 + c * 8];
    }
    __builtin_amdgcn_s_setprio(1);
    #pragma unroll
    for (int i = 0; i < 4; ++i)
      #pragma unroll
      for (int j = 0; j < 4; ++j)
        acc[i][j] = __builtin_amdgcn_mfma_f32_16x16x32_bf16(af[i], bfv[j], acc[i][j], 0, 0, 0);
    __builtin_amdgcn_s_setprio(0);
    __syncthreads();
    cur ^= 1;
  }

  if (MODE == 0 || MODE == 1) {
    const int CS = 136;
    u16* ct = smem;
    #pragma unroll
    for (int i = 0; i < 4; ++i)
      #pragma unroll
      for (int j = 0; j < 4; ++j)
        #pragma unroll
        for (int r = 0; r < 4; ++r) {
          int rl = wr * 64 + i * 16 + (lane >> 4) * 4 + r;
          int cl = wc * 64 + j * 16 + (lane & 15);
          float v = acc[i][j][r];
          if (MODE == 0) {
            int n = (col0 + cl) & 1023;
            int which = (col0 + cl) >> 10;
            v += (which == 0 ? bias0 : (which == 1 ? bias1 : bias2))[n];
          } else {
            v = geluf(v + bias0[col0 + cl]);
          }
          ct[rl * CS + cl] = (u16)bfr(v);
        }
    __syncthreads();
    #pragma unroll
    for (int it = 0; it < 16; ++it) {
      int linear = it * 256 + tid;
      int row = linear >> 5, c4 = (linear & 31) * 4;
      ushort4 val = *(const ushort4*)&ct[row * CS + c4];
      int grow = row0 + row;
      if (MODE == 1) {
        *(ushort4*)&outB[(size_t)grow * Dc + col0 + c4] = val;
      } else {
        int col = col0 + c4;
        int which = col >> 10, n = col & 1023;
        int hh = n >> 6, d = n & 63, bb = grow >> 11, t = grow & 2047;
        if (which == 0)
          *(ushort4*)&outQ[(((size_t)(bb * Hc + hh) * Tc + t) << 6) + d] = val;
        else if (which == 1)
          *(ushort4*)&outK[(((size_t)(bb * Hc + hh) * TP + t) << 6) + d] = val;
        else
          *(ushort4*)&outV[(((size_t)(bb * Hc + hh) * Tc + t) << 6) + d] = val;
      }
    }
  } else {
    const int CSF = 132;
    float* cf = (float*)smem;
    #pragma unroll
    for (int p = 0; p < 2; ++p) {
      if (wr == p) {
        #pragma unroll
        for (int i = 0; i < 4; ++i)
          #pragma unroll
          for (int j = 0; j < 4; ++j)
            #pragma unroll
            for (int r = 0; r < 4; ++r) {
              int rl = i * 16 + (lane >> 4) * 4 + r;
              int cl = wc * 64 + j * 16 + (lane & 15);
              cf[rl * CSF + cl] = acc[i][j][r];
            }
      }
      __syncthreads();
      #pragma unroll
      for (int it = 0; it < 8; ++it) {
        int linear = it * 256 + tid;
        int row = linear >> 5, c4 = (linear & 31) * 4;
        float4 v = *(const float4*)&cf[row * CSF + c4];
        int grow = row0 + p * 64 + row;
        int col = col0 + c4;
        float4 rr = *(const float4*)&resid[(size_t)grow * Dc + col];
        float4 o;
        o.x = v.x + bias0[col + 0] + rr.x;
        o.y = v.y + bias0[col + 1] + rr.y;
        o.z = v.z + bias0[col + 2] + rr.z;
        o.w = v.w + bias0[col + 3] + rr.w;
        *(float4*)&outF[(size_t)grow * Dc + col] = o;
      }
      __syncthreads();
    }
  }
}

// ---------------- flash attention, fixed-m, split-K x2, + prompt scores -----
// R13 proven config (69.5us: f32 full-line partials, lb2; lb3 null, lb4
// thrash, 8-wave fuse worse). ks==0 blocks also compute prompt-key scores
// (R3-proven fusion: kpls staged at start, 4 extra MFMA after K-loop).
__global__ __launch_bounds__(256, 2) void attn_k(
    const u16* __restrict__ qb,   // [bh][T][64]
    const u16* __restrict__ kb,   // [bh][T+32][64]
    const u16* __restrict__ vt,   // [bh][64][T]
    const float* __restrict__ maskp,   // [B][T]
    float* __restrict__ OP0, float* __restrict__ OP1,
    float* __restrict__ ML,
    float* __restrict__ SP) {     // [bh][32][T]
  __shared__ __align__(16) u16 kls[2][64 * 64];
  __shared__ __align__(16) u16 vls[2][64 * 64];
  __shared__ __align__(16) u16 kpls[32 * 64];
  __shared__ float mls[1024];

  const int tid = threadIdx.x, lane = tid & 63, wave = tid >> 6;
  const int wg = ((int)blockIdx.x & 7) * 128 + ((int)blockIdx.x >> 3);
  const int ks = wg & 1, qt = (wg >> 1) & 15, bh = wg >> 5;
  const int b = bh >> 4;
  const int lo = lane & 31, h5 = lane >> 5;
  const size_t kbase = (size_t)bh * TP * 64;
  const size_t vbase = (size_t)bh * 64 * Tc;

  for (int i = tid; i < 1024; i += 256)
    mls[i] = (1.0f - maskp[(size_t)b * Tc + ks * 1024 + i]) * NEGc;

  if (ks == 0) {  // prompt keys -> LDS (rows T..T+31), R3-proven pattern
    int r = tid >> 3, c = tid & 7, g = c ^ swz(r);
    gload16(kb + kbase + (size_t)(Tc + r) * 64 + g * 8, &kpls[wave * 64 * 8]);
  }

  const int q0 = qt * 128 + wave * 32;
  s16x8 qf[4];
  #pragma unroll
  for (int kc = 0; kc < 4; ++kc)
    qf[kc] = *(const s16x8*)(qb + ((size_t)bh * Tc + q0 + lo) * 64 + kc * 16 + h5 * 8);

  auto stageKV = [&](int buf, int kt2) {
    #pragma unroll
    for (int is = 0; is < 2; ++is) {
      int q = is * 256 + tid; int r = q >> 3, c = q & 7, g = c ^ swz(r);
      gload16(kb + kbase + (size_t)(kt2 * 64 + r) * 64 + g * 8,
              &kls[buf][(is * 256 + wave * 64) * 8]);
      gload16(vt + vbase + (size_t)r * Tc + kt2 * 64 + g * 8,
              &vls[buf][(is * 256 + wave * 64) * 8]);
    }
  };

  stageKV(0, ks * 16);
  asm volatile("s_waitcnt vmcnt(0)" ::: "memory");
  __syncthreads();

  f32x16 zero16;
  #pragma unroll
  for (int r = 0; r < 16; ++r) zero16[r] = 0.f;
  f32x16 O0 = zero16, O1 = zero16, racc = zero16;

  int cur = 0;
  for (int kt = 0; kt < 16; ++kt) {
    if (kt + 1 < 16) stageKV(cur ^ 1, ks * 16 + kt + 1);

    #pragma unroll
    for (int c = 0; c < 2; ++c) {
      f32x16 s = zero16;
      __builtin_amdgcn_s_setprio(1);
      #pragma unroll
      for (int kc = 0; kc < 4; ++kc) {
        int r = c * 32 + lo;
        int ci = (kc * 2 + h5) ^ swz(r);
        s16x8 kf = *(const s16x8*)&kls[cur][r * 64 + ci * 8];
        s = __builtin_amdgcn_mfma_f32_32x32x16_bf16(kf, qf[kc], s, 0, 0, 0);
      }
      __builtin_amdgcn_s_setprio(0);

      float4 mq[4];
      #pragma unroll
      for (int g = 0; g < 4; ++g)
        mq[g] = *(const float4*)&mls[kt * 64 + c * 32 + 4 * h5 + 8 * g];

      float p[16];
      #pragma unroll
      for (int r = 0; r < 16; ++r) {
        float mv = (&mq[r >> 2].x)[r & 3];
        p[r] = exp2f(s[r] * SCALE2c + mv);
        racc[r] += p[r];
      }

      // P -> bf16 A-frags: permlane32_swap half-exchange
      #pragma unroll
      for (int k1 = 0; k1 < 2; ++k1) {
        u32 w0 = cvtpk(p[8 * k1 + 0], p[8 * k1 + 1]);
        u32 w1 = cvtpk(p[8 * k1 + 2], p[8 * k1 + 3]);
        u32 w2 = cvtpk(p[8 * k1 + 4], p[8 * k1 + 5]);
        u32 w3 = cvtpk(p[8 * k1 + 6], p[8 * k1 + 7]);
        asm volatile("v_permlane32_swap_b32 %0, %1" : "+v"(w2), "+v"(w0));
        asm volatile("v_permlane32_swap_b32 %0, %1" : "+v"(w3), "+v"(w1));
        s16x8 pf = mk8(w0, w1, w2, w3);
        __builtin_amdgcn_s_setprio(1);
        #pragma unroll
        for (int db = 0; db < 2; ++db) {
          int d = db * 32 + lo;
          int ci = (c * 4 + k1 * 2 + h5) ^ swz(d);
          s16x8 vf = *(const s16x8*)&vls[cur][d * 64 + ci * 8];
          if (db == 0) O0 = __builtin_amdgcn_mfma_f32_32x32x16_bf16(pf, vf, O0, 0, 0, 0);
          else         O1 = __builtin_amdgcn_mfma_f32_32x32x16_bf16(pf, vf, O1, 0, 0, 0);
        }
        __builtin_amdgcn_s_setprio(0);
      }
    }
    __syncthreads();
    cur ^= 1;
  }

  // prompt scores (ks==0 blocks): S_p^T[pkey][q] * scale
  if (ks == 0) {
    f32x16 sp = zero16;
    #pragma unroll
    for (int kc = 0; kc < 4; ++kc) {
      int ci = (kc * 2 + h5) ^ swz(lo);
      s16x8 kf = *(const s16x8*)&kpls[lo * 64 + ci * 8];
      sp = __builtin_amdgcn_mfma_f32_32x32x16_bf16(kf, qf[kc], sp, 0, 0, 0);
    }
    #pragma unroll
    for (int r = 0; r < 16; ++r) {
      int pr = (r & 3) + 8 * (r >> 2) + 4 * h5;
      SP[((size_t)bh * 32 + pr) * Tc + q0 + lo] = sp[r] * SCALEc;
    }
  }

  // epilogue: f32 unnormalized partials (full 128B lines per row) + row sums
  float* dst = ks ? OP1 : OP0;
  #pragma unroll
  for (int r = 0; r < 16; ++r) {
    int row = q0 + (r & 3) + 8 * (r >> 2) + 4 * h5;
    dst[((size_t)bh * Tc + row) * 64 + lo]      = O0[r];
    dst[((size_t)bh * Tc + row) * 64 + 32 + lo] = O1[r];
  }
  float lt = 0.f;
  #pragma unroll
  for (int r = 0; r < 16; ++r) lt += racc[r];
  lt += __shfl_xor(lt, 32);
  if (lane < 32)
    ML[((size_t)ks * 32 + bh) * Tc + q0 + lo] = lt;
}

// ---------------- combine the 2 flash partials -> ctx -----------------------
__global__ __launch_bounds__(256) void combine_k(const float* __restrict__ OP0,
                                                 const float* __restrict__ OP1,
                                                 const float* __restrict__ ML,
                                                 float* __restrict__ ctx) {
  int idx = blockIdx.x * 256 + threadIdx.x;  // 32*2048*16
  int row = idx >> 4;                        // bh*T + t
  int c4 = (idx & 15) * 4;
  float linv = 1.0f / (ML[(size_t)row] + ML[(size_t)32 * Tc + row]);
  float4 v0 = *(const float4*)(OP0 + (size_t)row * 64 + c4);
  float4 v1 = *(const float4*)(OP1 + (size_t)row * 64 + c4);
  float4 o;
  o.x = (v0.x + v1.x) * linv;
  o.y = (v0.y + v1.y) * linv;
  o.z = (v0.z + v1.z) * linv;
  o.w = (v0.w + v1.w) * linv;
  *(float4*)(ctx + (size_t)row * 64 + c4) = o;
}

// ---------------- prompt double softmax over t ------------------------------
__global__ __launch_bounds__(256) void prompt_softmax_k(float* __restrict__ SP,
                                                        const float* __restrict__ pr1,
                                                        const float* __restrict__ pr2) {
  __shared__ float sm[4];
  int row = blockIdx.x;          // bh*32 + p
  int bh = row >> 5, p = row & 31, b = bh >> 4;
  const float* prior = (p < 16 ? pr1 : pr2) + (size_t)b * Tc;
  float* s = SP + (size_t)row * Tc;
  int tid = threadIdx.x;
  float v[8], pw[8];
  #pragma unroll
  for (int i = 0; i < 8; ++i) { int t = tid + i * 256; v[i] = s[t]; pw[i] = prior[t]; }
  float mx = -INFINITY;
  #pragma unroll
  for (int i = 0; i < 8; ++i) mx = fmaxf(mx, v[i]);
  mx = bredM(mx, sm);
  float sum = 0.f;
  #pragma unroll
  for (int i = 0; i < 8; ++i) { v[i] = __expf(v[i] - mx); sum += v[i]; }
  sum = bredS(sum, sm);
  float inv = 1.0f / sum;
  float mx2 = -INFINITY;
  #pragma unroll
  for (int i = 0; i < 8; ++i) { v[i] = v[i] * inv * pw[i]; mx2 = fmaxf(mx2, v[i]); }
  mx2 = bredM(mx2, sm);
  float sum2 = 0.f;
  #pragma unroll
  for (int i = 0; i < 8; ++i) { v[i] = __expf(v[i] - mx2); sum2 += v[i]; }
  sum2 = bredS(sum2, sm);
  float inv2 = 1.0f / sum2;
  #pragma unroll
  for (int i = 0; i < 8; ++i) s[tid + i * 256] = v[i] * inv2;
}

// ---------------- p_v partials: PVP[ts][bh][32][64] = PA-chunk @ ctx-chunk --
__global__ __launch_bounds__(256) void pv_partial_k(const float* __restrict__ PA,
                                                    const float* __restrict__ ctx,
                                                    float* __restrict__ PVP) {
  __shared__ float pal[32][128];
  const int bh = blockIdx.x, ts = blockIdx.y;
  const int tid = threadIdx.x;
  const int t0 = ts * 128;
  const float* pabase = PA + (size_t)bh * 32 * Tc;

  #pragma unroll
  for (int i = 0; i < 4; ++i) {
    int e = tid + i * 256;
    int p = e >> 5, c4 = e & 31;
    *(float4*)&pal[p][c4 * 4] = *(const float4*)&pabase[(size_t)p * Tc + t0 + c4 * 4];
  }
  __syncthreads();

  const int d4 = tid & 15, p0 = tid >> 4;
  const float* cb = ctx + ((size_t)bh * Tc + t0) * 64 + d4 * 4;
  float4 a0 = make_float4(0.f, 0.f, 0.f, 0.f);
  float4 a1 = make_float4(0.f, 0.f, 0.f, 0.f);
  for (int tt = 0; tt < 128; ++tt) {
    float4 v = *(const float4*)(cb + (size_t)tt * 64);
    float w0 = pal[p0][tt], w1 = pal[p0 + 16][tt];
    a0.x += w0 * v.x; a0.y += w0 * v.y; a0.z += w0 * v.z; a0.w += w0 * v.w;
    a1.x += w1 * v.x; a1.y += w1 * v.y; a1.z += w1 * v.z; a1.w += w1 * v.w;
  }
  float* o = PVP + (((size_t)ts * 32 + bh) * 32) * 64 + d4 * 4;
  *(float4*)(o + (size_t)p0 * 64) = a0;
  *(float4*)(o + (size_t)(p0 + 16) * 64) = a1;
}

// ---------------- residual + LN (main path) ---------------------------------
__global__ __launch_bounds__(256) void resln_k(const float* __restrict__ x,
                                               const float* __restrict__ ctx,
                                               const float* __restrict__ g,
                                               const float* __restrict__ be,
                                               float* __restrict__ res,
                                               u16* __restrict__ lnout) {
  __shared__ float sm[4];
  int row = blockIdx.x;            // 0..4095
  int b = row >> 11, t = row & 2047;
  int tid = threadIdx.x, c4 = tid * 4;
  int h = c4 >> 6, d = c4 & 63;
  float4 xv = *(const float4*)(x + (size_t)row * Dc + c4);
  float4 cv = *(const float4*)(ctx + (((size_t)(b * Hc + h) * Tc + t) << 6) + d);
  float r0 = xv.x + cv.x, r1 = xv.y + cv.y, r2 = xv.z + cv.z, r3 = xv.w + cv.w;
  float4 rr; rr.x = r0; rr.y = r1; rr.z = r2; rr.w = r3;
  *(float4*)(res + (size_t)row * Dc + c4) = rr;
  float s = bredS(r0 + r1 + r2 + r3, sm);
  float sq = bredS(r0 * r0 + r1 * r1 + r2 * r2 + r3 * r3, sm);
  float mu = s * (1.0f / Dc);
  float var = sq * (1.0f / Dc) - mu * mu;
  float rs = rsqrtf(var + 1e-6f);
  ushort4 o;
  o.x = (u16)bfr((r0 - mu) * rs * g[c4 + 0] + be[c4 + 0]);
  o.y = (u16)bfr((r1 - mu) * rs * g[c4 + 1] + be[c4 + 1]);
  o.z = (u16)bfr((r2 - mu) * rs * g[c4 + 2] + be[c4 + 2]);
  o.w = (u16)bfr((r3 - mu) * rs * g[c4 + 3] + be[c4 + 3]);
  *(ushort4*)(lnout + (size_t)row * Dc + c4) = o;
}

// ---------------- prompt merge (PVP reduce inline) + residual + LN ----------
__global__ __launch_bounds__(256) void promptln_k(const float* __restrict__ PVP,
                                                  const float* __restrict__ p1,
                                                  const float* __restrict__ p2,
                                                  const float* __restrict__ g,
                                                  const float* __restrict__ be,
                                                  float* __restrict__ PMLN) {
  __shared__ float sm[4];
  int row = blockIdx.x;            // 0..63 : b = row>>5, j = row&31
  int b = row >> 5, j = row & 31;
  int tid = threadIdx.x, c4 = tid * 4;
  int h = c4 >> 6, d = c4 & 63;
  int bh = b * Hc + h;
  const float* pr = (j < 16) ? (p1 + (size_t)(b * 16 + j) * Dc + c4)
                             : (p2 + (size_t)(b * 16 + j - 16) * Dc + c4);
  // inline reduce over 16 t-chunks of PVP
  float4 pv4 = make_float4(0.f, 0.f, 0.f, 0.f);
  #pragma unroll
  for (int ts = 0; ts < 16; ++ts) {
    float4 v = *(const float4*)(PVP + (((size_t)ts * 32 + bh) * 32 + j) * 64 + d);
    pv4.x += v.x; pv4.y += v.y; pv4.z += v.z; pv4.w += v.w;
  }
  float4 pp4 = *(const float4*)pr;
  float r0 = pv4.x + pp4.x, r1 = pv4.y + pp4.y, r2 = pv4.z + pp4.z, r3 = pv4.w + pp4.w;
  float s = bredS(r0 + r1 + r2 + r3, sm);
  float sq = bredS(r0 * r0 + r1 * r1 + r2 * r2 + r3 * r3, sm);
  float mu = s * (1.0f / Dc);
  float var = sq * (1.0f / Dc) - mu * mu;
  float rs = rsqrtf(var + 1e-6f);
  float4 o;
  o.x = (r0 - mu) * rs * g[c4 + 0] + be[c4 + 0];
  o.y = (r1 - mu) * rs * g[c4 + 1] + be[c4 + 1];
  o.z = (r2 - mu) * rs * g[c4 + 2] + be[c4 + 2];
  o.w = (r3 - mu) * rs * g[c4 + 3] + be[c4 + 3];
  *(float4*)(PMLN + (size_t)row * Dc + c4) = o;
}

// ---------------- prompt FFN, split-K partials ------------------------------
__global__ __launch_bounds__(256) void pffn_partial_k(const float* __restrict__ PMLN,
                                                      const float* __restrict__ Wp1,
                                                      const float* __restrict__ Wp2,
                                                      float* __restrict__ PB) {
  __shared__ float pm[32][32];
  const int tid = threadIdx.x;
  const int ks = blockIdx.x, ct = blockIdx.y, s = blockIdx.z;
  const int c = ct * 256 + tid;
  const int k0 = ks * 32;
  const float* W = s ? Wp2 : Wp1;

  #pragma unroll
  for (int i = 0; i < 4; ++i) {
    int e = tid + i * 256;
    int r = e >> 5, kk = e & 31;
    int grow = (r >> 4) * 32 + s * 16 + (r & 15);
    pm[r][kk] = PMLN[(size_t)grow * Dc + k0 + kk];
  }
  __syncthreads();

  float acc[32];
  #pragma unroll
  for (int r = 0; r < 32; ++r) acc[r] = 0.f;
  for (int kk = 0; kk < 32; ++kk) {
    float w = W[(size_t)(k0 + kk) * Dc + c];
    #pragma unroll
    for (int r = 0; r < 32; ++r) acc[r] += pm[r][kk] * w;
  }

  float* pb = PB + (((size_t)ks * 2 + s) * 32) * Dc + c;
  #pragma unroll
  for (int r = 0; r < 32; ++r) pb[(size_t)r * Dc] = acc[r];
}

__global__ __launch_bounds__(256) void pffn_reduce_k(const float* __restrict__ PB,
                                                     const float* __restrict__ bp1,
                                                     const float* __restrict__ bp2,
                                                     float* __restrict__ out) {
  int e = blockIdx.x * 256 + threadIdx.x;   // 0..65535
  int s = e >> 15, rem = e & 32767;
  int r = rem >> 10, c = rem & 1023;
  float sum = 0.f;
  const float* pb = PB + ((size_t)s * 32 + r) * Dc + c;
  #pragma unroll
  for (int ks = 0; ks < 32; ++ks) sum += pb[(size_t)ks * 2 * 32 * Dc];
  const float* bp = s ? bp2 : bp1;
  out[(size_t)Mc * Dc + (size_t)s * (32 * Dc) + (size_t)r * Dc + c] = geluf(sum + bp[c]);
}

// ============================================================================
extern "C" void kernel_launch(void* const* d_in, const int* in_sizes, int n_in,
                              void* d_out, int out_size, void* d_ws, size_t ws_size,
                              hipStream_t stream) {
  (void)in_sizes; (void)n_in; (void)out_size; (void)ws_size;
  const float* x   = (const float*)d_in[0];
  const float* p1  = (const float*)d_in[1];
  const float* p2  = (const float*)d_in[2];
  const float* pr1 = (const float*)d_in[3];
  const float* pr2 = (const float*)d_in[4];
  const float* msk = (const float*)d_in[5];
  const float* Wq  = (const float*)d_in[6];
  const float* bq  = (const float*)d_in[7];
  const float* Wk  = (const float*)d_in[8];
  const float* bk  = (const float*)d_in[9];
  const float* Wv  = (const float*)d_in[10];
  const float* bv  = (const float*)d_in[11];
  const float* g2  = (const float*)d_in[12];
  const float* be2 = (const float*)d_in[13];
  const float* W1  = (const float*)d_in[14];
  const float* b1  = (const float*)d_in[15];
  const float* W2  = (const float*)d_in[16];
  const float* b2  = (const float*)d_in[17];
  const float* Wp1 = (const float*)d_in[18];
  const float* bp1 = (const float*)d_in[19];
  const float* Wp2 = (const float*)d_in[20];
  const float* bp2 = (const float*)d_in[21];

  char* ws = (char*)d_ws;
  size_t off = 0;
  auto alloc = [&](size_t bytes) {
    void* p = ws + off;
    off += (bytes + 255) & ~(size_t)255;
    return p;
  };
  u16* WQKVT = (u16*)alloc((size_t)3072 * 1024 * 2);
  u16* W1T   = (u16*)alloc((size_t)1024 * 1024 * 2);
  u16* W2T   = (u16*)alloc((size_t)1024 * 1024 * 2);
  u16* XB    = (u16*)alloc((size_t)Mc * Dc * 2);
  u16* QB    = (u16*)alloc((size_t)32 * Tc * 64 * 2);
  u16* KB    = (u16*)alloc((size_t)32 * TP * 64 * 2);
  u16* VB    = (u16*)alloc((size_t)32 * Tc * 64 * 2);
  u16* VT    = (u16*)alloc((size_t)32 * 64 * Tc * 2);
  float* CTX = (float*)alloc((size_t)32 * Tc * 64 * 4);
  float* SP  = (float*)alloc((size_t)32 * 32 * Tc * 4);
  float* RES = (float*)alloc((size_t)Mc * Dc * 4);
  float* PMLN = (float*)alloc((size_t)64 * Dc * 4);
  float* ML  = (float*)alloc((size_t)2 * 32 * Tc * 4);
  float* PVP = (float*)alloc((size_t)16 * 32 * 32 * 64 * 4);
  u16* LNOUT = XB;    // reuse: XB dead after QKV GEMM
  u16* H1    = VB;    // reuse: VB dead after V transpose
  float* PB  = SP;    // reuse: SP dead after pv
  float* OP0 = CTX;   // attn partial ks=0 (combined in place -> ctx)
  float* OP1 = RES;   // attn partial ks=1 (RES free until resln_k)

  float* outMain = (float*)d_out;

  // 1. weight transposes (bf16), single batched launch
  transpose_w5_k<<<dim3(32, 32, 5), 256, 0, stream>>>(Wq, Wk, Wv, W1, W2,
                                                      WQKVT, W1T, W2T);
  // 2. x -> bf16
  cvt_bf16_k<<<4096, 256, 0, stream>>>(x, XB, (Mc * Dc) / 4);
  // 3. QKV fused GEMM (N=3072), 128x128 tile, XCD swizzle (768 blocks)
  gemm128_k<0, 32><<<768, 256, 0, stream>>>(XB, WQKVT, bq, bk, bv, QB, KB, VB,
                                            nullptr, nullptr, nullptr);
  // 4. append prompt key rows
  kprompt_k<<<256, 256, 0, stream>>>(p1, p2, KB);
  // 5. V transpose per head
  vtrans_k<<<1024, 256, 0, stream>>>(VB, VT);
  // 6. flash attention (fixed-m, split-K x2, f32 partials, 2 blocks/CU)
  //    + fused prompt scores (ks==0 blocks)
  attn_k<<<1024, 256, 0, stream>>>(QB, KB, VT, msk, OP0, OP1, ML, SP);
  // 6b. combine partials -> ctx (in place over OP0)
  combine_k<<<4096, 256, 0, stream>>>(OP0, OP1, ML, CTX);
  // 7. prompt double-softmax (in place)
  prompt_softmax_k<<<1024, 256, 0, stream>>>(SP, pr1, pr2);
  // 8. p_v = p_a @ ctx : split-T partials (reduce fused into promptln)
  pv_partial_k<<<dim3(32, 16), 256, 0, stream>>>(SP, CTX, PVP);
  // 9. residual + LN (main)
  resln_k<<<4096, 256, 0, stream>>>(x, CTX, g2, be2, RES, LNOUT);
  // 10. prompt merge (inline PVP reduce) + LN
  promptln_k<<<64, 256, 0, stream>>>(PVP, p1, p2, g2, be2, PMLN);
  // 11. prompt FFN (split-K): partials then reduce -> d_out (p1_out, p2_out)
  pffn_partial_k<<<dim3(32, 4, 2), 256, 0, stream>>>(PMLN, Wp1, Wp2, PB);
  pffn_reduce_k<<<256, 256, 0, stream>>>(PB, bp1, bp2, outMain);
  // 12. FFN1: gelu(ln @ W1 + b1) -> bf16, 128x128 tile (256 blocks)
  gemm128_k<1, 32><<<256, 256, 0, stream>>>(LNOUT, W1T, b1, nullptr, nullptr,
                                            nullptr, nullptr, nullptr, H1,
                                            nullptr, nullptr);
  // 13. FFN2: h1 @ W2 + b2 + residual -> d_out (main), 128x128 tile
  gemm128_k<2, 32><<<256, 256, 0, stream>>>(H1, W2T, b2, nullptr, nullptr,
                                            nullptr, nullptr, nullptr, nullptr,
                                            outMain, RES);
}

// Round 18
// 216.807 us; speedup vs baseline: 1.0925x; 1.0330x over previous
//
#include <hip/hip_runtime.h>

#define DEV __device__ __forceinline__

typedef unsigned short u16;
typedef unsigned int   u32;
typedef short  s16x8  __attribute__((ext_vector_type(8)));
typedef float  f32x4  __attribute__((ext_vector_type(4)));
typedef float  f32x16 __attribute__((ext_vector_type(16)));

constexpr int Bc = 2, Hc = 16, Tc = 2048, Dc = 1024, HDc = 64, Mc = 4096;
constexpr int TP = Tc + 32;           // key rows incl. prompts
constexpr float SCALEc = 0.125f;      // 1/sqrt(64)
constexpr float LOG2E = 1.44269504088896340736f;
constexpr float SCALE2c = SCALEc * LOG2E;   // log2-domain scale
constexpr float NEGc = -1e30f;

typedef __attribute__((address_space(3))) void lds_void;
typedef const __attribute__((address_space(1))) void g_void;

DEV void gload16(const void* g, void* l) {
  __builtin_amdgcn_global_load_lds((g_void*)g, (lds_void*)l, 16, 0, 0);
}

DEV int swz(int r) { return (r & 7) ^ ((r >> 3) & 7); }   // LDS col-slot swizzle

DEV u32 bfr(float f) {                 // f32 -> bf16 bits, RNE
  u32 u = __float_as_uint(f);
  return (u + 0x7fffu + ((u >> 16) & 1u)) >> 16;
}
DEV u32 cvtpk(float a, float b) {      // packed f32x2 -> bf16x2 (RNE), 1 inst
  u32 r;
  asm("v_cvt_pk_bf16_f32 %0, %1, %2" : "=v"(r) : "v"(a), "v"(b));
  return r;
}
DEV s16x8 mk8(u32 w0, u32 w1, u32 w2, u32 w3) {
  union { u32 u[4]; s16x8 v; } x;
  x.u[0] = w0; x.u[1] = w1; x.u[2] = w2; x.u[3] = w3;
  return x.v;
}
DEV float geluf(float x) { return 0.5f * x * (1.0f + erff(x * 0.70710678118654752440f)); }

DEV float wredS(float v) {
  #pragma unroll
  for (int o = 32; o; o >>= 1) v += __shfl_xor(v, o);
  return v;
}
DEV float wredM(float v) {
  #pragma unroll
  for (int o = 32; o; o >>= 1) v = fmaxf(v, __shfl_xor(v, o));
  return v;
}
DEV float bredS(float v, float* sm) {   // 4-wave block
  v = wredS(v);
  __syncthreads();
  if ((threadIdx.x & 63) == 0) sm[threadIdx.x >> 6] = v;
  __syncthreads();
  return sm[0] + sm[1] + sm[2] + sm[3];
}
DEV float bredM(float v, float* sm) {
  v = wredM(v);
  __syncthreads();
  if ((threadIdx.x & 63) == 0) sm[threadIdx.x >> 6] = v;
  __syncthreads();
  return fmaxf(fmaxf(sm[0], sm[1]), fmaxf(sm[2], sm[3]));
}

// ------ batched weight transpose+convert (5 matrices) + x->bf16 (z==5) -----
__global__ __launch_bounds__(256) void transpose_w5_k(
    const float* __restrict__ Wq, const float* __restrict__ Wk,
    const float* __restrict__ Wv, const float* __restrict__ W1,
    const float* __restrict__ W2, const float* __restrict__ x,
    u16* __restrict__ WQKVT, u16* __restrict__ W1T, u16* __restrict__ W2T,
    u16* __restrict__ XB) {
  int z = blockIdx.z;
  if (z == 5) {   // x -> bf16: 1024 blocks x 256 thr x 4 float4 = Mc*Dc/4
    int base = (int)(blockIdx.y * 32 + blockIdx.x);
    int i0 = base * 1024 + (int)threadIdx.x;
    #pragma unroll
    for (int k = 0; k < 4; ++k) {
      int i = i0 + k * 256;
      float4 v = ((const float4*)x)[i];
      ushort4 u;
      u.x = (u16)bfr(v.x); u.y = (u16)bfr(v.y);
      u.z = (u16)bfr(v.z); u.w = (u16)bfr(v.w);
      ((ushort4*)XB)[i] = u;
    }
    return;
  }
  __shared__ float tile[32][33];
  int bx = blockIdx.x, by = blockIdx.y;
  const float* src = (z == 0) ? Wq : (z == 1) ? Wk : (z == 2) ? Wv
                    : (z == 3) ? W1 : W2;
  u16* dst = (z == 0) ? WQKVT
           : (z == 1) ? WQKVT + (size_t)1024 * 1024
           : (z == 2) ? WQKVT + (size_t)2 * 1024 * 1024
           : (z == 3) ? W1T : W2T;
  int tx = threadIdx.x & 31, ty = threadIdx.x >> 5;
  #pragma unroll
  for (int i = 0; i < 32; i += 8)
    tile[ty + i][tx] = src[(size_t)(by * 32 + ty + i) * Dc + bx * 32 + tx];
  __syncthreads();
  #pragma unroll
  for (int i = 0; i < 32; i += 8)
    dst[(size_t)(bx * 32 + ty + i) * Dc + by * 32 + tx] = (u16)bfr(tile[tx][ty + i]);
}

// ---------------- V transpose per head: vb[bh][t][d] -> vt[bh][d][t] --------
__global__ __launch_bounds__(256) void vtrans_k(const u16* __restrict__ vb,
                                                u16* __restrict__ vt) {
  __shared__ u16 tl[64][65];
  int bh = blockIdx.x >> 5, tc = blockIdx.x & 31;
  int d = threadIdx.x & 63, r = threadIdx.x >> 6;
  #pragma unroll
  for (int i = 0; i < 64; i += 4)
    tl[r + i][d] = vb[(((size_t)bh * Tc + tc * 64 + r + i) << 6) + d];
  __syncthreads();
  int t = threadIdx.x & 63, dd = threadIdx.x >> 6;
  #pragma unroll
  for (int i = 0; i < 64; i += 4)
    vt[((size_t)bh * 64 + dd + i) * Tc + tc * 64 + t] = tl[t][dd + i];
}

// ---------------- 128x128 bf16 MFMA GEMM ------------------------------------
// BM=BN=128 BK=32; 4 waves 2x2. LDS-staged C epilogue -> coalesced vector
// stores. 1D grid + XCD swizzle.
// MODE 0: QKV epilogue; MODE 1: bias+gelu->bf16; MODE 2: bias+residual->f32
template <int MODE, int NBX>
__global__ __launch_bounds__(256, 3) void gemm128_k(
    const u16* __restrict__ A, const u16* __restrict__ Bt,
    const float* __restrict__ bias0, const float* __restrict__ bias1,
    const float* __restrict__ bias2,
    u16* __restrict__ outQ, u16* __restrict__ outK, u16* __restrict__ outV,
    u16* __restrict__ outB, float* __restrict__ outF,
    const float* __restrict__ resid) {
  __shared__ __align__(16) u16 smem[17408];
  u16* as0 = smem;                 // [2][128*32]
  u16* bs0 = smem + 2 * 128 * 32;  // [2][128*32]
  const int tid = threadIdx.x, lane = tid & 63, wave = tid >> 6;
  const int wr = wave >> 1, wc = wave & 1;
  const int nwg = gridDim.x, bid = (int)blockIdx.x;
  const int wg = (bid & 7) * (nwg >> 3) + (bid >> 3);
  const int row0 = (wg % NBX) * 128, col0 = (wg / NBX) * 128;

  f32x4 zero4;
  #pragma unroll
  for (int r = 0; r < 4; ++r) zero4[r] = 0.f;
  f32x4 acc[4][4];
  #pragma unroll
  for (int i = 0; i < 4; ++i)
    #pragma unroll
    for (int j = 0; j < 4; ++j) acc[i][j] = zero4;

  auto stage = [&](int buf, int kt) {
    const int k0 = kt * 32;
    #pragma unroll
    for (int is = 0; is < 2; ++is) {
      int q = is * 256 + tid; int r = q >> 2, c = q & 3, g = c ^ ((r >> 1) & 3);
      gload16(A + (size_t)(row0 + r) * Dc + k0 + g * 8,
              as0 + (size_t)buf * 4096 + (is * 256 + wave * 64) * 8);
    }
    #pragma unroll
    for (int is = 0; is < 2; ++is) {
      int q = is * 256 + tid; int r = q >> 2, c = q & 3, g = c ^ ((r >> 1) & 3);
      gload16(Bt + (size_t)(col0 + r) * Dc + k0 + g * 8,
              bs0 + (size_t)buf * 4096 + (is * 256 + wave * 64) * 8);
    }
  };

  stage(0, 0);
  asm volatile("s_waitcnt vmcnt(0)" ::: "memory");
  __syncthreads();

  int cur = 0;
  for (int kt = 0; kt < 32; ++kt) {
    if (kt + 1 < 32) stage(cur ^ 1, kt + 1);
    s16x8 af[4], bfv[4];
    #pragma unroll
    for (int f = 0; f < 4; ++f) {
      int r = wr * 64 + f * 16 + (lane & 15);
      int c = (lane >> 4) ^ ((r >> 1) & 3);
      af[f] = *(const s16x8*)&as0[cur * 4096 + r * 32 + c * 8];
    }
    #pragma unroll
    for (int f = 0; f < 4; ++f) {
      int r = wc * 64 + f * 16 + (lane & 15);
      int c = (lane >> 4) ^ ((r >> 1) & 3);
      bfv[f] = *(const s16x8*)&bs0[cur * 4096 + r * 32 + c * 8];
    }
    __builtin_amdgcn_s_setprio(1);
    #pragma unroll
    for (int i = 0; i < 4; ++i)
      #pragma unroll
      for (int j = 0; j < 4; ++j)
        acc[i][j] = __builtin_amdgcn_mfma_f32_16x16x32_bf16(af[i], bfv[j], acc[i][j], 0, 0, 0);
    __builtin_amdgcn_s_setprio(0);
    __syncthreads();
    cur ^= 1;
  }

  if (MODE == 0 || MODE == 1) {
    const int CS = 136;
    u16* ct = smem;
    #pragma unroll
    for (int i = 0; i < 4; ++i)
      #pragma unroll
      for (int j = 0; j < 4; ++j)
        #pragma unroll
        for (int r = 0; r < 4; ++r) {
          int rl = wr * 64 + i * 16 + (lane >> 4) * 4 + r;
          int cl = wc * 64 + j * 16 + (lane & 15);
          float v = acc[i][j][r];
          if (MODE == 0) {
            int n = (col0 + cl) & 1023;
            int which = (col0 + cl) >> 10;
            v += (which == 0 ? bias0 : (which == 1 ? bias1 : bias2))[n];
          } else {
            v = geluf(v + bias0[col0 + cl]);
          }
          ct[rl * CS + cl] = (u16)bfr(v);
        }
    __syncthreads();
    #pragma unroll
    for (int it = 0; it < 16; ++it) {
      int linear = it * 256 + tid;
      int row = linear >> 5, c4 = (linear & 31) * 4;
      ushort4 val = *(const ushort4*)&ct[row * CS + c4];
      int grow = row0 + row;
      if (MODE == 1) {
        *(ushort4*)&outB[(size_t)grow * Dc + col0 + c4] = val;
      } else {
        int col = col0 + c4;
        int which = col >> 10, n = col & 1023;
        int hh = n >> 6, d = n & 63, bb = grow >> 11, t = grow & 2047;
        if (which == 0)
          *(ushort4*)&outQ[(((size_t)(bb * Hc + hh) * Tc + t) << 6) + d] = val;
        else if (which == 1)
          *(ushort4*)&outK[(((size_t)(bb * Hc + hh) * TP + t) << 6) + d] = val;
        else
          *(ushort4*)&outV[(((size_t)(bb * Hc + hh) * Tc + t) << 6) + d] = val;
      }
    }
  } else {
    const int CSF = 132;
    float* cf = (float*)smem;
    #pragma unroll
    for (int p = 0; p < 2; ++p) {
      if (wr == p) {
        #pragma unroll
        for (int i = 0; i < 4; ++i)
          #pragma unroll
          for (int j = 0; j < 4; ++j)
            #pragma unroll
            for (int r = 0; r < 4; ++r) {
              int rl = i * 16 + (lane >> 4) * 4 + r;
              int cl = wc * 64 + j * 16 + (lane & 15);
              cf[rl * CSF + cl] = acc[i][j][r];
            }
      }
      __syncthreads();
      #pragma unroll
      for (int it = 0; it < 8; ++it) {
        int linear = it * 256 + tid;
        int row = linear >> 5, c4 = (linear & 31) * 4;
        float4 v = *(const float4*)&cf[row * CSF + c4];
        int grow = row0 + p * 64 + row;
        int col = col0 + c4;
        float4 rr = *(const float4*)&resid[(size_t)grow * Dc + col];
        float4 o;
        o.x = v.x + bias0[col + 0] + rr.x;
        o.y = v.y + bias0[col + 1] + rr.y;
        o.z = v.z + bias0[col + 2] + rr.z;
        o.w = v.w + bias0[col + 3] + rr.w;
        *(float4*)&outF[(size_t)grow * Dc + col] = o;
      }
      __syncthreads();
    }
  }
}

// ---------------- flash attention, fixed-m, split-K x2, + prompt scores -----
// R13 proven config (f32 full-line partials, lb2). ks==0 blocks also compute
// prompt-key scores; prompt keys loaded DIRECTLY from p1/p2 (kprompt_k fused).
__global__ __launch_bounds__(256, 2) void attn_k(
    const u16* __restrict__ qb,   // [bh][T][64]
    const u16* __restrict__ kb,   // [bh][T+32][64]
    const u16* __restrict__ vt,   // [bh][64][T]
    const float* __restrict__ maskp,   // [B][T]
    const float* __restrict__ p1, const float* __restrict__ p2,
    float* __restrict__ OP0, float* __restrict__ OP1,
    float* __restrict__ ML,
    float* __restrict__ SP) {     // [bh][32][T]
  __shared__ __align__(16) u16 kls[2][64 * 64];
  __shared__ __align__(16) u16 vls[2][64 * 64];
  __shared__ __align__(16) u16 kpls[32 * 64];
  __shared__ float mls[1024];

  const int tid = threadIdx.x, lane = tid & 63, wave = tid >> 6;
  const int wg = ((int)blockIdx.x & 7) * 128 + ((int)blockIdx.x >> 3);
  const int ks = wg & 1, qt = (wg >> 1) & 15, bh = wg >> 5;
  const int b = bh >> 4;
  const int lo = lane & 31, h5 = lane >> 5;
  const size_t kbase = (size_t)bh * TP * 64;
  const size_t vbase = (size_t)bh * 64 * Tc;

  for (int i = tid; i < 1024; i += 256)
    mls[i] = (1.0f - maskp[(size_t)b * Tc + ks * 1024 + i]) * NEGc;

  if (ks == 0) {  // prompt keys: f32 -> bf16 in-register, swizzled kpls layout
    int r = tid >> 3, cg = tid & 7, g = cg ^ swz(r);
    int h = bh & 15;
    const float* src = (r < 16)
        ? (p1 + (size_t)(b * 16 + r) * Dc + h * 64 + g * 8)
        : (p2 + (size_t)(b * 16 + (r - 16)) * Dc + h * 64 + g * 8);
    float4 a = *(const float4*)src;
    float4 c = *(const float4*)(src + 4);
    *(s16x8*)&kpls[tid * 8] = mk8(cvtpk(a.x, a.y), cvtpk(a.z, a.w),
                                  cvtpk(c.x, c.y), cvtpk(c.z, c.w));
  }

  const int q0 = qt * 128 + wave * 32;
  s16x8 qf[4];
  #pragma unroll
  for (int kc = 0; kc < 4; ++kc)
    qf[kc] = *(const s16x8*)(qb + ((size_t)bh * Tc + q0 + lo) * 64 + kc * 16 + h5 * 8);

  auto stageKV = [&](int buf, int kt2) {
    #pragma unroll
    for (int is = 0; is < 2; ++is) {
      int q = is * 256 + tid; int r = q >> 3, c = q & 7, g = c ^ swz(r);
      gload16(kb + kbase + (size_t)(kt2 * 64 + r) * 64 + g * 8,
              &kls[buf][(is * 256 + wave * 64) * 8]);
      gload16(vt + vbase + (size_t)r * Tc + kt2 * 64 + g * 8,
              &vls[buf][(is * 256 + wave * 64) * 8]);
    }
  };

  stageKV(0, ks * 16);
  asm volatile("s_waitcnt vmcnt(0)" ::: "memory");
  __syncthreads();

  f32x16 zero16;
  #pragma unroll
  for (int r = 0; r < 16; ++r) zero16[r] = 0.f;
  f32x16 O0 = zero16, O1 = zero16, racc = zero16;

  int cur = 0;
  for (int kt = 0; kt < 16; ++kt) {
    if (kt + 1 < 16) stageKV(cur ^ 1, ks * 16 + kt + 1);

    #pragma unroll
    for (int c = 0; c < 2; ++c) {
      f32x16 s = zero16;
      __builtin_amdgcn_s_setprio(1);
      #pragma unroll
      for (int kc = 0; kc < 4; ++kc) {
        int r = c * 32 + lo;
        int ci = (kc * 2 + h5) ^ swz(r);
        s16x8 kf = *(const s16x8*)&kls[cur][r * 64 + ci * 8];
        s = __builtin_amdgcn_mfma_f32_32x32x16_bf16(kf, qf[kc], s, 0, 0, 0);
      }
      __builtin_amdgcn_s_setprio(0);

      float4 mq[4];
      #pragma unroll
      for (int g = 0; g < 4; ++g)
        mq[g] = *(const float4*)&mls[kt * 64 + c * 32 + 4 * h5 + 8 * g];

      float p[16];
      #pragma unroll
      for (int r = 0; r < 16; ++r) {
        float mv = (&mq[r >> 2].x)[r & 3];
        p[r] = exp2f(s[r] * SCALE2c + mv);
        racc[r] += p[r];
      }

      #pragma unroll
      for (int k1 = 0; k1 < 2; ++k1) {
        u32 w0 = cvtpk(p[8 * k1 + 0], p[8 * k1 + 1]);
        u32 w1 = cvtpk(p[8 * k1 + 2], p[8 * k1 + 3]);
        u32 w2 = cvtpk(p[8 * k1 + 4], p[8 * k1 + 5]);
        u32 w3 = cvtpk(p[8 * k1 + 6], p[8 * k1 + 7]);
        asm volatile("v_permlane32_swap_b32 %0, %1" : "+v"(w2), "+v"(w0));
        asm volatile("v_permlane32_swap_b32 %0, %1" : "+v"(w3), "+v"(w1));
        s16x8 pf = mk8(w0, w1, w2, w3);
        __builtin_amdgcn_s_setprio(1);
        #pragma unroll
        for (int db = 0; db < 2; ++db) {
          int d = db * 32 + lo;
          int ci = (c * 4 + k1 * 2 + h5) ^ swz(d);
          s16x8 vf = *(const s16x8*)&vls[cur][d * 64 + ci * 8];
          if (db == 0) O0 = __builtin_amdgcn_mfma_f32_32x32x16_bf16(pf, vf, O0, 0, 0, 0);
          else         O1 = __builtin_amdgcn_mfma_f32_32x32x16_bf16(pf, vf, O1, 0, 0, 0);
        }
        __builtin_amdgcn_s_setprio(0);
      }
    }
    __syncthreads();
    cur ^= 1;
  }

  // prompt scores (ks==0 blocks): S_p^T[pkey][q] * scale
  if (ks == 0) {
    f32x16 sp = zero16;
    #pragma unroll
    for (int kc = 0; kc < 4; ++kc) {
      int ci = (kc * 2 + h5) ^ swz(lo);
      s16x8 kf = *(const s16x8*)&kpls[lo * 64 + ci * 8];
      sp = __builtin_amdgcn_mfma_f32_32x32x16_bf16(kf, qf[kc], sp, 0, 0, 0);
    }
    #pragma unroll
    for (int r = 0; r < 16; ++r) {
      int pr = (r & 3) + 8 * (r >> 2) + 4 * h5;
      SP[((size_t)bh * 32 + pr) * Tc + q0 + lo] = sp[r] * SCALEc;
    }
  }

  float* dst = ks ? OP1 : OP0;
  #pragma unroll
  for (int r = 0; r < 16; ++r) {
    int row = q0 + (r & 3) + 8 * (r >> 2) + 4 * h5;
    dst[((size_t)bh * Tc + row) * 64 + lo]      = O0[r];
    dst[((size_t)bh * Tc + row) * 64 + 32 + lo] = O1[r];
  }
  float lt = 0.f;
  #pragma unroll
  for (int r = 0; r < 16; ++r) lt += racc[r];
  lt += __shfl_xor(lt, 32);
  if (lane < 32)
    ML[((size_t)ks * 32 + bh) * Tc + q0 + lo] = lt;
}

// ---------------- prompt double softmax over t ------------------------------
__global__ __launch_bounds__(256) void prompt_softmax_k(float* __restrict__ SP,
                                                        const float* __restrict__ pr1,
                                                        const float* __restrict__ pr2) {
  __shared__ float sm[4];
  int row = blockIdx.x;          // bh*32 + p
  int bh = row >> 5, p = row & 31, b = bh >> 4;
  const float* prior = (p < 16 ? pr1 : pr2) + (size_t)b * Tc;
  float* s = SP + (size_t)row * Tc;
  int tid = threadIdx.x;
  float v[8], pw[8];
  #pragma unroll
  for (int i = 0; i < 8; ++i) { int t = tid + i * 256; v[i] = s[t]; pw[i] = prior[t]; }
  float mx = -INFINITY;
  #pragma unroll
  for (int i = 0; i < 8; ++i) mx = fmaxf(mx, v[i]);
  mx = bredM(mx, sm);
  float sum = 0.f;
  #pragma unroll
  for (int i = 0; i < 8; ++i) { v[i] = __expf(v[i] - mx); sum += v[i]; }
  sum = bredS(sum, sm);
  float inv = 1.0f / sum;
  float mx2 = -INFINITY;
  #pragma unroll
  for (int i = 0; i < 8; ++i) { v[i] = v[i] * inv * pw[i]; mx2 = fmaxf(mx2, v[i]); }
  mx2 = bredM(mx2, sm);
  float sum2 = 0.f;
  #pragma unroll
  for (int i = 0; i < 8; ++i) { v[i] = __expf(v[i] - mx2); sum2 += v[i]; }
  sum2 = bredS(sum2, sm);
  float inv2 = 1.0f / sum2;
  #pragma unroll
  for (int i = 0; i < 8; ++i) s[tid + i * 256] = v[i] * inv2;
}

// -------- p_v partials with fused combine (block-private ctx slice) ---------
// Prologue: combine OP0+OP1 (lsm-normalized) -> ctx in place (ctx == OP0;
// each (bh,ts) block owns disjoint 128-row slice; same-thread same-address).
__global__ __launch_bounds__(256) void pv_partial_k(const float* __restrict__ PA,
                                                    float* __restrict__ ctx,   // == OP0
                                                    const float* __restrict__ OP1,
                                                    const float* __restrict__ ML,
                                                    float* __restrict__ PVP) {
  __shared__ float pal[32][128];
  __shared__ float lsm[128];
  const int bh = blockIdx.x, ts = blockIdx.y;
  const int tid = threadIdx.x;
  const int t0 = ts * 128;
  const float* pabase = PA + (size_t)bh * 32 * Tc;

  if (tid < 128) {
    size_t r = (size_t)bh * Tc + t0 + tid;
    lsm[tid] = 1.0f / (ML[r] + ML[(size_t)32 * Tc + r]);
  }
  __syncthreads();
  #pragma unroll
  for (int pp = 0; pp < 8; ++pp) {
    int idx = pp * 256 + tid;              // 0..2047 = 128 rows x 16 quads
    int rr = idx >> 4, c4 = (idx & 15) * 4;
    size_t row = (size_t)bh * Tc + t0 + rr;
    float4 v0 = *(const float4*)(ctx + row * 64 + c4);
    float4 v1 = *(const float4*)(OP1 + row * 64 + c4);
    float li = lsm[rr];
    float4 o;
    o.x = (v0.x + v1.x) * li;
    o.y = (v0.y + v1.y) * li;
    o.z = (v0.z + v1.z) * li;
    o.w = (v0.w + v1.w) * li;
    *(float4*)(ctx + row * 64 + c4) = o;
  }
  __syncthreads();

  #pragma unroll
  for (int i = 0; i < 4; ++i) {
    int e = tid + i * 256;
    int p = e >> 5, c4 = e & 31;
    *(float4*)&pal[p][c4 * 4] = *(const float4*)&pabase[(size_t)p * Tc + t0 + c4 * 4];
  }
  __syncthreads();

  const int d4 = tid & 15, p0 = tid >> 4;
  const float* cb = ctx + ((size_t)bh * Tc + t0) * 64 + d4 * 4;
  float4 a0 = make_float4(0.f, 0.f, 0.f, 0.f);
  float4 a1 = make_float4(0.f, 0.f, 0.f, 0.f);
  for (int tt = 0; tt < 128; ++tt) {
    float4 v = *(const float4*)(cb + (size_t)tt * 64);
    float w0 = pal[p0][tt], w1 = pal[p0 + 16][tt];
    a0.x += w0 * v.x; a0.y += w0 * v.y; a0.z += w0 * v.z; a0.w += w0 * v.w;
    a1.x += w1 * v.x; a1.y += w1 * v.y; a1.z += w1 * v.z; a1.w += w1 * v.w;
  }
  float* o = PVP + (((size_t)ts * 32 + bh) * 32) * 64 + d4 * 4;
  *(float4*)(o + (size_t)p0 * 64) = a0;
  *(float4*)(o + (size_t)(p0 + 16) * 64) = a1;
}

// ---------------- residual + LN (main path) ---------------------------------
__global__ __launch_bounds__(256) void resln_k(const float* __restrict__ x,
                                               const float* __restrict__ ctx,
                                               const float* __restrict__ g,
                                               const float* __restrict__ be,
                                               float* __restrict__ res,
                                               u16* __restrict__ lnout) {
  __shared__ float sm[4];
  int row = blockIdx.x;            // 0..4095
  int b = row >> 11, t = row & 2047;
  int tid = threadIdx.x, c4 = tid * 4;
  int h = c4 >> 6, d = c4 & 63;
  float4 xv = *(const float4*)(x + (size_t)row * Dc + c4);
  float4 cv = *(const float4*)(ctx + (((size_t)(b * Hc + h) * Tc + t) << 6) + d);
  float r0 = xv.x + cv.x, r1 = xv.y + cv.y, r2 = xv.z + cv.z, r3 = xv.w + cv.w;
  float4 rr; rr.x = r0; rr.y = r1; rr.z = r2; rr.w = r3;
  *(float4*)(res + (size_t)row * Dc + c4) = rr;
  float s = bredS(r0 + r1 + r2 + r3, sm);
  float sq = bredS(r0 * r0 + r1 * r1 + r2 * r2 + r3 * r3, sm);
  float mu = s * (1.0f / Dc);
  float var = sq * (1.0f / Dc) - mu * mu;
  float rs = rsqrtf(var + 1e-6f);
  ushort4 o;
  o.x = (u16)bfr((r0 - mu) * rs * g[c4 + 0] + be[c4 + 0]);
  o.y = (u16)bfr((r1 - mu) * rs * g[c4 + 1] + be[c4 + 1]);
  o.z = (u16)bfr((r2 - mu) * rs * g[c4 + 2] + be[c4 + 2]);
  o.w = (u16)bfr((r3 - mu) * rs * g[c4 + 3] + be[c4 + 3]);
  *(ushort4*)(lnout + (size_t)row * Dc + c4) = o;
}

// ---------------- prompt merge (PVP reduce inline) + residual + LN ----------
__global__ __launch_bounds__(256) void promptln_k(const float* __restrict__ PVP,
                                                  const float* __restrict__ p1,
                                                  const float* __restrict__ p2,
                                                  const float* __restrict__ g,
                                                  const float* __restrict__ be,
                                                  float* __restrict__ PMLN) {
  __shared__ float sm[4];
  int row = blockIdx.x;            // 0..63 : b = row>>5, j = row&31
  int b = row >> 5, j = row & 31;
  int tid = threadIdx.x, c4 = tid * 4;
  int h = c4 >> 6, d = c4 & 63;
  int bh = b * Hc + h;
  const float* pr = (j < 16) ? (p1 + (size_t)(b * 16 + j) * Dc + c4)
                             : (p2 + (size_t)(b * 16 + j - 16) * Dc + c4);
  float4 pv4 = make_float4(0.f, 0.f, 0.f, 0.f);
  #pragma unroll
  for (int ts = 0; ts < 16; ++ts) {
    float4 v = *(const float4*)(PVP + (((size_t)ts * 32 + bh) * 32 + j) * 64 + d);
    pv4.x += v.x; pv4.y += v.y; pv4.z += v.z; pv4.w += v.w;
  }
  float4 pp4 = *(const float4*)pr;
  float r0 = pv4.x + pp4.x, r1 = pv4.y + pp4.y, r2 = pv4.z + pp4.z, r3 = pv4.w + pp4.w;
  float s = bredS(r0 + r1 + r2 + r3, sm);
  float sq = bredS(r0 * r0 + r1 * r1 + r2 * r2 + r3 * r3, sm);
  float mu = s * (1.0f / Dc);
  float var = sq * (1.0f / Dc) - mu * mu;
  float rs = rsqrtf(var + 1e-6f);
  float4 o;
  o.x = (r0 - mu) * rs * g[c4 + 0] + be[c4 + 0];
  o.y = (r1 - mu) * rs * g[c4 + 1] + be[c4 + 1];
  o.z = (r2 - mu) * rs * g[c4 + 2] + be[c4 + 2];
  o.w = (r3 - mu) * rs * g[c4 + 3] + be[c4 + 3];
  *(float4*)(PMLN + (size_t)row * Dc + c4) = o;
}

// ---------------- prompt FFN, split-K partials ------------------------------
__global__ __launch_bounds__(256) void pffn_partial_k(const float* __restrict__ PMLN,
                                                      const float* __restrict__ Wp1,
                                                      const float* __restrict__ Wp2,
                                                      float* __restrict__ PB) {
  __shared__ float pm[32][32];
  const int tid = threadIdx.x;
  const int ks = blockIdx.x, ct = blockIdx.y, s = blockIdx.z;
  const int c = ct * 256 + tid;
  const int k0 = ks * 32;
  const float* W = s ? Wp2 : Wp1;

  #pragma unroll
  for (int i = 0; i < 4; ++i) {
    int e = tid + i * 256;
    int r = e >> 5, kk = e & 31;
    int grow = (r >> 4) * 32 + s * 16 + (r & 15);
    pm[r][kk] = PMLN[(size_t)grow * Dc + k0 + kk];
  }
  __syncthreads();

  float acc[32];
  #pragma unroll
  for (int r = 0; r < 32; ++r) acc[r] = 0.f;
  for (int kk = 0; kk < 32; ++kk) {
    float w = W[(size_t)(k0 + kk) * Dc + c];
    #pragma unroll
    for (int r = 0; r < 32; ++r) acc[r] += pm[r][kk] * w;
  }

  float* pb = PB + (((size_t)ks * 2 + s) * 32) * Dc + c;
  #pragma unroll
  for (int r = 0; r < 32; ++r) pb[(size_t)r * Dc] = acc[r];
}

__global__ __launch_bounds__(256) void pffn_reduce_k(const float* __restrict__ PB,
                                                     const float* __restrict__ bp1,
                                                     const float* __restrict__ bp2,
                                                     float* __restrict__ out) {
  int e = blockIdx.x * 256 + threadIdx.x;   // 0..65535
  int s = e >> 15, rem = e & 32767;
  int r = rem >> 10, c = rem & 1023;
  float sum = 0.f;
  const float* pb = PB + ((size_t)s * 32 + r) * Dc + c;
  #pragma unroll
  for (int ks = 0; ks < 32; ++ks) sum += pb[(size_t)ks * 2 * 32 * Dc];
  const float* bp = s ? bp2 : bp1;
  out[(size_t)Mc * Dc + (size_t)s * (32 * Dc) + (size_t)r * Dc + c] = geluf(sum + bp[c]);
}

// ============================================================================
extern "C" void kernel_launch(void* const* d_in, const int* in_sizes, int n_in,
                              void* d_out, int out_size, void* d_ws, size_t ws_size,
                              hipStream_t stream) {
  (void)in_sizes; (void)n_in; (void)out_size; (void)ws_size;
  const float* x   = (const float*)d_in[0];
  const float* p1  = (const float*)d_in[1];
  const float* p2  = (const float*)d_in[2];
  const float* pr1 = (const float*)d_in[3];
  const float* pr2 = (const float*)d_in[4];
  const float* msk = (const float*)d_in[5];
  const float* Wq  = (const float*)d_in[6];
  const float* bq  = (const float*)d_in[7];
  const float* Wk  = (const float*)d_in[8];
  const float* bk  = (const float*)d_in[9];
  const float* Wv  = (const float*)d_in[10];
  const float* bv  = (const float*)d_in[11];
  const float* g2  = (const float*)d_in[12];
  const float* be2 = (const float*)d_in[13];
  const float* W1  = (const float*)d_in[14];
  const float* b1  = (const float*)d_in[15];
  const float* W2  = (const float*)d_in[16];
  const float* b2  = (const float*)d_in[17];
  const float* Wp1 = (const float*)d_in[18];
  const float* bp1 = (const float*)d_in[19];
  const float* Wp2 = (const float*)d_in[20];
  const float* bp2 = (const float*)d_in[21];

  char* ws = (char*)d_ws;
  size_t off = 0;
  auto alloc = [&](size_t bytes) {
    void* p = ws + off;
    off += (bytes + 255) & ~(size_t)255;
    return p;
  };
  u16* WQKVT = (u16*)alloc((size_t)3072 * 1024 * 2);
  u16* W1T   = (u16*)alloc((size_t)1024 * 1024 * 2);
  u16* W2T   = (u16*)alloc((size_t)1024 * 1024 * 2);
  u16* XB    = (u16*)alloc((size_t)Mc * Dc * 2);
  u16* QB    = (u16*)alloc((size_t)32 * Tc * 64 * 2);
  u16* KB    = (u16*)alloc((size_t)32 * TP * 64 * 2);
  u16* VB    = (u16*)alloc((size_t)32 * Tc * 64 * 2);
  u16* VT    = (u16*)alloc((size_t)32 * 64 * Tc * 2);
  float* CTX = (float*)alloc((size_t)32 * Tc * 64 * 4);
  float* SP  = (float*)alloc((size_t)32 * 32 * Tc * 4);
  float* RES = (float*)alloc((size_t)Mc * Dc * 4);
  float* PMLN = (float*)alloc((size_t)64 * Dc * 4);
  float* ML  = (float*)alloc((size_t)2 * 32 * Tc * 4);
  float* PVP = (float*)alloc((size_t)16 * 32 * 32 * 64 * 4);
  u16* LNOUT = XB;    // reuse: XB dead after QKV GEMM
  u16* H1    = VB;    // reuse: VB dead after V transpose
  float* PB  = SP;    // reuse: SP dead after pv
  float* OP0 = CTX;   // attn partial ks=0 (combined in place -> ctx in pv)
  float* OP1 = RES;   // attn partial ks=1 (RES free until resln_k)

  float* outMain = (float*)d_out;

  // 1. weight transposes (bf16) + x->bf16, single batched launch
  transpose_w5_k<<<dim3(32, 32, 6), 256, 0, stream>>>(Wq, Wk, Wv, W1, W2, x,
                                                      WQKVT, W1T, W2T, XB);
  // 2. QKV fused GEMM (N=3072), 128x128 tile, XCD swizzle (768 blocks)
  gemm128_k<0, 32><<<768, 256, 0, stream>>>(XB, WQKVT, bq, bk, bv, QB, KB, VB,
                                            nullptr, nullptr, nullptr);
  // 3. V transpose per head
  vtrans_k<<<1024, 256, 0, stream>>>(VB, VT);
  // 4. flash attention (fixed-m, split-K x2, f32 partials, 2 blocks/CU)
  //    + fused prompt scores + fused prompt-key load (from p1/p2)
  attn_k<<<1024, 256, 0, stream>>>(QB, KB, VT, msk, p1, p2, OP0, OP1, ML, SP);
  // 5. prompt double-softmax (in place)
  prompt_softmax_k<<<1024, 256, 0, stream>>>(SP, pr1, pr2);
  // 6. p_v = p_a @ ctx : fused combine prologue + split-T partials
  pv_partial_k<<<dim3(32, 16), 256, 0, stream>>>(SP, OP0, OP1, ML, PVP);
  // 7. residual + LN (main); ctx materialized by pv_partial
  resln_k<<<4096, 256, 0, stream>>>(x, CTX, g2, be2, RES, LNOUT);
  // 8. prompt merge (inline PVP reduce) + LN
  promptln_k<<<64, 256, 0, stream>>>(PVP, p1, p2, g2, be2, PMLN);
  // 9. prompt FFN (split-K): partials then reduce -> d_out (p1_out, p2_out)
  pffn_partial_k<<<dim3(32, 4, 2), 256, 0, stream>>>(PMLN, Wp1, Wp2, PB);
  pffn_reduce_k<<<256, 256, 0, stream>>>(PB, bp1, bp2, outMain);
  // 10. FFN1: gelu(ln @ W1 + b1) -> bf16, 128x128 tile (256 blocks)
  gemm128_k<1, 32><<<256, 256, 0, stream>>>(LNOUT, W1T, b1, nullptr, nullptr,
                                            nullptr, nullptr, nullptr, H1,
                                            nullptr, nullptr);
  // 11. FFN2: h1 @ W2 + b2 + residual -> d_out (main), 128x128 tile
  gemm128_k<2, 32><<<256, 256, 0, stream>>>(H1, W2T, b2, nullptr, nullptr,
                                            nullptr, nullptr, nullptr, nullptr,
                                            outMain, RES);
}

// Round 19
// 212.642 us; speedup vs baseline: 1.1138x; 1.0196x over previous
//
#include <hip/hip_runtime.h>

#define DEV __device__ __forceinline__

typedef unsigned short u16;
typedef unsigned int   u32;
typedef short  s16x8  __attribute__((ext_vector_type(8)));
typedef float  f32x4  __attribute__((ext_vector_type(4)));
typedef float  f32x16 __attribute__((ext_vector_type(16)));

constexpr int Bc = 2, Hc = 16, Tc = 2048, Dc = 1024, HDc = 64, Mc = 4096;
constexpr int TP = Tc + 32;           // key rows incl. prompts
constexpr float SCALEc = 0.125f;      // 1/sqrt(64)
constexpr float LOG2E = 1.44269504088896340736f;
constexpr float SCALE2c = SCALEc * LOG2E;   // log2-domain scale
constexpr float NEGc = -1e30f;

typedef __attribute__((address_space(3))) void lds_void;
typedef const __attribute__((address_space(1))) void g_void;

DEV void gload16(const void* g, void* l) {
  __builtin_amdgcn_global_load_lds((g_void*)g, (lds_void*)l, 16, 0, 0);
}

DEV int swz(int r) { return (r & 7) ^ ((r >> 3) & 7); }   // LDS col-slot swizzle

DEV u32 bfr(float f) {                 // f32 -> bf16 bits, RNE
  u32 u = __float_as_uint(f);
  return (u + 0x7fffu + ((u >> 16) & 1u)) >> 16;
}
DEV u32 cvtpk(float a, float b) {      // packed f32x2 -> bf16x2 (RNE), 1 inst
  u32 r;
  asm("v_cvt_pk_bf16_f32 %0, %1, %2" : "=v"(r) : "v"(a), "v"(b));
  return r;
}
DEV s16x8 mk8(u32 w0, u32 w1, u32 w2, u32 w3) {
  union { u32 u[4]; s16x8 v; } x;
  x.u[0] = w0; x.u[1] = w1; x.u[2] = w2; x.u[3] = w3;
  return x.v;
}
DEV float geluf(float x) { return 0.5f * x * (1.0f + erff(x * 0.70710678118654752440f)); }

DEV float wredS(float v) {
  #pragma unroll
  for (int o = 32; o; o >>= 1) v += __shfl_xor(v, o);
  return v;
}
DEV float wredM(float v) {
  #pragma unroll
  for (int o = 32; o; o >>= 1) v = fmaxf(v, __shfl_xor(v, o));
  return v;
}
DEV float bredS(float v, float* sm) {   // 4-wave block
  v = wredS(v);
  __syncthreads();
  if ((threadIdx.x & 63) == 0) sm[threadIdx.x >> 6] = v;
  __syncthreads();
  return sm[0] + sm[1] + sm[2] + sm[3];
}
DEV float bredM(float v, float* sm) {
  v = wredM(v);
  __syncthreads();
  if ((threadIdx.x & 63) == 0) sm[threadIdx.x >> 6] = v;
  __syncthreads();
  return fmaxf(fmaxf(sm[0], sm[1]), fmaxf(sm[2], sm[3]));
}

// ------ batched weight transpose+convert (5 matrices) + x->bf16 (z==5) -----
__global__ __launch_bounds__(256) void transpose_w5_k(
    const float* __restrict__ Wq, const float* __restrict__ Wk,
    const float* __restrict__ Wv, const float* __restrict__ W1,
    const float* __restrict__ W2, const float* __restrict__ x,
    u16* __restrict__ WQKVT, u16* __restrict__ W1T, u16* __restrict__ W2T,
    u16* __restrict__ XB) {
  int z = blockIdx.z;
  if (z == 5) {   // x -> bf16: 1024 blocks x 256 thr x 4 float4 = Mc*Dc/4
    int base = (int)(blockIdx.y * 32 + blockIdx.x);
    int i0 = base * 1024 + (int)threadIdx.x;
    #pragma unroll
    for (int k = 0; k < 4; ++k) {
      int i = i0 + k * 256;
      float4 v = ((const float4*)x)[i];
      ushort4 u;
      u.x = (u16)bfr(v.x); u.y = (u16)bfr(v.y);
      u.z = (u16)bfr(v.z); u.w = (u16)bfr(v.w);
      ((ushort4*)XB)[i] = u;
    }
    return;
  }
  __shared__ float tile[32][33];
  int bx = blockIdx.x, by = blockIdx.y;
  const float* src = (z == 0) ? Wq : (z == 1) ? Wk : (z == 2) ? Wv
                    : (z == 3) ? W1 : W2;
  u16* dst = (z == 0) ? WQKVT
           : (z == 1) ? WQKVT + (size_t)1024 * 1024
           : (z == 2) ? WQKVT + (size_t)2 * 1024 * 1024
           : (z == 3) ? W1T : W2T;
  int tx = threadIdx.x & 31, ty = threadIdx.x >> 5;
  #pragma unroll
  for (int i = 0; i < 32; i += 8)
    tile[ty + i][tx] = src[(size_t)(by * 32 + ty + i) * Dc + bx * 32 + tx];
  __syncthreads();
  #pragma unroll
  for (int i = 0; i < 32; i += 8)
    dst[(size_t)(bx * 32 + ty + i) * Dc + by * 32 + tx] = (u16)bfr(tile[tx][ty + i]);
}

// ---------------- 128x128 bf16 MFMA GEMM ------------------------------------
// BM=BN=128 BK=32; 4 waves 2x2. LDS-staged C epilogue -> coalesced vector
// stores. 1D grid + XCD swizzle. Segment (`which`) is block-uniform: tiles
// (128-aligned) never straddle a 1024-aligned Q/K/V segment boundary.
// MODE 0: QKV epilogue (V written TRANSPOSED to vt[bh][d][t], CSV=129 stride:
//   t-stride 258 dwords == 2 mod 32 -> 2-way (free) transposed LDS reads);
// MODE 1: bias+gelu->bf16; MODE 2: bias+residual->f32
template <int MODE, int NBX>
__global__ __launch_bounds__(256, 3) void gemm128_k(
    const u16* __restrict__ A, const u16* __restrict__ Bt,
    const float* __restrict__ bias0, const float* __restrict__ bias1,
    const float* __restrict__ bias2,
    u16* __restrict__ outQ, u16* __restrict__ outK, u16* __restrict__ outVT,
    u16* __restrict__ outB, float* __restrict__ outF,
    const float* __restrict__ resid) {
  __shared__ __align__(16) u16 smem[17408];
  u16* as0 = smem;                 // [2][128*32]
  u16* bs0 = smem + 2 * 128 * 32;  // [2][128*32]
  const int tid = threadIdx.x, lane = tid & 63, wave = tid >> 6;
  const int wr = wave >> 1, wc = wave & 1;
  const int nwg = gridDim.x, bid = (int)blockIdx.x;
  const int wg = (bid & 7) * (nwg >> 3) + (bid >> 3);
  const int row0 = (wg % NBX) * 128, col0 = (wg / NBX) * 128;

  f32x4 zero4;
  #pragma unroll
  for (int r = 0; r < 4; ++r) zero4[r] = 0.f;
  f32x4 acc[4][4];
  #pragma unroll
  for (int i = 0; i < 4; ++i)
    #pragma unroll
    for (int j = 0; j < 4; ++j) acc[i][j] = zero4;

  auto stage = [&](int buf, int kt) {
    const int k0 = kt * 32;
    #pragma unroll
    for (int is = 0; is < 2; ++is) {
      int q = is * 256 + tid; int r = q >> 2, c = q & 3, g = c ^ ((r >> 1) & 3);
      gload16(A + (size_t)(row0 + r) * Dc + k0 + g * 8,
              as0 + (size_t)buf * 4096 + (is * 256 + wave * 64) * 8);
    }
    #pragma unroll
    for (int is = 0; is < 2; ++is) {
      int q = is * 256 + tid; int r = q >> 2, c = q & 3, g = c ^ ((r >> 1) & 3);
      gload16(Bt + (size_t)(col0 + r) * Dc + k0 + g * 8,
              bs0 + (size_t)buf * 4096 + (is * 256 + wave * 64) * 8);
    }
  };

  stage(0, 0);
  asm volatile("s_waitcnt vmcnt(0)" ::: "memory");
  __syncthreads();

  int cur = 0;
  for (int kt = 0; kt < 32; ++kt) {
    if (kt + 1 < 32) stage(cur ^ 1, kt + 1);
    s16x8 af[4], bfv[4];
    #pragma unroll
    for (int f = 0; f < 4; ++f) {
      int r = wr * 64 + f * 16 + (lane & 15);
      int c = (lane >> 4) ^ ((r >> 1) & 3);
      af[f] = *(const s16x8*)&as0[cur * 4096 + r * 32 + c * 8];
    }
    #pragma unroll
    for (int f = 0; f < 4; ++f) {
      int r = wc * 64 + f * 16 + (lane & 15);
      int c = (lane >> 4) ^ ((r >> 1) & 3);
      bfv[f] = *(const s16x8*)&bs0[cur * 4096 + r * 32 + c * 8];
    }
    __builtin_amdgcn_s_setprio(1);
    #pragma unroll
    for (int i = 0; i < 4; ++i)
      #pragma unroll
      for (int j = 0; j < 4; ++j)
        acc[i][j] = __builtin_amdgcn_mfma_f32_16x16x32_bf16(af[i], bfv[j], acc[i][j], 0, 0, 0);
    __builtin_amdgcn_s_setprio(0);
    __syncthreads();
    cur ^= 1;
  }

  if (MODE == 0) {
    const int which = col0 >> 10;          // block-uniform segment
    const float* bias = (which == 0) ? bias0 : (which == 1) ? bias1 : bias2;
    if (which == 2) {
      // ---- V: stage with CSV=129, write TRANSPOSED vt[bh][d][t] ----
      const int CSV = 129;
      u16* ct = smem;
      #pragma unroll
      for (int i = 0; i < 4; ++i)
        #pragma unroll
        for (int j = 0; j < 4; ++j)
          #pragma unroll
          for (int r = 0; r < 4; ++r) {
            int rl = wr * 64 + i * 16 + (lane >> 4) * 4 + r;
            int cl = wc * 64 + j * 16 + (lane & 15);
            float v = acc[i][j][r] + bias[(col0 + cl) & 1023];
            ct[rl * CSV + cl] = (u16)bfr(v);
          }
      __syncthreads();
      int bb = row0 >> 11, tbase = row0 & 2047;
      #pragma unroll
      for (int it = 0; it < 16; ++it) {
        int linear = it * 256 + tid;       // 4096 quads = 128 d x 32 t-quads
        int dcol = linear >> 5, q4 = linear & 31;
        int t = q4 * 4;
        int n = (col0 & 1023) + dcol;
        int hh = n >> 6, dd = n & 63;
        ushort4 val;
        val.x = ct[(t + 0) * CSV + dcol];
        val.y = ct[(t + 1) * CSV + dcol];
        val.z = ct[(t + 2) * CSV + dcol];
        val.w = ct[(t + 3) * CSV + dcol];
        *(ushort4*)&outVT[((size_t)(bb * Hc + hh) * 64 + dd) * Tc + tbase + t] = val;
      }
    } else {
      // ---- Q/K: row-major head-split writes (as before) ----
      const int CS = 136;
      u16* ct = smem;
      #pragma unroll
      for (int i = 0; i < 4; ++i)
        #pragma unroll
        for (int j = 0; j < 4; ++j)
          #pragma unroll
          for (int r = 0; r < 4; ++r) {
            int rl = wr * 64 + i * 16 + (lane >> 4) * 4 + r;
            int cl = wc * 64 + j * 16 + (lane & 15);
            float v = acc[i][j][r] + bias[(col0 + cl) & 1023];
            ct[rl * CS + cl] = (u16)bfr(v);
          }
      __syncthreads();
      #pragma unroll
      for (int it = 0; it < 16; ++it) {
        int linear = it * 256 + tid;
        int row = linear >> 5, c4 = (linear & 31) * 4;
        ushort4 val = *(const ushort4*)&ct[row * CS + c4];
        int grow = row0 + row;
        int col = col0 + c4;
        int n = col & 1023;
        int hh = n >> 6, d = n & 63, bb = grow >> 11, t = grow & 2047;
        if (which == 0)
          *(ushort4*)&outQ[(((size_t)(bb * Hc + hh) * Tc + t) << 6) + d] = val;
        else
          *(ushort4*)&outK[(((size_t)(bb * Hc + hh) * TP + t) << 6) + d] = val;
      }
    }
  } else if (MODE == 1) {
    const int CS = 136;
    u16* ct = smem;
    #pragma unroll
    for (int i = 0; i < 4; ++i)
      #pragma unroll
      for (int j = 0; j < 4; ++j)
        #pragma unroll
        for (int r = 0; r < 4; ++r) {
          int rl = wr * 64 + i * 16 + (lane >> 4) * 4 + r;
          int cl = wc * 64 + j * 16 + (lane & 15);
          float v = geluf(acc[i][j][r] + bias0[col0 + cl]);
          ct[rl * CS + cl] = (u16)bfr(v);
        }
    __syncthreads();
    #pragma unroll
    for (int it = 0; it < 16; ++it) {
      int linear = it * 256 + tid;
      int row = linear >> 5, c4 = (linear & 31) * 4;
      ushort4 val = *(const ushort4*)&ct[row * CS + c4];
      *(ushort4*)&outB[(size_t)(row0 + row) * Dc + col0 + c4] = val;
    }
  } else {
    const int CSF = 132;
    float* cf = (float*)smem;
    #pragma unroll
    for (int p = 0; p < 2; ++p) {
      if (wr == p) {
        #pragma unroll
        for (int i = 0; i < 4; ++i)
          #pragma unroll
          for (int j = 0; j < 4; ++j)
            #pragma unroll
            for (int r = 0; r < 4; ++r) {
              int rl = i * 16 + (lane >> 4) * 4 + r;
              int cl = wc * 64 + j * 16 + (lane & 15);
              cf[rl * CSF + cl] = acc[i][j][r];
            }
      }
      __syncthreads();
      #pragma unroll
      for (int it = 0; it < 8; ++it) {
        int linear = it * 256 + tid;
        int row = linear >> 5, c4 = (linear & 31) * 4;
        float4 v = *(const float4*)&cf[row * CSF + c4];
        int grow = row0 + p * 64 + row;
        int col = col0 + c4;
        float4 rr = *(const float4*)&resid[(size_t)grow * Dc + col];
        float4 o;
        o.x = v.x + bias0[col + 0] + rr.x;
        o.y = v.y + bias0[col + 1] + rr.y;
        o.z = v.z + bias0[col + 2] + rr.z;
        o.w = v.w + bias0[col + 3] + rr.w;
        *(float4*)&outF[(size_t)grow * Dc + col] = o;
      }
      __syncthreads();
    }
  }
}

// ---------------- flash attention, fixed-m, split-K x2, + prompt scores -----
// R13 proven config (f32 full-line partials, lb2). ks==0 blocks also compute
// prompt-key scores; prompt keys loaded DIRECTLY from p1/p2.
__global__ __launch_bounds__(256, 2) void attn_k(
    const u16* __restrict__ qb,   // [bh][T][64]
    const u16* __restrict__ kb,   // [bh][T+32][64]
    const u16* __restrict__ vt,   // [bh][64][T]
    const float* __restrict__ maskp,   // [B][T]
    const float* __restrict__ p1, const float* __restrict__ p2,
    float* __restrict__ OP0, float* __restrict__ OP1,
    float* __restrict__ ML,
    float* __restrict__ SP) {     // [bh][32][T]
  __shared__ __align__(16) u16 kls[2][64 * 64];
  __shared__ __align__(16) u16 vls[2][64 * 64];
  __shared__ __align__(16) u16 kpls[32 * 64];
  __shared__ float mls[1024];

  const int tid = threadIdx.x, lane = tid & 63, wave = tid >> 6;
  const int wg = ((int)blockIdx.x & 7) * 128 + ((int)blockIdx.x >> 3);
  const int ks = wg & 1, qt = (wg >> 1) & 15, bh = wg >> 5;
  const int b = bh >> 4;
  const int lo = lane & 31, h5 = lane >> 5;
  const size_t kbase = (size_t)bh * TP * 64;
  const size_t vbase = (size_t)bh * 64 * Tc;

  for (int i = tid; i < 1024; i += 256)
    mls[i] = (1.0f - maskp[(size_t)b * Tc + ks * 1024 + i]) * NEGc;

  if (ks == 0) {  // prompt keys: f32 -> bf16 in-register, swizzled kpls layout
    int r = tid >> 3, cg = tid & 7, g = cg ^ swz(r);
    int h = bh & 15;
    const float* src = (r < 16)
        ? (p1 + (size_t)(b * 16 + r) * Dc + h * 64 + g * 8)
        : (p2 + (size_t)(b * 16 + (r - 16)) * Dc + h * 64 + g * 8);
    float4 a = *(const float4*)src;
    float4 c = *(const float4*)(src + 4);
    *(s16x8*)&kpls[tid * 8] = mk8(cvtpk(a.x, a.y), cvtpk(a.z, a.w),
                                  cvtpk(c.x, c.y), cvtpk(c.z, c.w));
  }

  const int q0 = qt * 128 + wave * 32;
  s16x8 qf[4];
  #pragma unroll
  for (int kc = 0; kc < 4; ++kc)
    qf[kc] = *(const s16x8*)(qb + ((size_t)bh * Tc + q0 + lo) * 64 + kc * 16 + h5 * 8);

  auto stageKV = [&](int buf, int kt2) {
    #pragma unroll
    for (int is = 0; is < 2; ++is) {
      int q = is * 256 + tid; int r = q >> 3, c = q & 7, g = c ^ swz(r);
      gload16(kb + kbase + (size_t)(kt2 * 64 + r) * 64 + g * 8,
              &kls[buf][(is * 256 + wave * 64) * 8]);
      gload16(vt + vbase + (size_t)r * Tc + kt2 * 64 + g * 8,
              &vls[buf][(is * 256 + wave * 64) * 8]);
    }
  };

  stageKV(0, ks * 16);
  asm volatile("s_waitcnt vmcnt(0)" ::: "memory");
  __syncthreads();

  f32x16 zero16;
  #pragma unroll
  for (int r = 0; r < 16; ++r) zero16[r] = 0.f;
  f32x16 O0 = zero16, O1 = zero16, racc = zero16;

  int cur = 0;
  for (int kt = 0; kt < 16; ++kt) {
    if (kt + 1 < 16) stageKV(cur ^ 1, ks * 16 + kt + 1);

    #pragma unroll
    for (int c = 0; c < 2; ++c) {
      f32x16 s = zero16;
      __builtin_amdgcn_s_setprio(1);
      #pragma unroll
      for (int kc = 0; kc < 4; ++kc) {
        int r = c * 32 + lo;
        int ci = (kc * 2 + h5) ^ swz(r);
        s16x8 kf = *(const s16x8*)&kls[cur][r * 64 + ci * 8];
        s = __builtin_amdgcn_mfma_f32_32x32x16_bf16(kf, qf[kc], s, 0, 0, 0);
      }
      __builtin_amdgcn_s_setprio(0);

      float4 mq[4];
      #pragma unroll
      for (int g = 0; g < 4; ++g)
        mq[g] = *(const float4*)&mls[kt * 64 + c * 32 + 4 * h5 + 8 * g];

      float p[16];
      #pragma unroll
      for (int r = 0; r < 16; ++r) {
        float mv = (&mq[r >> 2].x)[r & 3];
        p[r] = exp2f(s[r] * SCALE2c + mv);
        racc[r] += p[r];
      }

      #pragma unroll
      for (int k1 = 0; k1 < 2; ++k1) {
        u32 w0 = cvtpk(p[8 * k1 + 0], p[8 * k1 + 1]);
        u32 w1 = cvtpk(p[8 * k1 + 2], p[8 * k1 + 3]);
        u32 w2 = cvtpk(p[8 * k1 + 4], p[8 * k1 + 5]);
        u32 w3 = cvtpk(p[8 * k1 + 6], p[8 * k1 + 7]);
        asm volatile("v_permlane32_swap_b32 %0, %1" : "+v"(w2), "+v"(w0));
        asm volatile("v_permlane32_swap_b32 %0, %1" : "+v"(w3), "+v"(w1));
        s16x8 pf = mk8(w0, w1, w2, w3);
        __builtin_amdgcn_s_setprio(1);
        #pragma unroll
        for (int db = 0; db < 2; ++db) {
          int d = db * 32 + lo;
          int ci = (c * 4 + k1 * 2 + h5) ^ swz(d);
          s16x8 vf = *(const s16x8*)&vls[cur][d * 64 + ci * 8];
          if (db == 0) O0 = __builtin_amdgcn_mfma_f32_32x32x16_bf16(pf, vf, O0, 0, 0, 0);
          else         O1 = __builtin_amdgcn_mfma_f32_32x32x16_bf16(pf, vf, O1, 0, 0, 0);
        }
        __builtin_amdgcn_s_setprio(0);
      }
    }
    __syncthreads();
    cur ^= 1;
  }

  // prompt scores (ks==0 blocks): S_p^T[pkey][q] * scale
  if (ks == 0) {
    f32x16 sp = zero16;
    #pragma unroll
    for (int kc = 0; kc < 4; ++kc) {
      int ci = (kc * 2 + h5) ^ swz(lo);
      s16x8 kf = *(const s16x8*)&kpls[lo * 64 + ci * 8];
      sp = __builtin_amdgcn_mfma_f32_32x32x16_bf16(kf, qf[kc], sp, 0, 0, 0);
    }
    #pragma unroll
    for (int r = 0; r < 16; ++r) {
      int pr = (r & 3) + 8 * (r >> 2) + 4 * h5;
      SP[((size_t)bh * 32 + pr) * Tc + q0 + lo] = sp[r] * SCALEc;
    }
  }

  float* dst = ks ? OP1 : OP0;
  #pragma unroll
  for (int r = 0; r < 16; ++r) {
    int row = q0 + (r & 3) + 8 * (r >> 2) + 4 * h5;
    dst[((size_t)bh * Tc + row) * 64 + lo]      = O0[r];
    dst[((size_t)bh * Tc + row) * 64 + 32 + lo] = O1[r];
  }
  float lt = 0.f;
  #pragma unroll
  for (int r = 0; r < 16; ++r) lt += racc[r];
  lt += __shfl_xor(lt, 32);
  if (lane < 32)
    ML[((size_t)ks * 32 + bh) * Tc + q0 + lo] = lt;
}

// ---------------- prompt double softmax over t ------------------------------
__global__ __launch_bounds__(256) void prompt_softmax_k(float* __restrict__ SP,
                                                        const float* __restrict__ pr1,
                                                        const float* __restrict__ pr2) {
  __shared__ float sm[4];
  int row = blockIdx.x;          // bh*32 + p
  int bh = row >> 5, p = row & 31, b = bh >> 4;
  const float* prior = (p < 16 ? pr1 : pr2) + (size_t)b * Tc;
  float* s = SP + (size_t)row * Tc;
  int tid = threadIdx.x;
  float v[8], pw[8];
  #pragma unroll
  for (int i = 0; i < 8; ++i) { int t = tid + i * 256; v[i] = s[t]; pw[i] = prior[t]; }
  float mx = -INFINITY;
  #pragma unroll
  for (int i = 0; i < 8; ++i) mx = fmaxf(mx, v[i]);
  mx = bredM(mx, sm);
  float sum = 0.f;
  #pragma unroll
  for (int i = 0; i < 8; ++i) { v[i] = __expf(v[i] - mx); sum += v[i]; }
  sum = bredS(sum, sm);
  float inv = 1.0f / sum;
  float mx2 = -INFINITY;
  #pragma unroll
  for (int i = 0; i < 8; ++i) { v[i] = v[i] * inv * pw[i]; mx2 = fmaxf(mx2, v[i]); }
  mx2 = bredM(mx2, sm);
  float sum2 = 0.f;
  #pragma unroll
  for (int i = 0; i < 8; ++i) { v[i] = __expf(v[i] - mx2); sum2 += v[i]; }
  sum2 = bredS(sum2, sm);
  float inv2 = 1.0f / sum2;
  #pragma unroll
  for (int i = 0; i < 8; ++i) s[tid + i * 256] = v[i] * inv2;
}

// -------- p_v partials with fused combine (block-private ctx slice) ---------
__global__ __launch_bounds__(256) void pv_partial_k(const float* __restrict__ PA,
                                                    float* __restrict__ ctx,   // == OP0
                                                    const float* __restrict__ OP1,
                                                    const float* __restrict__ ML,
                                                    float* __restrict__ PVP) {
  __shared__ float pal[32][128];
  __shared__ float lsm[128];
  const int bh = blockIdx.x, ts = blockIdx.y;
  const int tid = threadIdx.x;
  const int t0 = ts * 128;
  const float* pabase = PA + (size_t)bh * 32 * Tc;

  if (tid < 128) {
    size_t r = (size_t)bh * Tc + t0 + tid;
    lsm[tid] = 1.0f / (ML[r] + ML[(size_t)32 * Tc + r]);
  }
  __syncthreads();
  #pragma unroll
  for (int pp = 0; pp < 8; ++pp) {
    int idx = pp * 256 + tid;
    int rr = idx >> 4, c4 = (idx & 15) * 4;
    size_t row = (size_t)bh * Tc + t0 + rr;
    float4 v0 = *(const float4*)(ctx + row * 64 + c4);
    float4 v1 = *(const float4*)(OP1 + row * 64 + c4);
    float li = lsm[rr];
    float4 o;
    o.x = (v0.x + v1.x) * li;
    o.y = (v0.y + v1.y) * li;
    o.z = (v0.z + v1.z) * li;
    o.w = (v0.w + v1.w) * li;
    *(float4*)(ctx + row * 64 + c4) = o;
  }
  __syncthreads();

  #pragma unroll
  for (int i = 0; i < 4; ++i) {
    int e = tid + i * 256;
    int p = e >> 5, c4 = e & 31;
    *(float4*)&pal[p][c4 * 4] = *(const float4*)&pabase[(size_t)p * Tc + t0 + c4 * 4];
  }
  __syncthreads();

  const int d4 = tid & 15, p0 = tid >> 4;
  const float* cb = ctx + ((size_t)bh * Tc + t0) * 64 + d4 * 4;
  float4 a0 = make_float4(0.f, 0.f, 0.f, 0.f);
  float4 a1 = make_float4(0.f, 0.f, 0.f, 0.f);
  for (int tt = 0; tt < 128; ++tt) {
    float4 v = *(const float4*)(cb + (size_t)tt * 64);
    float w0 = pal[p0][tt], w1 = pal[p0 + 16][tt];
    a0.x += w0 * v.x; a0.y += w0 * v.y; a0.z += w0 * v.z; a0.w += w0 * v.w;
    a1.x += w1 * v.x; a1.y += w1 * v.y; a1.z += w1 * v.z; a1.w += w1 * v.w;
  }
  float* o = PVP + (((size_t)ts * 32 + bh) * 32) * 64 + d4 * 4;
  *(float4*)(o + (size_t)p0 * 64) = a0;
  *(float4*)(o + (size_t)(p0 + 16) * 64) = a1;
}

// ---------------- residual + LN (main path) ---------------------------------
__global__ __launch_bounds__(256) void resln_k(const float* __restrict__ x,
                                               const float* __restrict__ ctx,
                                               const float* __restrict__ g,
                                               const float* __restrict__ be,
                                               float* __restrict__ res,
                                               u16* __restrict__ lnout) {
  __shared__ float sm[4];
  int row = blockIdx.x;            // 0..4095
  int b = row >> 11, t = row & 2047;
  int tid = threadIdx.x, c4 = tid * 4;
  int h = c4 >> 6, d = c4 & 63;
  float4 xv = *(const float4*)(x + (size_t)row * Dc + c4);
  float4 cv = *(const float4*)(ctx + (((size_t)(b * Hc + h) * Tc + t) << 6) + d);
  float r0 = xv.x + cv.x, r1 = xv.y + cv.y, r2 = xv.z + cv.z, r3 = xv.w + cv.w;
  float4 rr; rr.x = r0; rr.y = r1; rr.z = r2; rr.w = r3;
  *(float4*)(res + (size_t)row * Dc + c4) = rr;
  float s = bredS(r0 + r1 + r2 + r3, sm);
  float sq = bredS(r0 * r0 + r1 * r1 + r2 * r2 + r3 * r3, sm);
  float mu = s * (1.0f / Dc);
  float var = sq * (1.0f / Dc) - mu * mu;
  float rs = rsqrtf(var + 1e-6f);
  ushort4 o;
  o.x = (u16)bfr((r0 - mu) * rs * g[c4 + 0] + be[c4 + 0]);
  o.y = (u16)bfr((r1 - mu) * rs * g[c4 + 1] + be[c4 + 1]);
  o.z = (u16)bfr((r2 - mu) * rs * g[c4 + 2] + be[c4 + 2]);
  o.w = (u16)bfr((r3 - mu) * rs * g[c4 + 3] + be[c4 + 3]);
  *(ushort4*)(lnout + (size_t)row * Dc + c4) = o;
}

// ---------------- prompt merge (PVP reduce inline) + residual + LN ----------
__global__ __launch_bounds__(256) void promptln_k(const float* __restrict__ PVP,
                                                  const float* __restrict__ p1,
                                                  const float* __restrict__ p2,
                                                  const float* __restrict__ g,
                                                  const float* __restrict__ be,
                                                  float* __restrict__ PMLN) {
  __shared__ float sm[4];
  int row = blockIdx.x;            // 0..63 : b = row>>5, j = row&31
  int b = row >> 5, j = row & 31;
  int tid = threadIdx.x, c4 = tid * 4;
  int h = c4 >> 6, d = c4 & 63;
  int bh = b * Hc + h;
  const float* pr = (j < 16) ? (p1 + (size_t)(b * 16 + j) * Dc + c4)
                             : (p2 + (size_t)(b * 16 + j - 16) * Dc + c4);
  float4 pv4 = make_float4(0.f, 0.f, 0.f, 0.f);
  #pragma unroll
  for (int ts = 0; ts < 16; ++ts) {
    float4 v = *(const float4*)(PVP + (((size_t)ts * 32 + bh) * 32 + j) * 64 + d);
    pv4.x += v.x; pv4.y += v.y; pv4.z += v.z; pv4.w += v.w;
  }
  float4 pp4 = *(const float4*)pr;
  float r0 = pv4.x + pp4.x, r1 = pv4.y + pp4.y, r2 = pv4.z + pp4.z, r3 = pv4.w + pp4.w;
  float s = bredS(r0 + r1 + r2 + r3, sm);
  float sq = bredS(r0 * r0 + r1 * r1 + r2 * r2 + r3 * r3, sm);
  float mu = s * (1.0f / Dc);
  float var = sq * (1.0f / Dc) - mu * mu;
  float rs = rsqrtf(var + 1e-6f);
  float4 o;
  o.x = (r0 - mu) * rs * g[c4 + 0] + be[c4 + 0];
  o.y = (r1 - mu) * rs * g[c4 + 1] + be[c4 + 1];
  o.z = (r2 - mu) * rs * g[c4 + 2] + be[c4 + 2];
  o.w = (r3 - mu) * rs * g[c4 + 3] + be[c4 + 3];
  *(float4*)(PMLN + (size_t)row * Dc + c4) = o;
}

// ---------------- prompt FFN, split-K partials ------------------------------
__global__ __launch_bounds__(256) void pffn_partial_k(const float* __restrict__ PMLN,
                                                      const float* __restrict__ Wp1,
                                                      const float* __restrict__ Wp2,
                                                      float* __restrict__ PB) {
  __shared__ float pm[32][32];
  const int tid = threadIdx.x;
  const int ks = blockIdx.x, ct = blockIdx.y, s = blockIdx.z;
  const int c = ct * 256 + tid;
  const int k0 = ks * 32;
  const float* W = s ? Wp2 : Wp1;

  #pragma unroll
  for (int i = 0; i < 4; ++i) {
    int e = tid + i * 256;
    int r = e >> 5, kk = e & 31;
    int grow = (r >> 4) * 32 + s * 16 + (r & 15);
    pm[r][kk] = PMLN[(size_t)grow * Dc + k0 + kk];
  }
  __syncthreads();

  float acc[32];
  #pragma unroll
  for (int r = 0; r < 32; ++r) acc[r] = 0.f;
  for (int kk = 0; kk < 32; ++kk) {
    float w = W[(size_t)(k0 + kk) * Dc + c];
    #pragma unroll
    for (int r = 0; r < 32; ++r) acc[r] += pm[r][kk] * w;
  }

  float* pb = PB + (((size_t)ks * 2 + s) * 32) * Dc + c;
  #pragma unroll
  for (int r = 0; r < 32; ++r) pb[(size_t)r * Dc] = acc[r];
}

__global__ __launch_bounds__(256) void pffn_reduce_k(const float* __restrict__ PB,
                                                     const float* __restrict__ bp1,
                                                     const float* __restrict__ bp2,
                                                     float* __restrict__ out) {
  int e = blockIdx.x * 256 + threadIdx.x;   // 0..65535
  int s = e >> 15, rem = e & 32767;
  int r = rem >> 10, c = rem & 1023;
  float sum = 0.f;
  const float* pb = PB + ((size_t)s * 32 + r) * Dc + c;
  #pragma unroll
  for (int ks = 0; ks < 32; ++ks) sum += pb[(size_t)ks * 2 * 32 * Dc];
  const float* bp = s ? bp2 : bp1;
  out[(size_t)Mc * Dc + (size_t)s * (32 * Dc) + (size_t)r * Dc + c] = geluf(sum + bp[c]);
}

// ============================================================================
extern "C" void kernel_launch(void* const* d_in, const int* in_sizes, int n_in,
                              void* d_out, int out_size, void* d_ws, size_t ws_size,
                              hipStream_t stream) {
  (void)in_sizes; (void)n_in; (void)out_size; (void)ws_size;
  const float* x   = (const float*)d_in[0];
  const float* p1  = (const float*)d_in[1];
  const float* p2  = (const float*)d_in[2];
  const float* pr1 = (const float*)d_in[3];
  const float* pr2 = (const float*)d_in[4];
  const float* msk = (const float*)d_in[5];
  const float* Wq  = (const float*)d_in[6];
  const float* bq  = (const float*)d_in[7];
  const float* Wk  = (const float*)d_in[8];
  const float* bk  = (const float*)d_in[9];
  const float* Wv  = (const float*)d_in[10];
  const float* bv  = (const float*)d_in[11];
  const float* g2  = (const float*)d_in[12];
  const float* be2 = (const float*)d_in[13];
  const float* W1  = (const float*)d_in[14];
  const float* b1  = (const float*)d_in[15];
  const float* W2  = (const float*)d_in[16];
  const float* b2  = (const float*)d_in[17];
  const float* Wp1 = (const float*)d_in[18];
  const float* bp1 = (const float*)d_in[19];
  const float* Wp2 = (const float*)d_in[20];
  const float* bp2 = (const float*)d_in[21];

  char* ws = (char*)d_ws;
  size_t off = 0;
  auto alloc = [&](size_t bytes) {
    void* p = ws + off;
    off += (bytes + 255) & ~(size_t)255;
    return p;
  };
  u16* WQKVT = (u16*)alloc((size_t)3072 * 1024 * 2);
  u16* W1T   = (u16*)alloc((size_t)1024 * 1024 * 2);
  u16* W2T   = (u16*)alloc((size_t)1024 * 1024 * 2);
  u16* XB    = (u16*)alloc((size_t)Mc * Dc * 2);
  u16* QB    = (u16*)alloc((size_t)32 * Tc * 64 * 2);
  u16* KB    = (u16*)alloc((size_t)32 * TP * 64 * 2);
  u16* H1    = (u16*)alloc((size_t)Mc * Dc * 2);
  u16* VT    = (u16*)alloc((size_t)32 * 64 * Tc * 2);
  float* CTX = (float*)alloc((size_t)32 * Tc * 64 * 4);
  float* SP  = (float*)alloc((size_t)32 * 32 * Tc * 4);
  float* RES = (float*)alloc((size_t)Mc * Dc * 4);
  float* PMLN = (float*)alloc((size_t)64 * Dc * 4);
  float* ML  = (float*)alloc((size_t)2 * 32 * Tc * 4);
  float* PVP = (float*)alloc((size_t)16 * 32 * 32 * 64 * 4);
  u16* LNOUT = XB;    // reuse: XB dead after QKV GEMM
  float* PB  = SP;    // reuse: SP dead after pv
  float* OP0 = CTX;   // attn partial ks=0 (combined in place -> ctx in pv)
  float* OP1 = RES;   // attn partial ks=1 (RES free until resln_k)

  float* outMain = (float*)d_out;

  // 1. weight transposes (bf16) + x->bf16, single batched launch
  transpose_w5_k<<<dim3(32, 32, 6), 256, 0, stream>>>(Wq, Wk, Wv, W1, W2, x,
                                                      WQKVT, W1T, W2T, XB);
  // 2. QKV fused GEMM (N=3072); V written TRANSPOSED to VT (vtrans fused)
  gemm128_k<0, 32><<<768, 256, 0, stream>>>(XB, WQKVT, bq, bk, bv, QB, KB, VT,
                                            nullptr, nullptr, nullptr);
  // 3. flash attention (fixed-m, split-K x2, f32 partials, 2 blocks/CU)
  //    + fused prompt scores + fused prompt-key load (from p1/p2)
  attn_k<<<1024, 256, 0, stream>>>(QB, KB, VT, msk, p1, p2, OP0, OP1, ML, SP);
  // 4. prompt double-softmax (in place)
  prompt_softmax_k<<<1024, 256, 0, stream>>>(SP, pr1, pr2);
  // 5. p_v = p_a @ ctx : fused combine prologue + split-T partials
  pv_partial_k<<<dim3(32, 16), 256, 0, stream>>>(SP, OP0, OP1, ML, PVP);
  // 6. residual + LN (main); ctx materialized by pv_partial
  resln_k<<<4096, 256, 0, stream>>>(x, CTX, g2, be2, RES, LNOUT);
  // 7. prompt merge (inline PVP reduce) + LN
  promptln_k<<<64, 256, 0, stream>>>(PVP, p1, p2, g2, be2, PMLN);
  // 8. prompt FFN (split-K): partials then reduce -> d_out (p1_out, p2_out)
  pffn_partial_k<<<dim3(32, 4, 2), 256, 0, stream>>>(PMLN, Wp1, Wp2, PB);
  pffn_reduce_k<<<256, 256, 0, stream>>>(PB, bp1, bp2, outMain);
  // 9. FFN1: gelu(ln @ W1 + b1) -> bf16, 128x128 tile (256 blocks)
  gemm128_k<1, 32><<<256, 256, 0, stream>>>(LNOUT, W1T, b1, nullptr, nullptr,
                                            nullptr, nullptr, nullptr, H1,
                                            nullptr, nullptr);
  // 10. FFN2: h1 @ W2 + b2 + residual -> d_out (main), 128x128 tile
  gemm128_k<2, 32><<<256, 256, 0, stream>>>(H1, W2T, b2, nullptr, nullptr,
                                            nullptr, nullptr, nullptr, nullptr,
                                            outMain, RES);
}

// Round 20
// 211.738 us; speedup vs baseline: 1.1186x; 1.0043x over previous
//
#include <hip/hip_runtime.h>

#define DEV __device__ __forceinline__

typedef unsigned short u16;
typedef unsigned int   u32;
typedef short  s16x8  __attribute__((ext_vector_type(8)));
typedef float  f32x4  __attribute__((ext_vector_type(4)));
typedef float  f32x16 __attribute__((ext_vector_type(16)));

constexpr int Bc = 2, Hc = 16, Tc = 2048, Dc = 1024, HDc = 64, Mc = 4096;
constexpr int TP = Tc + 32;           // key rows incl. prompts
constexpr float SCALEc = 0.125f;      // 1/sqrt(64)
constexpr float LOG2E = 1.44269504088896340736f;
constexpr float SCALE2c = SCALEc * LOG2E;   // log2-domain scale
constexpr float NEGc = -1e30f;

typedef __attribute__((address_space(3))) void lds_void;
typedef const __attribute__((address_space(1))) void g_void;

DEV void gload16(const void* g, void* l) {
  __builtin_amdgcn_global_load_lds((g_void*)g, (lds_void*)l, 16, 0, 0);
}

DEV int swz(int r) { return (r & 7) ^ ((r >> 3) & 7); }   // LDS col-slot swizzle

DEV u32 bfr(float f) {                 // f32 -> bf16 bits, RNE
  u32 u = __float_as_uint(f);
  return (u + 0x7fffu + ((u >> 16) & 1u)) >> 16;
}
DEV u32 cvtpk(float a, float b) {      // packed f32x2 -> bf16x2 (RNE), 1 inst
  u32 r;
  asm("v_cvt_pk_bf16_f32 %0, %1, %2" : "=v"(r) : "v"(a), "v"(b));
  return r;
}
DEV s16x8 mk8(u32 w0, u32 w1, u32 w2, u32 w3) {
  union { u32 u[4]; s16x8 v; } x;
  x.u[0] = w0; x.u[1] = w1; x.u[2] = w2; x.u[3] = w3;
  return x.v;
}
DEV float geluf(float x) { return 0.5f * x * (1.0f + erff(x * 0.70710678118654752440f)); }

DEV float wredS(float v) {
  #pragma unroll
  for (int o = 32; o; o >>= 1) v += __shfl_xor(v, o);
  return v;
}
DEV float wredM(float v) {
  #pragma unroll
  for (int o = 32; o; o >>= 1) v = fmaxf(v, __shfl_xor(v, o));
  return v;
}
DEV float bredS(float v, float* sm) {   // 4-wave block
  v = wredS(v);
  __syncthreads();
  if ((threadIdx.x & 63) == 0) sm[threadIdx.x >> 6] = v;
  __syncthreads();
  return sm[0] + sm[1] + sm[2] + sm[3];
}
DEV float bredM(float v, float* sm) {
  v = wredM(v);
  __syncthreads();
  if ((threadIdx.x & 63) == 0) sm[threadIdx.x >> 6] = v;
  __syncthreads();
  return fmaxf(fmaxf(sm[0], sm[1]), fmaxf(sm[2], sm[3]));
}

// ------ batched weight transpose+convert (5 matrices) + x->bf16 (z==5) -----
__global__ __launch_bounds__(256) void transpose_w5_k(
    const float* __restrict__ Wq, const float* __restrict__ Wk,
    const float* __restrict__ Wv, const float* __restrict__ W1,
    const float* __restrict__ W2, const float* __restrict__ x,
    u16* __restrict__ WQKVT, u16* __restrict__ W1T, u16* __restrict__ W2T,
    u16* __restrict__ XB) {
  int z = blockIdx.z;
  if (z == 5) {   // x -> bf16: 1024 blocks x 256 thr x 4 float4 = Mc*Dc/4
    int base = (int)(blockIdx.y * 32 + blockIdx.x);
    int i0 = base * 1024 + (int)threadIdx.x;
    #pragma unroll
    for (int k = 0; k < 4; ++k) {
      int i = i0 + k * 256;
      float4 v = ((const float4*)x)[i];
      ushort4 u;
      u.x = (u16)bfr(v.x); u.y = (u16)bfr(v.y);
      u.z = (u16)bfr(v.z); u.w = (u16)bfr(v.w);
      ((ushort4*)XB)[i] = u;
    }
    return;
  }
  __shared__ float tile[32][33];
  int bx = blockIdx.x, by = blockIdx.y;
  const float* src = (z == 0) ? Wq : (z == 1) ? Wk : (z == 2) ? Wv
                    : (z == 3) ? W1 : W2;
  u16* dst = (z == 0) ? WQKVT
           : (z == 1) ? WQKVT + (size_t)1024 * 1024
           : (z == 2) ? WQKVT + (size_t)2 * 1024 * 1024
           : (z == 3) ? W1T : W2T;
  int tx = threadIdx.x & 31, ty = threadIdx.x >> 5;
  #pragma unroll
  for (int i = 0; i < 32; i += 8)
    tile[ty + i][tx] = src[(size_t)(by * 32 + ty + i) * Dc + bx * 32 + tx];
  __syncthreads();
  #pragma unroll
  for (int i = 0; i < 32; i += 8)
    dst[(size_t)(bx * 32 + ty + i) * Dc + by * 32 + tx] = (u16)bfr(tile[tx][ty + i]);
}

// ---------------- 128x128 bf16 MFMA GEMM ------------------------------------
// BM=BN=128 BK=32; 4 waves 2x2. LDS-staged C epilogue -> coalesced vector
// stores. 2D XCD chunking (4 row-groups x 2 col-groups): per-XCD working set
// = (NBX/4)*128 A-rows + (NBY/2)*128 B-cols -- fits 4MB L2 (the 1D col-strip
// mapping streamed the whole 8MB A from HBM per XCD: ~190MB fetch for QKV).
// MODE 0: QKV epilogue (V written TRANSPOSED, CSV=129); MODE 1: bias+gelu;
// MODE 2: bias+residual->f32
template <int MODE, int NBX, int NBY>
__global__ __launch_bounds__(256, 3) void gemm128_k(
    const u16* __restrict__ A, const u16* __restrict__ Bt,
    const float* __restrict__ bias0, const float* __restrict__ bias1,
    const float* __restrict__ bias2,
    u16* __restrict__ outQ, u16* __restrict__ outK, u16* __restrict__ outVT,
    u16* __restrict__ outB, float* __restrict__ outF,
    const float* __restrict__ resid) {
  __shared__ __align__(16) u16 smem[17408];
  u16* as0 = smem;                 // [2][128*32]
  u16* bs0 = smem + 2 * 128 * 32;  // [2][128*32]
  const int tid = threadIdx.x, lane = tid & 63, wave = tid >> 6;
  const int wr = wave >> 1, wc = wave & 1;
  // 2D XCD chunk: xcd = bid&7 -> (row-group xcd&3, col-group xcd>>2)
  constexpr int RPX = NBX / 4, CPX = NBY / 2;   // tiles per XCD chunk
  const int bid = (int)blockIdx.x;
  const int xcd = bid & 7, l = bid >> 3;
  const int row0 = ((xcd & 3) * RPX + l % RPX) * 128;
  const int col0 = ((xcd >> 2) * CPX + l / RPX) * 128;

  f32x4 zero4;
  #pragma unroll
  for (int r = 0; r < 4; ++r) zero4[r] = 0.f;
  f32x4 acc[4][4];
  #pragma unroll
  for (int i = 0; i < 4; ++i)
    #pragma unroll
    for (int j = 0; j < 4; ++j) acc[i][j] = zero4;

  auto stage = [&](int buf, int kt) {
    const int k0 = kt * 32;
    #pragma unroll
    for (int is = 0; is < 2; ++is) {
      int q = is * 256 + tid; int r = q >> 2, c = q & 3, g = c ^ ((r >> 1) & 3);
      gload16(A + (size_t)(row0 + r) * Dc + k0 + g * 8,
              as0 + (size_t)buf * 4096 + (is * 256 + wave * 64) * 8);
    }
    #pragma unroll
    for (int is = 0; is < 2; ++is) {
      int q = is * 256 + tid; int r = q >> 2, c = q & 3, g = c ^ ((r >> 1) & 3);
      gload16(Bt + (size_t)(col0 + r) * Dc + k0 + g * 8,
              bs0 + (size_t)buf * 4096 + (is * 256 + wave * 64) * 8);
    }
  };

  stage(0, 0);
  asm volatile("s_waitcnt vmcnt(0)" ::: "memory");
  __syncthreads();

  int cur = 0;
  for (int kt = 0; kt < 32; ++kt) {
    if (kt + 1 < 32) stage(cur ^ 1, kt + 1);
    s16x8 af[4], bfv[4];
    #pragma unroll
    for (int f = 0; f < 4; ++f) {
      int r = wr * 64 + f * 16 + (lane & 15);
      int c = (lane >> 4) ^ ((r >> 1) & 3);
      af[f] = *(const s16x8*)&as0[cur * 4096 + r * 32 + c * 8];
    }
    #pragma unroll
    for (int f = 0; f < 4; ++f) {
      int r = wc * 64 + f * 16 + (lane & 15);
      int c = (lane >> 4) ^ ((r >> 1) & 3);
      bfv[f] = *(const s16x8*)&bs0[cur * 4096 + r * 32 + c * 8];
    }
    __builtin_amdgcn_s_setprio(1);
    #pragma unroll
    for (int i = 0; i < 4; ++i)
      #pragma unroll
      for (int j = 0; j < 4; ++j)
        acc[i][j] = __builtin_amdgcn_mfma_f32_16x16x32_bf16(af[i], bfv[j], acc[i][j], 0, 0, 0);
    __builtin_amdgcn_s_setprio(0);
    __syncthreads();
    cur ^= 1;
  }

  if (MODE == 0) {
    const int which = col0 >> 10;          // block-uniform segment
    const float* bias = (which == 0) ? bias0 : (which == 1) ? bias1 : bias2;
    if (which == 2) {
      // ---- V: stage with CSV=129, write TRANSPOSED vt[bh][d][t] ----
      const int CSV = 129;
      u16* ct = smem;
      #pragma unroll
      for (int i = 0; i < 4; ++i)
        #pragma unroll
        for (int j = 0; j < 4; ++j)
          #pragma unroll
          for (int r = 0; r < 4; ++r) {
            int rl = wr * 64 + i * 16 + (lane >> 4) * 4 + r;
            int cl = wc * 64 + j * 16 + (lane & 15);
            float v = acc[i][j][r] + bias[(col0 + cl) & 1023];
            ct[rl * CSV + cl] = (u16)bfr(v);
          }
      __syncthreads();
      int bb = row0 >> 11, tbase = row0 & 2047;
      #pragma unroll
      for (int it = 0; it < 16; ++it) {
        int linear = it * 256 + tid;       // 4096 quads = 128 d x 32 t-quads
        int dcol = linear >> 5, q4 = linear & 31;
        int t = q4 * 4;
        int n = (col0 & 1023) + dcol;
        int hh = n >> 6, dd = n & 63;
        ushort4 val;
        val.x = ct[(t + 0) * CSV + dcol];
        val.y = ct[(t + 1) * CSV + dcol];
        val.z = ct[(t + 2) * CSV + dcol];
        val.w = ct[(t + 3) * CSV + dcol];
        *(ushort4*)&outVT[((size_t)(bb * Hc + hh) * 64 + dd) * Tc + tbase + t] = val;
      }
    } else {
      const int CS = 136;
      u16* ct = smem;
      #pragma unroll
      for (int i = 0; i < 4; ++i)
        #pragma unroll
        for (int j = 0; j < 4; ++j)
          #pragma unroll
          for (int r = 0; r < 4; ++r) {
            int rl = wr * 64 + i * 16 + (lane >> 4) * 4 + r;
            int cl = wc * 64 + j * 16 + (lane & 15);
            float v = acc[i][j][r] + bias[(col0 + cl) & 1023];
            ct[rl * CS + cl] = (u16)bfr(v);
          }
      __syncthreads();
      #pragma unroll
      for (int it = 0; it < 16; ++it) {
        int linear = it * 256 + tid;
        int row = linear >> 5, c4 = (linear & 31) * 4;
        ushort4 val = *(const ushort4*)&ct[row * CS + c4];
        int grow = row0 + row;
        int col = col0 + c4;
        int n = col & 1023;
        int hh = n >> 6, d = n & 63, bb = grow >> 11, t = grow & 2047;
        if (which == 0)
          *(ushort4*)&outQ[(((size_t)(bb * Hc + hh) * Tc + t) << 6) + d] = val;
        else
          *(ushort4*)&outK[(((size_t)(bb * Hc + hh) * TP + t) << 6) + d] = val;
      }
    }
  } else if (MODE == 1) {
    const int CS = 136;
    u16* ct = smem;
    #pragma unroll
    for (int i = 0; i < 4; ++i)
      #pragma unroll
      for (int j = 0; j < 4; ++j)
        #pragma unroll
        for (int r = 0; r < 4; ++r) {
          int rl = wr * 64 + i * 16 + (lane >> 4) * 4 + r;
          int cl = wc * 64 + j * 16 + (lane & 15);
          float v = geluf(acc[i][j][r] + bias0[col0 + cl]);
          ct[rl * CS + cl] = (u16)bfr(v);
        }
    __syncthreads();
    #pragma unroll
    for (int it = 0; it < 16; ++it) {
      int linear = it * 256 + tid;
      int row = linear >> 5, c4 = (linear & 31) * 4;
      ushort4 val = *(const ushort4*)&ct[row * CS + c4];
      *(ushort4*)&outB[(size_t)(row0 + row) * Dc + col0 + c4] = val;
    }
  } else {
    const int CSF = 132;
    float* cf = (float*)smem;
    #pragma unroll
    for (int p = 0; p < 2; ++p) {
      if (wr == p) {
        #pragma unroll
        for (int i = 0; i < 4; ++i)
          #pragma unroll
          for (int j = 0; j < 4; ++j)
            #pragma unroll
            for (int r = 0; r < 4; ++r) {
              int rl = i * 16 + (lane >> 4) * 4 + r;
              int cl = wc * 64 + j * 16 + (lane & 15);
              cf[rl * CSF + cl] = acc[i][j][r];
            }
      }
      __syncthreads();
      #pragma unroll
      for (int it = 0; it < 8; ++it) {
        int linear = it * 256 + tid;
        int row = linear >> 5, c4 = (linear & 31) * 4;
        float4 v = *(const float4*)&cf[row * CSF + c4];
        int grow = row0 + p * 64 + row;
        int col = col0 + c4;
        float4 rr = *(const float4*)&resid[(size_t)grow * Dc + col];
        float4 o;
        o.x = v.x + bias0[col + 0] + rr.x;
        o.y = v.y + bias0[col + 1] + rr.y;
        o.z = v.z + bias0[col + 2] + rr.z;
        o.w = v.w + bias0[col + 3] + rr.w;
        *(float4*)&outF[(size_t)grow * Dc + col] = o;
      }
      __syncthreads();
    }
  }
}

// ---------------- flash attention, fixed-m, split-K x2, + prompt scores -----
__global__ __launch_bounds__(256, 2) void attn_k(
    const u16* __restrict__ qb,   // [bh][T][64]
    const u16* __restrict__ kb,   // [bh][T+32][64]
    const u16* __restrict__ vt,   // [bh][64][T]
    const float* __restrict__ maskp,   // [B][T]
    const float* __restrict__ p1, const float* __restrict__ p2,
    float* __restrict__ OP0, float* __restrict__ OP1,
    float* __restrict__ ML,
    float* __restrict__ SP) {     // [bh][32][T]
  __shared__ __align__(16) u16 kls[2][64 * 64];
  __shared__ __align__(16) u16 vls[2][64 * 64];
  __shared__ __align__(16) u16 kpls[32 * 64];
  __shared__ float mls[1024];

  const int tid = threadIdx.x, lane = tid & 63, wave = tid >> 6;
  const int wg = ((int)blockIdx.x & 7) * 128 + ((int)blockIdx.x >> 3);
  const int ks = wg & 1, qt = (wg >> 1) & 15, bh = wg >> 5;
  const int b = bh >> 4;
  const int lo = lane & 31, h5 = lane >> 5;
  const size_t kbase = (size_t)bh * TP * 64;
  const size_t vbase = (size_t)bh * 64 * Tc;

  for (int i = tid; i < 1024; i += 256)
    mls[i] = (1.0f - maskp[(size_t)b * Tc + ks * 1024 + i]) * NEGc;

  if (ks == 0) {  // prompt keys: f32 -> bf16 in-register, swizzled kpls layout
    int r = tid >> 3, cg = tid & 7, g = cg ^ swz(r);
    int h = bh & 15;
    const float* src = (r < 16)
        ? (p1 + (size_t)(b * 16 + r) * Dc + h * 64 + g * 8)
        : (p2 + (size_t)(b * 16 + (r - 16)) * Dc + h * 64 + g * 8);
    float4 a = *(const float4*)src;
    float4 c = *(const float4*)(src + 4);
    *(s16x8*)&kpls[tid * 8] = mk8(cvtpk(a.x, a.y), cvtpk(a.z, a.w),
                                  cvtpk(c.x, c.y), cvtpk(c.z, c.w));
  }

  const int q0 = qt * 128 + wave * 32;
  s16x8 qf[4];
  #pragma unroll
  for (int kc = 0; kc < 4; ++kc)
    qf[kc] = *(const s16x8*)(qb + ((size_t)bh * Tc + q0 + lo) * 64 + kc * 16 + h5 * 8);

  auto stageKV = [&](int buf, int kt2) {
    #pragma unroll
    for (int is = 0; is < 2; ++is) {
      int q = is * 256 + tid; int r = q >> 3, c = q & 7, g = c ^ swz(r);
      gload16(kb + kbase + (size_t)(kt2 * 64 + r) * 64 + g * 8,
              &kls[buf][(is * 256 + wave * 64) * 8]);
      gload16(vt + vbase + (size_t)r * Tc + kt2 * 64 + g * 8,
              &vls[buf][(is * 256 + wave * 64) * 8]);
    }
  };

  stageKV(0, ks * 16);
  asm volatile("s_waitcnt vmcnt(0)" ::: "memory");
  __syncthreads();

  f32x16 zero16;
  #pragma unroll
  for (int r = 0; r < 16; ++r) zero16[r] = 0.f;
  f32x16 O0 = zero16, O1 = zero16, racc = zero16;

  int cur = 0;
  for (int kt = 0; kt < 16; ++kt) {
    if (kt + 1 < 16) stageKV(cur ^ 1, ks * 16 + kt + 1);

    #pragma unroll
    for (int c = 0; c < 2; ++c) {
      f32x16 s = zero16;
      __builtin_amdgcn_s_setprio(1);
      #pragma unroll
      for (int kc = 0; kc < 4; ++kc) {
        int r = c * 32 + lo;
        int ci = (kc * 2 + h5) ^ swz(r);
        s16x8 kf = *(const s16x8*)&kls[cur][r * 64 + ci * 8];
        s = __builtin_amdgcn_mfma_f32_32x32x16_bf16(kf, qf[kc], s, 0, 0, 0);
      }
      __builtin_amdgcn_s_setprio(0);

      float4 mq[4];
      #pragma unroll
      for (int g = 0; g < 4; ++g)
        mq[g] = *(const float4*)&mls[kt * 64 + c * 32 + 4 * h5 + 8 * g];

      float p[16];
      #pragma unroll
      for (int r = 0; r < 16; ++r) {
        float mv = (&mq[r >> 2].x)[r & 3];
        p[r] = exp2f(s[r] * SCALE2c + mv);
        racc[r] += p[r];
      }

      #pragma unroll
      for (int k1 = 0; k1 < 2; ++k1) {
        u32 w0 = cvtpk(p[8 * k1 + 0], p[8 * k1 + 1]);
        u32 w1 = cvtpk(p[8 * k1 + 2], p[8 * k1 + 3]);
        u32 w2 = cvtpk(p[8 * k1 + 4], p[8 * k1 + 5]);
        u32 w3 = cvtpk(p[8 * k1 + 6], p[8 * k1 + 7]);
        asm volatile("v_permlane32_swap_b32 %0, %1" : "+v"(w2), "+v"(w0));
        asm volatile("v_permlane32_swap_b32 %0, %1" : "+v"(w3), "+v"(w1));
        s16x8 pf = mk8(w0, w1, w2, w3);
        __builtin_amdgcn_s_setprio(1);
        #pragma unroll
        for (int db = 0; db < 2; ++db) {
          int d = db * 32 + lo;
          int ci = (c * 4 + k1 * 2 + h5) ^ swz(d);
          s16x8 vf = *(const s16x8*)&vls[cur][d * 64 + ci * 8];
          if (db == 0) O0 = __builtin_amdgcn_mfma_f32_32x32x16_bf16(pf, vf, O0, 0, 0, 0);
          else         O1 = __builtin_amdgcn_mfma_f32_32x32x16_bf16(pf, vf, O1, 0, 0, 0);
        }
        __builtin_amdgcn_s_setprio(0);
      }
    }
    __syncthreads();
    cur ^= 1;
  }

  // prompt scores (ks==0 blocks): S_p^T[pkey][q] * scale
  if (ks == 0) {
    f32x16 sp = zero16;
    #pragma unroll
    for (int kc = 0; kc < 4; ++kc) {
      int ci = (kc * 2 + h5) ^ swz(lo);
      s16x8 kf = *(const s16x8*)&kpls[lo * 64 + ci * 8];
      sp = __builtin_amdgcn_mfma_f32_32x32x16_bf16(kf, qf[kc], sp, 0, 0, 0);
    }
    #pragma unroll
    for (int r = 0; r < 16; ++r) {
      int pr = (r & 3) + 8 * (r >> 2) + 4 * h5;
      SP[((size_t)bh * 32 + pr) * Tc + q0 + lo] = sp[r] * SCALEc;
    }
  }

  float* dst = ks ? OP1 : OP0;
  #pragma unroll
  for (int r = 0; r < 16; ++r) {
    int row = q0 + (r & 3) + 8 * (r >> 2) + 4 * h5;
    dst[((size_t)bh * Tc + row) * 64 + lo]      = O0[r];
    dst[((size_t)bh * Tc + row) * 64 + 32 + lo] = O1[r];
  }
  float lt = 0.f;
  #pragma unroll
  for (int r = 0; r < 16; ++r) lt += racc[r];
  lt += __shfl_xor(lt, 32);
  if (lane < 32)
    ML[((size_t)ks * 32 + bh) * Tc + q0 + lo] = lt;
}

// ---------------- prompt double softmax over t ------------------------------
__global__ __launch_bounds__(256) void prompt_softmax_k(float* __restrict__ SP,
                                                        const float* __restrict__ pr1,
                                                        const float* __restrict__ pr2) {
  __shared__ float sm[4];
  int row = blockIdx.x;          // bh*32 + p
  int bh = row >> 5, p = row & 31, b = bh >> 4;
  const float* prior = (p < 16 ? pr1 : pr2) + (size_t)b * Tc;
  float* s = SP + (size_t)row * Tc;
  int tid = threadIdx.x;
  float v[8], pw[8];
  #pragma unroll
  for (int i = 0; i < 8; ++i) { int t = tid + i * 256; v[i] = s[t]; pw[i] = prior[t]; }
  float mx = -INFINITY;
  #pragma unroll
  for (int i = 0; i < 8; ++i) mx = fmaxf(mx, v[i]);
  mx = bredM(mx, sm);
  float sum = 0.f;
  #pragma unroll
  for (int i = 0; i < 8; ++i) { v[i] = __expf(v[i] - mx); sum += v[i]; }
  sum = bredS(sum, sm);
  float inv = 1.0f / sum;
  float mx2 = -INFINITY;
  #pragma unroll
  for (int i = 0; i < 8; ++i) { v[i] = v[i] * inv * pw[i]; mx2 = fmaxf(mx2, v[i]); }
  mx2 = bredM(mx2, sm);
  float sum2 = 0.f;
  #pragma unroll
  for (int i = 0; i < 8; ++i) { v[i] = __expf(v[i] - mx2); sum2 += v[i]; }
  sum2 = bredS(sum2, sm);
  float inv2 = 1.0f / sum2;
  #pragma unroll
  for (int i = 0; i < 8; ++i) s[tid + i * 256] = v[i] * inv2;
}

// -------- p_v partials with fused combine (block-private ctx slice) ---------
__global__ __launch_bounds__(256) void pv_partial_k(const float* __restrict__ PA,
                                                    float* __restrict__ ctx,   // == OP0
                                                    const float* __restrict__ OP1,
                                                    const float* __restrict__ ML,
                                                    float* __restrict__ PVP) {
  __shared__ float pal[32][128];
  __shared__ float lsm[128];
  const int bh = blockIdx.x, ts = blockIdx.y;
  const int tid = threadIdx.x;
  const int t0 = ts * 128;
  const float* pabase = PA + (size_t)bh * 32 * Tc;

  if (tid < 128) {
    size_t r = (size_t)bh * Tc + t0 + tid;
    lsm[tid] = 1.0f / (ML[r] + ML[(size_t)32 * Tc + r]);
  }
  __syncthreads();
  #pragma unroll
  for (int pp = 0; pp < 8; ++pp) {
    int idx = pp * 256 + tid;
    int rr = idx >> 4, c4 = (idx & 15) * 4;
    size_t row = (size_t)bh * Tc + t0 + rr;
    float4 v0 = *(const float4*)(ctx + row * 64 + c4);
    float4 v1 = *(const float4*)(OP1 + row * 64 + c4);
    float li = lsm[rr];
    float4 o;
    o.x = (v0.x + v1.x) * li;
    o.y = (v0.y + v1.y) * li;
    o.z = (v0.z + v1.z) * li;
    o.w = (v0.w + v1.w) * li;
    *(float4*)(ctx + row * 64 + c4) = o;
  }
  __syncthreads();

  #pragma unroll
  for (int i = 0; i < 4; ++i) {
    int e = tid + i * 256;
    int p = e >> 5, c4 = e & 31;
    *(float4*)&pal[p][c4 * 4] = *(const float4*)&pabase[(size_t)p * Tc + t0 + c4 * 4];
  }
  __syncthreads();

  const int d4 = tid & 15, p0 = tid >> 4;
  const float* cb = ctx + ((size_t)bh * Tc + t0) * 64 + d4 * 4;
  float4 a0 = make_float4(0.f, 0.f, 0.f, 0.f);
  float4 a1 = make_float4(0.f, 0.f, 0.f, 0.f);
  for (int tt = 0; tt < 128; ++tt) {
    float4 v = *(const float4*)(cb + (size_t)tt * 64);
    float w0 = pal[p0][tt], w1 = pal[p0 + 16][tt];
    a0.x += w0 * v.x; a0.y += w0 * v.y; a0.z += w0 * v.z; a0.w += w0 * v.w;
    a1.x += w1 * v.x; a1.y += w1 * v.y; a1.z += w1 * v.z; a1.w += w1 * v.w;
  }
  float* o = PVP + (((size_t)ts * 32 + bh) * 32) * 64 + d4 * 4;
  *(float4*)(o + (size_t)p0 * 64) = a0;
  *(float4*)(o + (size_t)(p0 + 16) * 64) = a1;
}

// ---------------- residual + LN (main path) ---------------------------------
__global__ __launch_bounds__(256) void resln_k(const float* __restrict__ x,
                                               const float* __restrict__ ctx,
                                               const float* __restrict__ g,
                                               const float* __restrict__ be,
                                               float* __restrict__ res,
                                               u16* __restrict__ lnout) {
  __shared__ float sm[4];
  int row = blockIdx.x;            // 0..4095
  int b = row >> 11, t = row & 2047;
  int tid = threadIdx.x, c4 = tid * 4;
  int h = c4 >> 6, d = c4 & 63;
  float4 xv = *(const float4*)(x + (size_t)row * Dc + c4);
  float4 cv = *(const float4*)(ctx + (((size_t)(b * Hc + h) * Tc + t) << 6) + d);
  float r0 = xv.x + cv.x, r1 = xv.y + cv.y, r2 = xv.z + cv.z, r3 = xv.w + cv.w;
  float4 rr; rr.x = r0; rr.y = r1; rr.z = r2; rr.w = r3;
  *(float4*)(res + (size_t)row * Dc + c4) = rr;
  float s = bredS(r0 + r1 + r2 + r3, sm);
  float sq = bredS(r0 * r0 + r1 * r1 + r2 * r2 + r3 * r3, sm);
  float mu = s * (1.0f / Dc);
  float var = sq * (1.0f / Dc) - mu * mu;
  float rs = rsqrtf(var + 1e-6f);
  ushort4 o;
  o.x = (u16)bfr((r0 - mu) * rs * g[c4 + 0] + be[c4 + 0]);
  o.y = (u16)bfr((r1 - mu) * rs * g[c4 + 1] + be[c4 + 1]);
  o.z = (u16)bfr((r2 - mu) * rs * g[c4 + 2] + be[c4 + 2]);
  o.w = (u16)bfr((r3 - mu) * rs * g[c4 + 3] + be[c4 + 3]);
  *(ushort4*)(lnout + (size_t)row * Dc + c4) = o;
}

// ---------------- prompt merge (PVP reduce inline) + residual + LN ----------
__global__ __launch_bounds__(256) void promptln_k(const float* __restrict__ PVP,
                                                  const float* __restrict__ p1,
                                                  const float* __restrict__ p2,
                                                  const float* __restrict__ g,
                                                  const float* __restrict__ be,
                                                  float* __restrict__ PMLN) {
  __shared__ float sm[4];
  int row = blockIdx.x;            // 0..63 : b = row>>5, j = row&31
  int b = row >> 5, j = row & 31;
  int tid = threadIdx.x, c4 = tid * 4;
  int h = c4 >> 6, d = c4 & 63;
  int bh = b * Hc + h;
  const float* pr = (j < 16) ? (p1 + (size_t)(b * 16 + j) * Dc + c4)
                             : (p2 + (size_t)(b * 16 + j - 16) * Dc + c4);
  float4 pv4 = make_float4(0.f, 0.f, 0.f, 0.f);
  #pragma unroll
  for (int ts = 0; ts < 16; ++ts) {
    float4 v = *(const float4*)(PVP + (((size_t)ts * 32 + bh) * 32 + j) * 64 + d);
    pv4.x += v.x; pv4.y += v.y; pv4.z += v.z; pv4.w += v.w;
  }
  float4 pp4 = *(const float4*)pr;
  float r0 = pv4.x + pp4.x, r1 = pv4.y + pp4.y, r2 = pv4.z + pp4.z, r3 = pv4.w + pp4.w;
  float s = bredS(r0 + r1 + r2 + r3, sm);
  float sq = bredS(r0 * r0 + r1 * r1 + r2 * r2 + r3 * r3, sm);
  float mu = s * (1.0f / Dc);
  float var = sq * (1.0f / Dc) - mu * mu;
  float rs = rsqrtf(var + 1e-6f);
  float4 o;
  o.x = (r0 - mu) * rs * g[c4 + 0] + be[c4 + 0];
  o.y = (r1 - mu) * rs * g[c4 + 1] + be[c4 + 1];
  o.z = (r2 - mu) * rs * g[c4 + 2] + be[c4 + 2];
  o.w = (r3 - mu) * rs * g[c4 + 3] + be[c4 + 3];
  *(float4*)(PMLN + (size_t)row * Dc + c4) = o;
}

// ---------------- prompt FFN, split-K partials ------------------------------
__global__ __launch_bounds__(256) void pffn_partial_k(const float* __restrict__ PMLN,
                                                      const float* __restrict__ Wp1,
                                                      const float* __restrict__ Wp2,
                                                      float* __restrict__ PB) {
  __shared__ float pm[32][32];
  const int tid = threadIdx.x;
  const int ks = blockIdx.x, ct = blockIdx.y, s = blockIdx.z;
  const int c = ct * 256 + tid;
  const int k0 = ks * 32;
  const float* W = s ? Wp2 : Wp1;

  #pragma unroll
  for (int i = 0; i < 4; ++i) {
    int e = tid + i * 256;
    int r = e >> 5, kk = e & 31;
    int grow = (r >> 4) * 32 + s * 16 + (r & 15);
    pm[r][kk] = PMLN[(size_t)grow * Dc + k0 + kk];
  }
  __syncthreads();

  float acc[32];
  #pragma unroll
  for (int r = 0; r < 32; ++r) acc[r] = 0.f;
  for (int kk = 0; kk < 32; ++kk) {
    float w = W[(size_t)(k0 + kk) * Dc + c];
    #pragma unroll
    for (int r = 0; r < 32; ++r) acc[r] += pm[r][kk] * w;
  }

  float* pb = PB + (((size_t)ks * 2 + s) * 32) * Dc + c;
  #pragma unroll
  for (int r = 0; r < 32; ++r) pb[(size_t)r * Dc] = acc[r];
}

__global__ __launch_bounds__(256) void pffn_reduce_k(const float* __restrict__ PB,
                                                     const float* __restrict__ bp1,
                                                     const float* __restrict__ bp2,
                                                     float* __restrict__ out) {
  int e = blockIdx.x * 256 + threadIdx.x;   // 0..65535
  int s = e >> 15, rem = e & 32767;
  int r = rem >> 10, c = rem & 1023;
  float sum = 0.f;
  const float* pb = PB + ((size_t)s * 32 + r) * Dc + c;
  #pragma unroll
  for (int ks = 0; ks < 32; ++ks) sum += pb[(size_t)ks * 2 * 32 * Dc];
  const float* bp = s ? bp2 : bp1;
  out[(size_t)Mc * Dc + (size_t)s * (32 * Dc) + (size_t)r * Dc + c] = geluf(sum + bp[c]);
}

// ============================================================================
extern "C" void kernel_launch(void* const* d_in, const int* in_sizes, int n_in,
                              void* d_out, int out_size, void* d_ws, size_t ws_size,
                              hipStream_t stream) {
  (void)in_sizes; (void)n_in; (void)out_size; (void)ws_size;
  const float* x   = (const float*)d_in[0];
  const float* p1  = (const float*)d_in[1];
  const float* p2  = (const float*)d_in[2];
  const float* pr1 = (const float*)d_in[3];
  const float* pr2 = (const float*)d_in[4];
  const float* msk = (const float*)d_in[5];
  const float* Wq  = (const float*)d_in[6];
  const float* bq  = (const float*)d_in[7];
  const float* Wk  = (const float*)d_in[8];
  const float* bk  = (const float*)d_in[9];
  const float* Wv  = (const float*)d_in[10];
  const float* bv  = (const float*)d_in[11];
  const float* g2  = (const float*)d_in[12];
  const float* be2 = (const float*)d_in[13];
  const float* W1  = (const float*)d_in[14];
  const float* b1  = (const float*)d_in[15];
  const float* W2  = (const float*)d_in[16];
  const float* b2  = (const float*)d_in[17];
  const float* Wp1 = (const float*)d_in[18];
  const float* bp1 = (const float*)d_in[19];
  const float* Wp2 = (const float*)d_in[20];
  const float* bp2 = (const float*)d_in[21];

  char* ws = (char*)d_ws;
  size_t off = 0;
  auto alloc = [&](size_t bytes) {
    void* p = ws + off;
    off += (bytes + 255) & ~(size_t)255;
    return p;
  };
  u16* WQKVT = (u16*)alloc((size_t)3072 * 1024 * 2);
  u16* W1T   = (u16*)alloc((size_t)1024 * 1024 * 2);
  u16* W2T   = (u16*)alloc((size_t)1024 * 1024 * 2);
  u16* XB    = (u16*)alloc((size_t)Mc * Dc * 2);
  u16* QB    = (u16*)alloc((size_t)32 * Tc * 64 * 2);
  u16* KB    = (u16*)alloc((size_t)32 * TP * 64 * 2);
  u16* H1    = (u16*)alloc((size_t)Mc * Dc * 2);
  u16* VT    = (u16*)alloc((size_t)32 * 64 * Tc * 2);
  float* CTX = (float*)alloc((size_t)32 * Tc * 64 * 4);
  float* SP  = (float*)alloc((size_t)32 * 32 * Tc * 4);
  float* RES = (float*)alloc((size_t)Mc * Dc * 4);
  float* PMLN = (float*)alloc((size_t)64 * Dc * 4);
  float* ML  = (float*)alloc((size_t)2 * 32 * Tc * 4);
  float* PVP = (float*)alloc((size_t)16 * 32 * 32 * 64 * 4);
  u16* LNOUT = XB;    // reuse: XB dead after QKV GEMM
  float* PB  = SP;    // reuse: SP dead after pv
  float* OP0 = CTX;   // attn partial ks=0 (combined in place -> ctx in pv)
  float* OP1 = RES;   // attn partial ks=1 (RES free until resln_k)

  float* outMain = (float*)d_out;

  // 1. weight transposes (bf16) + x->bf16, single batched launch
  transpose_w5_k<<<dim3(32, 32, 6), 256, 0, stream>>>(Wq, Wk, Wv, W1, W2, x,
                                                      WQKVT, W1T, W2T, XB);
  // 2. QKV fused GEMM (N=3072); V TRANSPOSED; 2D XCD chunking (L2-fit)
  gemm128_k<0, 32, 24><<<768, 256, 0, stream>>>(XB, WQKVT, bq, bk, bv, QB, KB,
                                                VT, nullptr, nullptr, nullptr);
  // 3. flash attention + fused prompt scores + fused prompt-key load
  attn_k<<<1024, 256, 0, stream>>>(QB, KB, VT, msk, p1, p2, OP0, OP1, ML, SP);
  // 4. prompt double-softmax (in place)
  prompt_softmax_k<<<1024, 256, 0, stream>>>(SP, pr1, pr2);
  // 5. p_v = p_a @ ctx : fused combine prologue + split-T partials
  pv_partial_k<<<dim3(32, 16), 256, 0, stream>>>(SP, OP0, OP1, ML, PVP);
  // 6. residual + LN (main); ctx materialized by pv_partial
  resln_k<<<4096, 256, 0, stream>>>(x, CTX, g2, be2, RES, LNOUT);
  // 7. prompt merge (inline PVP reduce) + LN
  promptln_k<<<64, 256, 0, stream>>>(PVP, p1, p2, g2, be2, PMLN);
  // 8. prompt FFN (split-K): partials then reduce -> d_out (p1_out, p2_out)
  pffn_partial_k<<<dim3(32, 4, 2), 256, 0, stream>>>(PMLN, Wp1, Wp2, PB);
  pffn_reduce_k<<<256, 256, 0, stream>>>(PB, bp1, bp2, outMain);
  // 9. FFN1: gelu(ln @ W1 + b1) -> bf16; 2D XCD chunking
  gemm128_k<1, 32, 8><<<256, 256, 0, stream>>>(LNOUT, W1T, b1, nullptr, nullptr,
                                               nullptr, nullptr, nullptr, H1,
                                               nullptr, nullptr);
  // 10. FFN2: h1 @ W2 + b2 + residual -> d_out (main); 2D XCD chunking
  gemm128_k<2, 32, 8><<<256, 256, 0, stream>>>(H1, W2T, b2, nullptr, nullptr,
                                               nullptr, nullptr, nullptr, nullptr,
                                               outMain, RES);
}

// Round 21
// 211.019 us; speedup vs baseline: 1.1224x; 1.0034x over previous
//
#include <hip/hip_runtime.h>

#define DEV __device__ __forceinline__

typedef unsigned short u16;
typedef unsigned int   u32;
typedef short  s16x8  __attribute__((ext_vector_type(8)));
typedef float  f32x4  __attribute__((ext_vector_type(4)));
typedef float  f32x16 __attribute__((ext_vector_type(16)));

constexpr int Bc = 2, Hc = 16, Tc = 2048, Dc = 1024, HDc = 64, Mc = 4096;
constexpr int TP = Tc + 32;           // key rows incl. prompts
constexpr float SCALEc = 0.125f;      // 1/sqrt(64)
constexpr float LOG2E = 1.44269504088896340736f;
constexpr float SCALE2c = SCALEc * LOG2E;   // log2-domain scale
constexpr float NEGc = -1e30f;

typedef __attribute__((address_space(3))) void lds_void;
typedef const __attribute__((address_space(1))) void g_void;

DEV void gload16(const void* g, void* l) {
  __builtin_amdgcn_global_load_lds((g_void*)g, (lds_void*)l, 16, 0, 0);
}

DEV int swz(int r) { return (r & 7) ^ ((r >> 3) & 7); }   // LDS col-slot swizzle

DEV u32 bfr(float f) {                 // f32 -> bf16 bits, RNE
  u32 u = __float_as_uint(f);
  return (u + 0x7fffu + ((u >> 16) & 1u)) >> 16;
}
DEV float b2f(u32 lo16) { return __uint_as_float(lo16 << 16); }
DEV u32 cvtpk(float a, float b) {      // packed f32x2 -> bf16x2 (RNE), 1 inst
  u32 r;
  asm("v_cvt_pk_bf16_f32 %0, %1, %2" : "=v"(r) : "v"(a), "v"(b));
  return r;
}
DEV s16x8 mk8(u32 w0, u32 w1, u32 w2, u32 w3) {
  union { u32 u[4]; s16x8 v; } x;
  x.u[0] = w0; x.u[1] = w1; x.u[2] = w2; x.u[3] = w3;
  return x.v;
}
DEV float geluf(float x) { return 0.5f * x * (1.0f + erff(x * 0.70710678118654752440f)); }

DEV float wredS(float v) {
  #pragma unroll
  for (int o = 32; o; o >>= 1) v += __shfl_xor(v, o);
  return v;
}
DEV float wredM(float v) {
  #pragma unroll
  for (int o = 32; o; o >>= 1) v = fmaxf(v, __shfl_xor(v, o));
  return v;
}
DEV float bredS(float v, float* sm) {   // 4-wave block
  v = wredS(v);
  __syncthreads();
  if ((threadIdx.x & 63) == 0) sm[threadIdx.x >> 6] = v;
  __syncthreads();
  return sm[0] + sm[1] + sm[2] + sm[3];
}
DEV float bredM(float v, float* sm) {
  v = wredM(v);
  __syncthreads();
  if ((threadIdx.x & 63) == 0) sm[threadIdx.x >> 6] = v;
  __syncthreads();
  return fmaxf(fmaxf(sm[0], sm[1]), fmaxf(sm[2], sm[3]));
}

// ------ batched weight transpose+convert (5 matrices, 64x64 tiles -> full-
// line 128B dst writes) + x->bf16 (z==5). grid dim3(16,16,6).
__global__ __launch_bounds__(256) void transpose_w5_k(
    const float* __restrict__ Wq, const float* __restrict__ Wk,
    const float* __restrict__ Wv, const float* __restrict__ W1,
    const float* __restrict__ W2, const float* __restrict__ x,
    u16* __restrict__ WQKVT, u16* __restrict__ W1T, u16* __restrict__ W2T,
    u16* __restrict__ XB) {
  int z = blockIdx.z;
  if (z == 5) {   // x -> bf16: 256 blocks x 256 thr x 16 float4 = Mc*Dc/4
    int base = (int)(blockIdx.y * 16 + blockIdx.x);
    int i0 = base * 4096 + (int)threadIdx.x;
    #pragma unroll
    for (int k = 0; k < 16; ++k) {
      int i = i0 + k * 256;
      float4 v = ((const float4*)x)[i];
      ushort4 u;
      u.x = (u16)bfr(v.x); u.y = (u16)bfr(v.y);
      u.z = (u16)bfr(v.z); u.w = (u16)bfr(v.w);
      ((ushort4*)XB)[i] = u;
    }
    return;
  }
  __shared__ float tile[64][65];
  int bx = blockIdx.x, by = blockIdx.y;   // dst rows bx*64.., src rows by*64..
  const float* src = (z == 0) ? Wq : (z == 1) ? Wk : (z == 2) ? Wv
                    : (z == 3) ? W1 : W2;
  u16* dst = (z == 0) ? WQKVT
           : (z == 1) ? WQKVT + (size_t)1024 * 1024
           : (z == 2) ? WQKVT + (size_t)2 * 1024 * 1024
           : (z == 3) ? W1T : W2T;
  int tx = threadIdx.x & 63, ty = threadIdx.x >> 6;   // ty 0..3
  #pragma unroll
  for (int i = 0; i < 64; i += 4)
    tile[ty + i][tx] = src[(size_t)(by * 64 + ty + i) * Dc + bx * 64 + tx];
  __syncthreads();
  // write: 16 lanes x ushort4 per dst row = 128B full lines
  int quad = threadIdx.x & 15, rw0 = threadIdx.x >> 4;   // rw0 0..15
  #pragma unroll
  for (int it = 0; it < 4; ++it) {
    int rw = it * 16 + rw0;
    ushort4 u;
    u.x = (u16)bfr(tile[quad * 4 + 0][rw]);
    u.y = (u16)bfr(tile[quad * 4 + 1][rw]);
    u.z = (u16)bfr(tile[quad * 4 + 2][rw]);
    u.w = (u16)bfr(tile[quad * 4 + 3][rw]);
    *(ushort4*)&dst[(size_t)(bx * 64 + rw) * Dc + by * 64 + quad * 4] = u;
  }
}

// ---------------- 128x128 bf16 MFMA GEMM ------------------------------------
// BM=BN=128 BK=32; 4 waves 2x2. LDS-staged C epilogue -> coalesced vector
// stores. 2D XCD chunking. MODE 0: QKV (V TRANSPOSED, CSV=129); MODE 1:
// bias+gelu->bf16; MODE 2: bias+residual->f32
template <int MODE, int NBX, int NBY>
__global__ __launch_bounds__(256, 3) void gemm128_k(
    const u16* __restrict__ A, const u16* __restrict__ Bt,
    const float* __restrict__ bias0, const float* __restrict__ bias1,
    const float* __restrict__ bias2,
    u16* __restrict__ outQ, u16* __restrict__ outK, u16* __restrict__ outVT,
    u16* __restrict__ outB, float* __restrict__ outF,
    const float* __restrict__ resid) {
  __shared__ __align__(16) u16 smem[17408];
  u16* as0 = smem;                 // [2][128*32]
  u16* bs0 = smem + 2 * 128 * 32;  // [2][128*32]
  const int tid = threadIdx.x, lane = tid & 63, wave = tid >> 6;
  const int wr = wave >> 1, wc = wave & 1;
  constexpr int RPX = NBX / 4, CPX = NBY / 2;
  const int bid = (int)blockIdx.x;
  const int xcd = bid & 7, l = bid >> 3;
  const int row0 = ((xcd & 3) * RPX + l % RPX) * 128;
  const int col0 = ((xcd >> 2) * CPX + l / RPX) * 128;

  f32x4 zero4;
  #pragma unroll
  for (int r = 0; r < 4; ++r) zero4[r] = 0.f;
  f32x4 acc[4][4];
  #pragma unroll
  for (int i = 0; i < 4; ++i)
    #pragma unroll
    for (int j = 0; j < 4; ++j) acc[i][j] = zero4;

  auto stage = [&](int buf, int kt) {
    const int k0 = kt * 32;
    #pragma unroll
    for (int is = 0; is < 2; ++is) {
      int q = is * 256 + tid; int r = q >> 2, c = q & 3, g = c ^ ((r >> 1) & 3);
      gload16(A + (size_t)(row0 + r) * Dc + k0 + g * 8,
              as0 + (size_t)buf * 4096 + (is * 256 + wave * 64) * 8);
    }
    #pragma unroll
    for (int is = 0; is < 2; ++is) {
      int q = is * 256 + tid; int r = q >> 2, c = q & 3, g = c ^ ((r >> 1) & 3);
      gload16(Bt + (size_t)(col0 + r) * Dc + k0 + g * 8,
              bs0 + (size_t)buf * 4096 + (is * 256 + wave * 64) * 8);
    }
  };

  stage(0, 0);
  asm volatile("s_waitcnt vmcnt(0)" ::: "memory");
  __syncthreads();

  int cur = 0;
  for (int kt = 0; kt < 32; ++kt) {
    if (kt + 1 < 32) stage(cur ^ 1, kt + 1);
    s16x8 af[4], bfv[4];
    #pragma unroll
    for (int f = 0; f < 4; ++f) {
      int r = wr * 64 + f * 16 + (lane & 15);
      int c = (lane >> 4) ^ ((r >> 1) & 3);
      af[f] = *(const s16x8*)&as0[cur * 4096 + r * 32 + c * 8];
    }
    #pragma unroll
    for (int f = 0; f < 4; ++f) {
      int r = wc * 64 + f * 16 + (lane & 15);
      int c = (lane >> 4) ^ ((r >> 1) & 3);
      bfv[f] = *(const s16x8*)&bs0[cur * 4096 + r * 32 + c * 8];
    }
    __builtin_amdgcn_s_setprio(1);
    #pragma unroll
    for (int i = 0; i < 4; ++i)
      #pragma unroll
      for (int j = 0; j < 4; ++j)
        acc[i][j] = __builtin_amdgcn_mfma_f32_16x16x32_bf16(af[i], bfv[j], acc[i][j], 0, 0, 0);
    __builtin_amdgcn_s_setprio(0);
    __syncthreads();
    cur ^= 1;
  }

  if (MODE == 0) {
    const int which = col0 >> 10;          // block-uniform segment
    const float* bias = (which == 0) ? bias0 : (which == 1) ? bias1 : bias2;
    if (which == 2) {
      const int CSV = 129;
      u16* ct = smem;
      #pragma unroll
      for (int i = 0; i < 4; ++i)
        #pragma unroll
        for (int j = 0; j < 4; ++j)
          #pragma unroll
          for (int r = 0; r < 4; ++r) {
            int rl = wr * 64 + i * 16 + (lane >> 4) * 4 + r;
            int cl = wc * 64 + j * 16 + (lane & 15);
            float v = acc[i][j][r] + bias[(col0 + cl) & 1023];
            ct[rl * CSV + cl] = (u16)bfr(v);
          }
      __syncthreads();
      int bb = row0 >> 11, tbase = row0 & 2047;
      #pragma unroll
      for (int it = 0; it < 16; ++it) {
        int linear = it * 256 + tid;       // 4096 quads = 128 d x 32 t-quads
        int dcol = linear >> 5, q4 = linear & 31;
        int t = q4 * 4;
        int n = (col0 & 1023) + dcol;
        int hh = n >> 6, dd = n & 63;
        ushort4 val;
        val.x = ct[(t + 0) * CSV + dcol];
        val.y = ct[(t + 1) * CSV + dcol];
        val.z = ct[(t + 2) * CSV + dcol];
        val.w = ct[(t + 3) * CSV + dcol];
        *(ushort4*)&outVT[((size_t)(bb * Hc + hh) * 64 + dd) * Tc + tbase + t] = val;
      }
    } else {
      const int CS = 136;
      u16* ct = smem;
      #pragma unroll
      for (int i = 0; i < 4; ++i)
        #pragma unroll
        for (int j = 0; j < 4; ++j)
          #pragma unroll
          for (int r = 0; r < 4; ++r) {
            int rl = wr * 64 + i * 16 + (lane >> 4) * 4 + r;
            int cl = wc * 64 + j * 16 + (lane & 15);
            float v = acc[i][j][r] + bias[(col0 + cl) & 1023];
            ct[rl * CS + cl] = (u16)bfr(v);
          }
      __syncthreads();
      #pragma unroll
      for (int it = 0; it < 16; ++it) {
        int linear = it * 256 + tid;
        int row = linear >> 5, c4 = (linear & 31) * 4;
        ushort4 val = *(const ushort4*)&ct[row * CS + c4];
        int grow = row0 + row;
        int col = col0 + c4;
        int n = col & 1023;
        int hh = n >> 6, d = n & 63, bb = grow >> 11, t = grow & 2047;
        if (which == 0)
          *(ushort4*)&outQ[(((size_t)(bb * Hc + hh) * Tc + t) << 6) + d] = val;
        else
          *(ushort4*)&outK[(((size_t)(bb * Hc + hh) * TP + t) << 6) + d] = val;
      }
    }
  } else if (MODE == 1) {
    const int CS = 136;
    u16* ct = smem;
    #pragma unroll
    for (int i = 0; i < 4; ++i)
      #pragma unroll
      for (int j = 0; j < 4; ++j)
        #pragma unroll
        for (int r = 0; r < 4; ++r) {
          int rl = wr * 64 + i * 16 + (lane >> 4) * 4 + r;
          int cl = wc * 64 + j * 16 + (lane & 15);
          float v = geluf(acc[i][j][r] + bias0[col0 + cl]);
          ct[rl * CS + cl] = (u16)bfr(v);
        }
    __syncthreads();
    #pragma unroll
    for (int it = 0; it < 16; ++it) {
      int linear = it * 256 + tid;
      int row = linear >> 5, c4 = (linear & 31) * 4;
      ushort4 val = *(const ushort4*)&ct[row * CS + c4];
      *(ushort4*)&outB[(size_t)(row0 + row) * Dc + col0 + c4] = val;
    }
  } else {
    const int CSF = 132;
    float* cf = (float*)smem;
    #pragma unroll
    for (int p = 0; p < 2; ++p) {
      if (wr == p) {
        #pragma unroll
        for (int i = 0; i < 4; ++i)
          #pragma unroll
          for (int j = 0; j < 4; ++j)
            #pragma unroll
            for (int r = 0; r < 4; ++r) {
              int rl = i * 16 + (lane >> 4) * 4 + r;
              int cl = wc * 64 + j * 16 + (lane & 15);
              cf[rl * CSF + cl] = acc[i][j][r];
            }
      }
      __syncthreads();
      #pragma unroll
      for (int it = 0; it < 8; ++it) {
        int linear = it * 256 + tid;
        int row = linear >> 5, c4 = (linear & 31) * 4;
        float4 v = *(const float4*)&cf[row * CSF + c4];
        int grow = row0 + p * 64 + row;
        int col = col0 + c4;
        float4 rr = *(const float4*)&resid[(size_t)grow * Dc + col];
        float4 o;
        o.x = v.x + bias0[col + 0] + rr.x;
        o.y = v.y + bias0[col + 1] + rr.y;
        o.z = v.z + bias0[col + 2] + rr.z;
        o.w = v.w + bias0[col + 3] + rr.w;
        *(float4*)&outF[(size_t)grow * Dc + col] = o;
      }
      __syncthreads();
    }
  }
}

// ---------------- flash attention, fixed-m, split-K x2, + prompt scores -----
// O-partials packed to bf16 FULL-LINE stores (lane-pair shuffle: lane lo
// stores u32 = bf16(d=2lo)|bf16(d=2lo+1)<<16; 32 lanes = 128B line).
// bf16 partial rounding measured safe (R8: absmax 0.031 with bf16 partials).
__global__ __launch_bounds__(256, 2) void attn_k(
    const u16* __restrict__ qb,   // [bh][T][64]
    const u16* __restrict__ kb,   // [bh][T+32][64]
    const u16* __restrict__ vt,   // [bh][64][T]
    const float* __restrict__ maskp,   // [B][T]
    const float* __restrict__ p1, const float* __restrict__ p2,
    u16* __restrict__ OP0B, u16* __restrict__ OP1B,
    float* __restrict__ ML,
    float* __restrict__ SP) {     // [bh][32][T]
  __shared__ __align__(16) u16 kls[2][64 * 64];
  __shared__ __align__(16) u16 vls[2][64 * 64];
  __shared__ __align__(16) u16 kpls[32 * 64];
  __shared__ float mls[1024];

  const int tid = threadIdx.x, lane = tid & 63, wave = tid >> 6;
  const int wg = ((int)blockIdx.x & 7) * 128 + ((int)blockIdx.x >> 3);
  const int ks = wg & 1, qt = (wg >> 1) & 15, bh = wg >> 5;
  const int b = bh >> 4;
  const int lo = lane & 31, h5 = lane >> 5;
  const size_t kbase = (size_t)bh * TP * 64;
  const size_t vbase = (size_t)bh * 64 * Tc;

  for (int i = tid; i < 1024; i += 256)
    mls[i] = (1.0f - maskp[(size_t)b * Tc + ks * 1024 + i]) * NEGc;

  if (ks == 0) {  // prompt keys: f32 -> bf16 in-register, swizzled kpls layout
    int r = tid >> 3, cg = tid & 7, g = cg ^ swz(r);
    int h = bh & 15;
    const float* src = (r < 16)
        ? (p1 + (size_t)(b * 16 + r) * Dc + h * 64 + g * 8)
        : (p2 + (size_t)(b * 16 + (r - 16)) * Dc + h * 64 + g * 8);
    float4 a = *(const float4*)src;
    float4 c = *(const float4*)(src + 4);
    *(s16x8*)&kpls[tid * 8] = mk8(cvtpk(a.x, a.y), cvtpk(a.z, a.w),
                                  cvtpk(c.x, c.y), cvtpk(c.z, c.w));
  }

  const int q0 = qt * 128 + wave * 32;
  s16x8 qf[4];
  #pragma unroll
  for (int kc = 0; kc < 4; ++kc)
    qf[kc] = *(const s16x8*)(qb + ((size_t)bh * Tc + q0 + lo) * 64 + kc * 16 + h5 * 8);

  auto stageKV = [&](int buf, int kt2) {
    #pragma unroll
    for (int is = 0; is < 2; ++is) {
      int q = is * 256 + tid; int r = q >> 3, c = q & 7, g = c ^ swz(r);
      gload16(kb + kbase + (size_t)(kt2 * 64 + r) * 64 + g * 8,
              &kls[buf][(is * 256 + wave * 64) * 8]);
      gload16(vt + vbase + (size_t)r * Tc + kt2 * 64 + g * 8,
              &vls[buf][(is * 256 + wave * 64) * 8]);
    }
  };

  stageKV(0, ks * 16);
  asm volatile("s_waitcnt vmcnt(0)" ::: "memory");
  __syncthreads();

  f32x16 zero16;
  #pragma unroll
  for (int r = 0; r < 16; ++r) zero16[r] = 0.f;
  f32x16 O0 = zero16, O1 = zero16, racc = zero16;

  int cur = 0;
  for (int kt = 0; kt < 16; ++kt) {
    if (kt + 1 < 16) stageKV(cur ^ 1, ks * 16 + kt + 1);

    #pragma unroll
    for (int c = 0; c < 2; ++c) {
      f32x16 s = zero16;
      __builtin_amdgcn_s_setprio(1);
      #pragma unroll
      for (int kc = 0; kc < 4; ++kc) {
        int r = c * 32 + lo;
        int ci = (kc * 2 + h5) ^ swz(r);
        s16x8 kf = *(const s16x8*)&kls[cur][r * 64 + ci * 8];
        s = __builtin_amdgcn_mfma_f32_32x32x16_bf16(kf, qf[kc], s, 0, 0, 0);
      }
      __builtin_amdgcn_s_setprio(0);

      float4 mq[4];
      #pragma unroll
      for (int g = 0; g < 4; ++g)
        mq[g] = *(const float4*)&mls[kt * 64 + c * 32 + 4 * h5 + 8 * g];

      float p[16];
      #pragma unroll
      for (int r = 0; r < 16; ++r) {
        float mv = (&mq[r >> 2].x)[r & 3];
        p[r] = exp2f(s[r] * SCALE2c + mv);
        racc[r] += p[r];
      }

      #pragma unroll
      for (int k1 = 0; k1 < 2; ++k1) {
        u32 w0 = cvtpk(p[8 * k1 + 0], p[8 * k1 + 1]);
        u32 w1 = cvtpk(p[8 * k1 + 2], p[8 * k1 + 3]);
        u32 w2 = cvtpk(p[8 * k1 + 4], p[8 * k1 + 5]);
        u32 w3 = cvtpk(p[8 * k1 + 6], p[8 * k1 + 7]);
        asm volatile("v_permlane32_swap_b32 %0, %1" : "+v"(w2), "+v"(w0));
        asm volatile("v_permlane32_swap_b32 %0, %1" : "+v"(w3), "+v"(w1));
        s16x8 pf = mk8(w0, w1, w2, w3);
        __builtin_amdgcn_s_setprio(1);
        #pragma unroll
        for (int db = 0; db < 2; ++db) {
          int d = db * 32 + lo;
          int ci = (c * 4 + k1 * 2 + h5) ^ swz(d);
          s16x8 vf = *(const s16x8*)&vls[cur][d * 64 + ci * 8];
          if (db == 0) O0 = __builtin_amdgcn_mfma_f32_32x32x16_bf16(pf, vf, O0, 0, 0, 0);
          else         O1 = __builtin_amdgcn_mfma_f32_32x32x16_bf16(pf, vf, O1, 0, 0, 0);
        }
        __builtin_amdgcn_s_setprio(0);
      }
    }
    __syncthreads();
    cur ^= 1;
  }

  // prompt scores (ks==0 blocks): S_p^T[pkey][q] * scale
  if (ks == 0) {
    f32x16 sp = zero16;
    #pragma unroll
    for (int kc = 0; kc < 4; ++kc) {
      int ci = (kc * 2 + h5) ^ swz(lo);
      s16x8 kf = *(const s16x8*)&kpls[lo * 64 + ci * 8];
      sp = __builtin_amdgcn_mfma_f32_32x32x16_bf16(kf, qf[kc], sp, 0, 0, 0);
    }
    #pragma unroll
    for (int r = 0; r < 16; ++r) {
      int pr = (r & 3) + 8 * (r >> 2) + 4 * h5;
      SP[((size_t)bh * 32 + pr) * Tc + q0 + lo] = sp[r] * SCALEc;
    }
  }

  // epilogue: bf16 PACKED full-line partials (lane-pair shuffle) + row sums
  u32* dstw = (u32*)(ks ? OP1B : OP0B);
  #pragma unroll
  for (int r = 0; r < 16; ++r) {
    int row = q0 + (r & 3) + 8 * (r >> 2) + 4 * h5;
    int srcE = (h5 << 5) | ((2 * lo) & 31);
    int srcO = (h5 << 5) | ((2 * lo + 1) & 31);
    float aE = __shfl(O0[r], srcE), bE = __shfl(O1[r], srcE);
    float aO = __shfl(O0[r], srcO), bO = __shfl(O1[r], srcO);
    float vE = (lo < 16) ? aE : bE;
    float vO = (lo < 16) ? aO : bO;
    dstw[((size_t)bh * Tc + row) * 32 + lo] = cvtpk(vE, vO);
  }
  float lt = 0.f;
  #pragma unroll
  for (int r = 0; r < 16; ++r) lt += racc[r];
  lt += __shfl_xor(lt, 32);
  if (lane < 32)
    ML[((size_t)ks * 32 + bh) * Tc + q0 + lo] = lt;
}

// ---------------- prompt double softmax over t ------------------------------
__global__ __launch_bounds__(256) void prompt_softmax_k(float* __restrict__ SP,
                                                        const float* __restrict__ pr1,
                                                        const float* __restrict__ pr2) {
  __shared__ float sm[4];
  int row = blockIdx.x;          // bh*32 + p
  int bh = row >> 5, p = row & 31, b = bh >> 4;
  const float* prior = (p < 16 ? pr1 : pr2) + (size_t)b * Tc;
  float* s = SP + (size_t)row * Tc;
  int tid = threadIdx.x;
  float v[8], pw[8];
  #pragma unroll
  for (int i = 0; i < 8; ++i) { int t = tid + i * 256; v[i] = s[t]; pw[i] = prior[t]; }
  float mx = -INFINITY;
  #pragma unroll
  for (int i = 0; i < 8; ++i) mx = fmaxf(mx, v[i]);
  mx = bredM(mx, sm);
  float sum = 0.f;
  #pragma unroll
  for (int i = 0; i < 8; ++i) { v[i] = __expf(v[i] - mx); sum += v[i]; }
  sum = bredS(sum, sm);
  float inv = 1.0f / sum;
  float mx2 = -INFINITY;
  #pragma unroll
  for (int i = 0; i < 8; ++i) { v[i] = v[i] * inv * pw[i]; mx2 = fmaxf(mx2, v[i]); }
  mx2 = bredM(mx2, sm);
  float sum2 = 0.f;
  #pragma unroll
  for (int i = 0; i < 8; ++i) { v[i] = __expf(v[i] - mx2); sum2 += v[i]; }
  sum2 = bredS(sum2, sm);
  float inv2 = 1.0f / sum2;
  #pragma unroll
  for (int i = 0; i < 8; ++i) s[tid + i * 256] = v[i] * inv2;
}

// -------- p_v partials with fused combine (bf16 partials -> f32 ctx) --------
__global__ __launch_bounds__(256) void pv_partial_k(const float* __restrict__ PA,
                                                    const u16* __restrict__ OP0B,
                                                    const u16* __restrict__ OP1B,
                                                    const float* __restrict__ ML,
                                                    float* __restrict__ ctx,
                                                    float* __restrict__ PVP) {
  __shared__ float pal[32][128];
  __shared__ float lsm[128];
  const int bh = blockIdx.x, ts = blockIdx.y;
  const int tid = threadIdx.x;
  const int t0 = ts * 128;
  const float* pabase = PA + (size_t)bh * 32 * Tc;
  const u32* w0p = (const u32*)OP0B;
  const u32* w1p = (const u32*)OP1B;

  if (tid < 128) {
    size_t r = (size_t)bh * Tc + t0 + tid;
    lsm[tid] = 1.0f / (ML[r] + ML[(size_t)32 * Tc + r]);
  }
  __syncthreads();
  #pragma unroll
  for (int pp = 0; pp < 8; ++pp) {
    int idx = pp * 256 + tid;              // 0..2047 = 128 rows x 16 quads
    int rr = idx >> 4, c4 = (idx & 15) * 4;
    size_t rowb = ((size_t)bh * Tc + t0 + rr) * 32 + (c4 >> 1);
    u32 a0 = w0p[rowb], a1 = w0p[rowb + 1];
    u32 b0 = w1p[rowb], b1 = w1p[rowb + 1];
    float li = lsm[rr];
    float4 o;
    o.x = (b2f(a0 & 0xffffu) + b2f(b0 & 0xffffu)) * li;
    o.y = (b2f(a0 >> 16)     + b2f(b0 >> 16))     * li;
    o.z = (b2f(a1 & 0xffffu) + b2f(b1 & 0xffffu)) * li;
    o.w = (b2f(a1 >> 16)     + b2f(b1 >> 16))     * li;
    *(float4*)(ctx + ((size_t)bh * Tc + t0 + rr) * 64 + c4) = o;
  }
  __syncthreads();

  #pragma unroll
  for (int i = 0; i < 4; ++i) {
    int e = tid + i * 256;
    int p = e >> 5, c4 = e & 31;
    *(float4*)&pal[p][c4 * 4] = *(const float4*)&pabase[(size_t)p * Tc + t0 + c4 * 4];
  }
  __syncthreads();

  const int d4 = tid & 15, p0 = tid >> 4;
  const float* cb = ctx + ((size_t)bh * Tc + t0) * 64 + d4 * 4;
  float4 a0 = make_float4(0.f, 0.f, 0.f, 0.f);
  float4 a1 = make_float4(0.f, 0.f, 0.f, 0.f);
  for (int tt = 0; tt < 128; ++tt) {
    float4 v = *(const float4*)(cb + (size_t)tt * 64);
    float w0 = pal[p0][tt], w1 = pal[p0 + 16][tt];
    a0.x += w0 * v.x; a0.y += w0 * v.y; a0.z += w0 * v.z; a0.w += w0 * v.w;
    a1.x += w1 * v.x; a1.y += w1 * v.y; a1.z += w1 * v.z; a1.w += w1 * v.w;
  }
  float* o = PVP + (((size_t)ts * 32 + bh) * 32) * 64 + d4 * 4;
  *(float4*)(o + (size_t)p0 * 64) = a0;
  *(float4*)(o + (size_t)(p0 + 16) * 64) = a1;
}

// ---------------- residual + LN (main path) ---------------------------------
__global__ __launch_bounds__(256) void resln_k(const float* __restrict__ x,
                                               const float* __restrict__ ctx,
                                               const float* __restrict__ g,
                                               const float* __restrict__ be,
                                               float* __restrict__ res,
                                               u16* __restrict__ lnout) {
  __shared__ float sm[4];
  int row = blockIdx.x;            // 0..4095
  int b = row >> 11, t = row & 2047;
  int tid = threadIdx.x, c4 = tid * 4;
  int h = c4 >> 6, d = c4 & 63;
  float4 xv = *(const float4*)(x + (size_t)row * Dc + c4);
  float4 cv = *(const float4*)(ctx + (((size_t)(b * Hc + h) * Tc + t) << 6) + d);
  float r0 = xv.x + cv.x, r1 = xv.y + cv.y, r2 = xv.z + cv.z, r3 = xv.w + cv.w;
  float4 rr; rr.x = r0; rr.y = r1; rr.z = r2; rr.w = r3;
  *(float4*)(res + (size_t)row * Dc + c4) = rr;
  float s = bredS(r0 + r1 + r2 + r3, sm);
  float sq = bredS(r0 * r0 + r1 * r1 + r2 * r2 + r3 * r3, sm);
  float mu = s * (1.0f / Dc);
  float var = sq * (1.0f / Dc) - mu * mu;
  float rs = rsqrtf(var + 1e-6f);
  ushort4 o;
  o.x = (u16)bfr((r0 - mu) * rs * g[c4 + 0] + be[c4 + 0]);
  o.y = (u16)bfr((r1 - mu) * rs * g[c4 + 1] + be[c4 + 1]);
  o.z = (u16)bfr((r2 - mu) * rs * g[c4 + 2] + be[c4 + 2]);
  o.w = (u16)bfr((r3 - mu) * rs * g[c4 + 3] + be[c4 + 3]);
  *(ushort4*)(lnout + (size_t)row * Dc + c4) = o;
}

// ---------------- prompt merge (PVP reduce inline) + residual + LN ----------
__global__ __launch_bounds__(256) void promptln_k(const float* __restrict__ PVP,
                                                  const float* __restrict__ p1,
                                                  const float* __restrict__ p2,
                                                  const float* __restrict__ g,
                                                  const float* __restrict__ be,
                                                  float* __restrict__ PMLN) {
  __shared__ float sm[4];
  int row = blockIdx.x;            // 0..63 : b = row>>5, j = row&31
  int b = row >> 5, j = row & 31;
  int tid = threadIdx.x, c4 = tid * 4;
  int h = c4 >> 6, d = c4 & 63;
  int bh = b * Hc + h;
  const float* pr = (j < 16) ? (p1 + (size_t)(b * 16 + j) * Dc + c4)
                             : (p2 + (size_t)(b * 16 + j - 16) * Dc + c4);
  float4 pv4 = make_float4(0.f, 0.f, 0.f, 0.f);
  #pragma unroll
  for (int ts = 0; ts < 16; ++ts) {
    float4 v = *(const float4*)(PVP + (((size_t)ts * 32 + bh) * 32 + j) * 64 + d);
    pv4.x += v.x; pv4.y += v.y; pv4.z += v.z; pv4.w += v.w;
  }
  float4 pp4 = *(const float4*)pr;
  float r0 = pv4.x + pp4.x, r1 = pv4.y + pp4.y, r2 = pv4.z + pp4.z, r3 = pv4.w + pp4.w;
  float s = bredS(r0 + r1 + r2 + r3, sm);
  float sq = bredS(r0 * r0 + r1 * r1 + r2 * r2 + r3 * r3, sm);
  float mu = s * (1.0f / Dc);
  float var = sq * (1.0f / Dc) - mu * mu;
  float rs = rsqrtf(var + 1e-6f);
  float4 o;
  o.x = (r0 - mu) * rs * g[c4 + 0] + be[c4 + 0];
  o.y = (r1 - mu) * rs * g[c4 + 1] + be[c4 + 1];
  o.z = (r2 - mu) * rs * g[c4 + 2] + be[c4 + 2];
  o.w = (r3 - mu) * rs * g[c4 + 3] + be[c4 + 3];
  *(float4*)(PMLN + (size_t)row * Dc + c4) = o;
}

// ---------------- prompt FFN, split-K partials ------------------------------
__global__ __launch_bounds__(256) void pffn_partial_k(const float* __restrict__ PMLN,
                                                      const float* __restrict__ Wp1,
                                                      const float* __restrict__ Wp2,
                                                      float* __restrict__ PB) {
  __shared__ float pm[32][32];
  const int tid = threadIdx.x;
  const int ks = blockIdx.x, ct = blockIdx.y, s = blockIdx.z;
  const int c = ct * 256 + tid;
  const int k0 = ks * 32;
  const float* W = s ? Wp2 : Wp1;

  #pragma unroll
  for (int i = 0; i < 4; ++i) {
    int e = tid + i * 256;
    int r = e >> 5, kk = e & 31;
    int grow = (r >> 4) * 32 + s * 16 + (r & 15);
    pm[r][kk] = PMLN[(size_t)grow * Dc + k0 + kk];
  }
  __syncthreads();

  float acc[32];
  #pragma unroll
  for (int r = 0; r < 32; ++r) acc[r] = 0.f;
  for (int kk = 0; kk < 32; ++kk) {
    float w = W[(size_t)(k0 + kk) * Dc + c];
    #pragma unroll
    for (int r = 0; r < 32; ++r) acc[r] += pm[r][kk] * w;
  }

  float* pb = PB + (((size_t)ks * 2 + s) * 32) * Dc + c;
  #pragma unroll
  for (int r = 0; r < 32; ++r) pb[(size_t)r * Dc] = acc[r];
}

__global__ __launch_bounds__(256) void pffn_reduce_k(const float* __restrict__ PB,
                                                     const float* __restrict__ bp1,
                                                     const float* __restrict__ bp2,
                                                     float* __restrict__ out) {
  int e = blockIdx.x * 256 + threadIdx.x;   // 0..65535
  int s = e >> 15, rem = e & 32767;
  int r = rem >> 10, c = rem & 1023;
  float sum = 0.f;
  const float* pb = PB + ((size_t)s * 32 + r) * Dc + c;
  #pragma unroll
  for (int ks = 0; ks < 32; ++ks) sum += pb[(size_t)ks * 2 * 32 * Dc];
  const float* bp = s ? bp2 : bp1;
  out[(size_t)Mc * Dc + (size_t)s * (32 * Dc) + (size_t)r * Dc + c] = geluf(sum + bp[c]);
}

// ============================================================================
extern "C" void kernel_launch(void* const* d_in, const int* in_sizes, int n_in,
                              void* d_out, int out_size, void* d_ws, size_t ws_size,
                              hipStream_t stream) {
  (void)in_sizes; (void)n_in; (void)out_size; (void)ws_size;
  const float* x   = (const float*)d_in[0];
  const float* p1  = (const float*)d_in[1];
  const float* p2  = (const float*)d_in[2];
  const float* pr1 = (const float*)d_in[3];
  const float* pr2 = (const float*)d_in[4];
  const float* msk = (const float*)d_in[5];
  const float* Wq  = (const float*)d_in[6];
  const float* bq  = (const float*)d_in[7];
  const float* Wk  = (const float*)d_in[8];
  const float* bk  = (const float*)d_in[9];
  const float* Wv  = (const float*)d_in[10];
  const float* bv  = (const float*)d_in[11];
  const float* g2  = (const float*)d_in[12];
  const float* be2 = (const float*)d_in[13];
  const float* W1  = (const float*)d_in[14];
  const float* b1  = (const float*)d_in[15];
  const float* W2  = (const float*)d_in[16];
  const float* b2  = (const float*)d_in[17];
  const float* Wp1 = (const float*)d_in[18];
  const float* bp1 = (const float*)d_in[19];
  const float* Wp2 = (const float*)d_in[20];
  const float* bp2 = (const float*)d_in[21];

  char* ws = (char*)d_ws;
  size_t off = 0;
  auto alloc = [&](size_t bytes) {
    void* p = ws + off;
    off += (bytes + 255) & ~(size_t)255;
    return p;
  };
  u16* WQKVT = (u16*)alloc((size_t)3072 * 1024 * 2);
  u16* W1T   = (u16*)alloc((size_t)1024 * 1024 * 2);
  u16* W2T   = (u16*)alloc((size_t)1024 * 1024 * 2);
  u16* XB    = (u16*)alloc((size_t)Mc * Dc * 2);
  u16* QB    = (u16*)alloc((size_t)32 * Tc * 64 * 2);
  u16* KB    = (u16*)alloc((size_t)32 * TP * 64 * 2);
  u16* H1    = (u16*)alloc((size_t)Mc * Dc * 2);
  u16* VT    = (u16*)alloc((size_t)32 * 64 * Tc * 2);
  float* CTX = (float*)alloc((size_t)32 * Tc * 64 * 4);
  float* SP  = (float*)alloc((size_t)32 * 32 * Tc * 4);
  float* RES = (float*)alloc((size_t)Mc * Dc * 4);
  float* PMLN = (float*)alloc((size_t)64 * Dc * 4);
  float* ML  = (float*)alloc((size_t)2 * 32 * Tc * 4);
  float* PVP = (float*)alloc((size_t)16 * 32 * 32 * 64 * 4);
  u16* LNOUT = XB;    // reuse: XB dead after QKV GEMM
  float* PB  = SP;    // reuse: SP dead after pv
  u16* OP0B  = (u16*)RES;                          // bf16 partials live in RES
  u16* OP1B  = (u16*)RES + (size_t)32 * Tc * 64;   // (RES free until resln_k)

  float* outMain = (float*)d_out;

  // 1. weight transposes (64x64 tiles, full-line writes) + x->bf16
  transpose_w5_k<<<dim3(16, 16, 6), 256, 0, stream>>>(Wq, Wk, Wv, W1, W2, x,
                                                      WQKVT, W1T, W2T, XB);
  // 2. QKV fused GEMM (N=3072); V TRANSPOSED; 2D XCD chunking
  gemm128_k<0, 32, 24><<<768, 256, 0, stream>>>(XB, WQKVT, bq, bk, bv, QB, KB,
                                                VT, nullptr, nullptr, nullptr);
  // 3. flash attention (bf16 packed full-line partials) + fused prompt scores
  attn_k<<<1024, 256, 0, stream>>>(QB, KB, VT, msk, p1, p2, OP0B, OP1B, ML, SP);
  // 4. prompt double-softmax (in place)
  prompt_softmax_k<<<1024, 256, 0, stream>>>(SP, pr1, pr2);
  // 5. p_v = p_a @ ctx : fused combine (bf16 unpack -> f32 ctx) + partials
  pv_partial_k<<<dim3(32, 16), 256, 0, stream>>>(SP, OP0B, OP1B, ML, CTX, PVP);
  // 6. residual + LN (main); ctx materialized by pv_partial
  resln_k<<<4096, 256, 0, stream>>>(x, CTX, g2, be2, RES, LNOUT);
  // 7. prompt merge (inline PVP reduce) + LN
  promptln_k<<<64, 256, 0, stream>>>(PVP, p1, p2, g2, be2, PMLN);
  // 8. prompt FFN (split-K): partials then reduce -> d_out (p1_out, p2_out)
  pffn_partial_k<<<dim3(32, 4, 2), 256, 0, stream>>>(PMLN, Wp1, Wp2, PB);
  pffn_reduce_k<<<256, 256, 0, stream>>>(PB, bp1, bp2, outMain);
  // 9. FFN1: gelu(ln @ W1 + b1) -> bf16; 2D XCD chunking
  gemm128_k<1, 32, 8><<<256, 256, 0, stream>>>(LNOUT, W1T, b1, nullptr, nullptr,
                                               nullptr, nullptr, nullptr, H1,
                                               nullptr, nullptr);
  // 10. FFN2: h1 @ W2 + b2 + residual -> d_out (main); 2D XCD chunking
  gemm128_k<2, 32, 8><<<256, 256, 0, stream>>>(H1, W2T, b2, nullptr, nullptr,
                                               nullptr, nullptr, nullptr, nullptr,
                                               outMain, RES);
}